// Round 7
// baseline (428.721 us; speedup 1.0000x reference)
//
#include <hip/hip_runtime.h>
#include <cstdint>
#include <cstddef>

#define TOK    32768   // B*L
#define BATCH  8
#define SEQ    4096
#define DMODEL 256
#define DINNER 512
#define DSTATE 64
#define NH     16
#define HD     32
#define DPROJ  1168
#define NPAD   1280    // in_proj N padded to 10*128
#define CONVD  640
#define VOCAB  512
#define HGRP   4       // heads per chunk/yoff block
#define TS     132     // conv tile LDS stride (shorts)

typedef __attribute__((ext_vector_type(8))) short bf16x8;
typedef __attribute__((ext_vector_type(4))) float f32x4;

__device__ __forceinline__ unsigned short f2bf(float f) {
    unsigned u = __float_as_uint(f);
    u += 0x7fffu + ((u >> 16) & 1u);       // RNE
    return (unsigned short)(u >> 16);
}
__device__ __forceinline__ float bf2f(short s) {
    return __uint_as_float(((unsigned)(unsigned short)s) << 16);
}
__device__ __forceinline__ float sp(float v) { return v > 20.f ? v : log1pf(expf(v)); }

// ---------------- ws layout (floats, all 16B aligned) ----------------
#define U16_OFF   0                                    // TOK*256 bf16
#define Z16_OFF   (U16_OFF  + (size_t)TOK*128)         // TOK*512 bf16
#define XBC_OFF   (Z16_OFF  + (size_t)TOK*256)         // TOK*640 bf16
#define DTS_OFF   (XBC_OFF  + (size_t)TOK*320)         // TOK*16 fp32
#define ACS_OFF   (DTS_OFF  + (size_t)TOK*16)
#define CDEC_OFF  (ACS_OFF  + (size_t)BATCH*NH*64*64)
#define WP_OFF    (CDEC_OFF + (size_t)BATCH*NH*64)
#define WO_OFF    (WP_OFF   + 163840)
#define WE_OFF    (WO_OFF   + 65536)
#define UNION_OFF (WE_OFF   + 65536)
// union: st fp32 8*64*16*2048 | Yb bf16 TOK*512 + xf16 bf16 TOK*256
#define UNION_FL  ((size_t)BATCH*64*NH*2048)
#define XF_SUB    ((size_t)TOK*256)
#define WS_FLOATS (UNION_OFF + UNION_FL)

__global__ void k_diag(float* out, float wsmb) {
    if (blockIdx.x == 0 && threadIdx.x == 0) out[0] = wsmb;
}

// ---------------- weight fp32 -> bf16 (+ zero pad) ----------------
__global__ void k_cvt(const float* __restrict__ s, short* __restrict__ d, int nsrc, int ntot) {
    int i = blockIdx.x * 256 + threadIdx.x;
    if (i < ntot) d[i] = (i < nsrc) ? (short)f2bf(s[i]) : (short)0;
}

// ---------------- embed gather + rmsnorm -> u16 (bf16) ----------------
__global__ void k_embed(const int* __restrict__ ids, const float* __restrict__ embed,
                        const float* __restrict__ norm_w, short* __restrict__ u16) {
    int t = blockIdx.x;
    int lane = threadIdx.x;   // 64
    int id = ids[t];
    float4 v = ((const float4*)(embed + (size_t)id * DMODEL))[lane];
    float ss = v.x*v.x + v.y*v.y + v.z*v.z + v.w*v.w;
    #pragma unroll
    for (int o = 32; o > 0; o >>= 1) ss += __shfl_down(ss, o);
    ss = __shfl(ss, 0);
    float r = rsqrtf(ss * (1.0f / DMODEL) + 1e-6f);
    float4 w = ((const float4*)norm_w)[lane];
    unsigned p0 = (unsigned)f2bf(v.x * r * w.x) | ((unsigned)f2bf(v.y * r * w.y) << 16);
    unsigned p1 = (unsigned)f2bf(v.z * r * w.z) | ((unsigned)f2bf(v.w * r * w.w) << 16);
    ((uint2*)(u16 + (size_t)t * DMODEL))[lane] = make_uint2(p0, p1);
}

// ---------------- bf16 MFMA GEMM, BK=64, reg-prefetch pipeline, swizzled LDS ----------------
// MODE 0: in_proj: cols<512 -> z16 ; 512..1151 -> fused conv+silu -> xbc (halo via MFMA) ; 1152.. -> dt
// MODE 1: out_proj: + embed[ids] residual -> xf16 (via z16 param)
// MODE 2: logits: fp32 -> outF
template<int MODE>
__global__ __launch_bounds__(256) void k_gemm_mfma(
    const short* __restrict__ A, const short* __restrict__ B, int K,
    float* __restrict__ outF, short* __restrict__ z16, short* __restrict__ xbc,
    float* __restrict__ dts, const float* __restrict__ dt_bias,
    const int* __restrict__ ids, const float* __restrict__ embed,
    const float* __restrict__ cw, const float* __restrict__ cb) {
    __shared__ __align__(16) short SM[MODE == 0 ? (131 * TS) : 16384];  // As|Bs, union conv Tile
    short* As = SM;
    short* Bs = SM + 8192;
    int tid = threadIdx.x;
    int m0 = blockIdx.y << 7;
    int n0 = blockIdx.x << 7;
    int wave = tid >> 6, lane = tid & 63;
    int wm = wave >> 1, wn = wave & 1;
    int lr = lane & 15, lg = lane >> 4;
    const f32x4 zer = {0.f, 0.f, 0.f, 0.f};
    f32x4 acc[4][4];
    #pragma unroll
    for (int i = 0; i < 4; i++)
        #pragma unroll
        for (int j = 0; j < 4; j++) acc[i][j] = zer;

    const bool isXBC = (MODE == 0) && (n0 >= 512) && (n0 < 1152);
    const bool atStart = (m0 & (SEQ - 1)) == 0;
    const bool haloLane = isXBC && (wm == 0) && !atStart && (lr < 3);
    f32x4 hacc[4];
    #pragma unroll
    for (int j = 0; j < 4; j++) hacc[j] = zer;
    const bf16x8 hz = {0, 0, 0, 0, 0, 0, 0, 0};
    bf16x8 hc0 = hz, hc1 = hz, hn0 = hz, hn1 = hz;

    int4 pa[4], pb[4];
    const int nK = K >> 6;

    // prologue: load + write tile 0
    {
        #pragma unroll
        for (int i = 0; i < 4; i++) {
            int u = i * 256 + tid, row = u >> 3, kb = u & 7;
            pa[i] = *(const int4*)(A + (size_t)(m0 + row) * K + kb * 8);
            pb[i] = *(const int4*)(B + (size_t)(n0 + row) * K + kb * 8);
        }
        if (haloLane) {
            hc0 = *(const bf16x8*)(A + (size_t)(m0 - 3 + lr) * K + lg * 8);
            hc1 = *(const bf16x8*)(A + (size_t)(m0 - 3 + lr) * K + 32 + lg * 8);
        }
        #pragma unroll
        for (int i = 0; i < 4; i++) {
            int u = i * 256 + tid, row = u >> 3, kb = u & 7;
            int off = row * 64 + ((kb ^ (row & 7)) << 3);
            *(int4*)&As[off] = pa[i];
            *(int4*)&Bs[off] = pb[i];
        }
    }

    for (int kt = 0; kt < nK; ++kt) {
        __syncthreads();                      // tile kt visible
        bool pre = (kt + 1 < nK);
        if (pre) {                            // issue next-tile loads (fly under MFMA)
            int k0 = (kt + 1) << 6;
            #pragma unroll
            for (int i = 0; i < 4; i++) {
                int u = i * 256 + tid, row = u >> 3, kb = u & 7;
                pa[i] = *(const int4*)(A + (size_t)(m0 + row) * K + k0 + kb * 8);
                pb[i] = *(const int4*)(B + (size_t)(n0 + row) * K + k0 + kb * 8);
            }
            if (haloLane) {
                hn0 = *(const bf16x8*)(A + (size_t)(m0 - 3 + lr) * K + k0 + lg * 8);
                hn1 = *(const bf16x8*)(A + (size_t)(m0 - 3 + lr) * K + k0 + 32 + lg * 8);
            }
        }
        #pragma unroll
        for (int kk = 0; kk < 2; kk++) {
            int sw = (((kk << 2) + lg) ^ (lr & 7)) << 3;
            bf16x8 af[4], bfr[4];
            #pragma unroll
            for (int mi = 0; mi < 4; mi++)
                af[mi] = *(const bf16x8*)&As[(wm * 64 + mi * 16 + lr) * 64 + sw];
            #pragma unroll
            for (int ni = 0; ni < 4; ni++)
                bfr[ni] = *(const bf16x8*)&Bs[(wn * 64 + ni * 16 + lr) * 64 + sw];
            #pragma unroll
            for (int mi = 0; mi < 4; mi++)
                #pragma unroll
                for (int ni = 0; ni < 4; ni++)
                    acc[mi][ni] = __builtin_amdgcn_mfma_f32_16x16x32_bf16(af[mi], bfr[ni], acc[mi][ni], 0, 0, 0);
            if (isXBC && wm == 0) {
                bf16x8 h = (kk == 0) ? hc0 : hc1;
                #pragma unroll
                for (int ni = 0; ni < 4; ni++)
                    hacc[ni] = __builtin_amdgcn_mfma_f32_16x16x32_bf16(h, bfr[ni], hacc[ni], 0, 0, 0);
            }
        }
        __syncthreads();                      // all reads of tile kt done
        if (pre) {
            #pragma unroll
            for (int i = 0; i < 4; i++) {
                int u = i * 256 + tid, row = u >> 3, kb = u & 7;
                int off = row * 64 + ((kb ^ (row & 7)) << 3);
                *(int4*)&As[off] = pa[i];
                *(int4*)&Bs[off] = pb[i];
            }
            hc0 = hn0; hc1 = hn1;
        }
    }

    if (isXBC) {
        // ---- fused causal conv(k=4) + SiLU, sliding-window epilogue ----
        short* Tile = SM;   // [131][TS]: rows 0-2 = halo, 3+row = token m0+row
        #pragma unroll
        for (int mi = 0; mi < 4; mi++)
            #pragma unroll
            for (int ni = 0; ni < 4; ni++)
                #pragma unroll
                for (int r = 0; r < 4; r++) {
                    int row = wm * 64 + mi * 16 + lg * 4 + r;
                    int col = wn * 64 + ni * 16 + lr;
                    unsigned mv = f2bf(acc[mi][ni][r]);
                    unsigned ov = (unsigned)__shfl_xor((int)mv, 1);
                    if (!(lr & 1))
                        *(unsigned*)&Tile[(3 + row) * TS + col] = (mv & 0xffffu) | (ov << 16);
                }
        if (wm == 0 && lg == 0) {
            #pragma unroll
            for (int ni = 0; ni < 4; ni++)
                #pragma unroll
                for (int r = 0; r < 3; r++)
                    Tile[r * TS + wn * 64 + ni * 16 + lr] = (short)f2bf(hacc[ni][r]);
        }
        __syncthreads();
        int cp = tid & 63, rg = tid >> 6;
        int colb = cp * 2;
        int ch = (n0 - 512) + colb;
        float c0w0 = cw[ch * 4], c0w1 = cw[ch * 4 + 1], c0w2 = cw[ch * 4 + 2], c0w3 = cw[ch * 4 + 3];
        float c1w0 = cw[ch * 4 + 4], c1w1 = cw[ch * 4 + 5], c1w2 = cw[ch * 4 + 6], c1w3 = cw[ch * 4 + 7];
        float b0v = cb[ch], b1v = cb[ch + 1];
        int rbase = rg * 32;
        unsigned w0 = *(const unsigned*)&Tile[(rbase + 0) * TS + colb];
        unsigned w1 = *(const unsigned*)&Tile[(rbase + 1) * TS + colb];
        unsigned w2 = *(const unsigned*)&Tile[(rbase + 2) * TS + colb];
        for (int i = 0; i < 32; i++) {
            unsigned w3 = *(const unsigned*)&Tile[(rbase + i + 3) * TS + colb];
            float s0 = b0v, s1 = b1v;
            s0 = fmaf(bf2f((short)(w0 & 0xffffu)), c0w0, s0); s1 = fmaf(bf2f((short)(w0 >> 16)), c1w0, s1);
            s0 = fmaf(bf2f((short)(w1 & 0xffffu)), c0w1, s0); s1 = fmaf(bf2f((short)(w1 >> 16)), c1w1, s1);
            s0 = fmaf(bf2f((short)(w2 & 0xffffu)), c0w2, s0); s1 = fmaf(bf2f((short)(w2 >> 16)), c1w2, s1);
            s0 = fmaf(bf2f((short)(w3 & 0xffffu)), c0w3, s0); s1 = fmaf(bf2f((short)(w3 >> 16)), c1w3, s1);
            s0 = s0 / (1.f + expf(-s0));
            s1 = s1 / (1.f + expf(-s1));
            *(unsigned*)&xbc[(size_t)(m0 + rbase + i) * CONVD + ch] =
                (unsigned)f2bf(s0) | ((unsigned)f2bf(s1) << 16);
            w0 = w1; w1 = w2; w2 = w3;
        }
        return;
    }

    #pragma unroll
    for (int mi = 0; mi < 4; mi++) {
        #pragma unroll
        for (int r = 0; r < 4; r++) {
            int row = m0 + wm * 64 + mi * 16 + lg * 4 + r;
            int id = 0;
            if (MODE == 1) id = ids[row];
            #pragma unroll
            for (int ni = 0; ni < 4; ni++) {
                int col = n0 + wn * 64 + ni * 16 + lr;
                float v = acc[mi][ni][r];
                if (MODE == 0) {
                    if (n0 < 512) {
                        unsigned mv = f2bf(v);
                        unsigned ov = (unsigned)__shfl_xor((int)mv, 1);
                        if (!(lr & 1))
                            *(unsigned*)&z16[(size_t)row * DINNER + col] = (mv & 0xffffu) | (ov << 16);
                    } else if (wn == 0 && ni == 0) {   // dt cols 1152..1167
                        dts[(size_t)row * NH + lr] = sp(v + dt_bias[lr]);
                    }
                } else if (MODE == 1) {
                    float vo = __shfl_xor(v, 1);
                    if (!(lr & 1)) {
                        float2 res = *(const float2*)&embed[(size_t)id * DMODEL + col];
                        *(unsigned*)&z16[(size_t)row * DMODEL + col] =
                            (unsigned)f2bf(v + res.x) | ((unsigned)f2bf(vo + res.y) << 16);
                    }
                } else {
                    outF[(size_t)row * VOCAB + col] = v;
                }
            }
        }
    }
}

// ---------------- K4a: per-(b,c,headgroup): M via MFMA, Y_diag + states via MFMA ----------------
__global__ __launch_bounds__(256) void k_chunk(const short* __restrict__ xbc, const float* __restrict__ dts,
                                               const float* __restrict__ A_log,
                                               float* __restrict__ Y, float* __restrict__ states,
                                               float* __restrict__ acs_g, float* __restrict__ cdec) {
    __shared__ short CsB[64 * 72];   // C[q][n]
    __shared__ short BsB[64 * 72];   // B[k][n]
    __shared__ short Wsh[64 * 72];   // W[q][k] per head
    __shared__ short XtS[32 * 72];   // Xt[p][k] per head
    __shared__ short BdS[64 * 72];   // Bd[n][k] per head
    __shared__ float acsS[HGRP][64];
    __shared__ float dkS[HGRP][64];
    int tid = threadIdx.x;
    int bid = blockIdx.x;
    int hg = bid & 3;
    int bc = bid >> 2;
    int b = bc >> 6, c = bc & 63;
    int h0 = hg * HGRP;
    size_t tbase = (size_t)b * SEQ + (size_t)c * 64;
    int wave = tid >> 6, lane = tid & 63;
    int lr = lane & 15, lg = lane >> 4;

    for (int i = tid; i < 64 * 64; i += 256) {
        int q = i >> 6, n = i & 63;
        const short* rowp = xbc + (tbase + q) * CONVD + DINNER;
        BsB[q * 72 + n] = rowp[n];
        CsB[q * 72 + n] = rowp[DSTATE + n];
    }
    {
        int h = h0 + wave;
        float Ah = -expf(A_log[h]);
        float v = dts[(tbase + lane) * NH + h] * Ah;
        #pragma unroll
        for (int off = 1; off < 64; off <<= 1) {
            float o = __shfl_up(v, off);
            if (lane >= off) v += o;
        }
        acsS[wave][lane] = v;
        acs_g[(((size_t)(b * NH + h)) * 64 + c) * 64 + lane] = v;
        float alast = __shfl(v, 63);
        dkS[wave][lane] = expf(alast - v);
        if (lane == 0) cdec[(b * NH + h) * 64 + c] = expf(alast);
    }
    __syncthreads();

    f32x4 macc[4];
    {
        bf16x8 aw0 = *(const bf16x8*)&CsB[(wave * 16 + lr) * 72 + lg * 8];
        bf16x8 aw1 = *(const bf16x8*)&CsB[(wave * 16 + lr) * 72 + 32 + lg * 8];
        #pragma unroll
        for (int ct = 0; ct < 4; ct++) {
            bf16x8 b0 = *(const bf16x8*)&BsB[(ct * 16 + lr) * 72 + lg * 8];
            bf16x8 b1 = *(const bf16x8*)&BsB[(ct * 16 + lr) * 72 + 32 + lg * 8];
            f32x4 z = {0.f, 0.f, 0.f, 0.f};
            z = __builtin_amdgcn_mfma_f32_16x16x32_bf16(aw0, b0, z, 0, 0, 0);
            z = __builtin_amdgcn_mfma_f32_16x16x32_bf16(aw1, b1, z, 0, 0, 0);
            macc[ct] = z;
        }
    }

    for (int hh = 0; hh < HGRP; hh++) {
        int h = h0 + hh;
        #pragma unroll
        for (int ct = 0; ct < 4; ct++) {
            int k = ct * 16 + lr;
            #pragma unroll
            for (int r = 0; r < 4; r++) {
                int q = wave * 16 + lg * 4 + r;
                float wv = 0.f;
                if (k <= q) wv = macc[ct][r] * expf(acsS[hh][q] - acsS[hh][k]);
                Wsh[q * 72 + k] = (short)f2bf(wv);
            }
        }
        for (int i = tid; i < 2048; i += 256) {
            int p = i & 31, k = i >> 5;
            float xv = bf2f(xbc[(tbase + k) * CONVD + h * HD + p]);
            XtS[p * 72 + k] = (short)f2bf(xv * dts[(tbase + k) * NH + h]);
        }
        for (int i = tid; i < 4096; i += 256) {
            int n = i & 63, k = i >> 6;
            BdS[n * 72 + k] = (short)f2bf(bf2f(BsB[k * 72 + n]) * dkS[hh][k]);
        }
        __syncthreads();
        {
            bf16x8 a0 = *(const bf16x8*)&Wsh[(wave * 16 + lr) * 72 + lg * 8];
            bf16x8 a1 = *(const bf16x8*)&Wsh[(wave * 16 + lr) * 72 + 32 + lg * 8];
            #pragma unroll
            for (int pt = 0; pt < 2; pt++) {
                bf16x8 b0 = *(const bf16x8*)&XtS[(pt * 16 + lr) * 72 + lg * 8];
                bf16x8 b1 = *(const bf16x8*)&XtS[(pt * 16 + lr) * 72 + 32 + lg * 8];
                f32x4 z = {0.f, 0.f, 0.f, 0.f};
                z = __builtin_amdgcn_mfma_f32_16x16x32_bf16(a0, b0, z, 0, 0, 0);
                z = __builtin_amdgcn_mfma_f32_16x16x32_bf16(a1, b1, z, 0, 0, 0);
                #pragma unroll
                for (int r = 0; r < 4; r++) {
                    int q = wave * 16 + lg * 4 + r;
                    Y[((tbase + q) * NH + h) * HD + pt * 16 + lr] = z[r];
                }
            }
        }
        {
            int ptile = wave & 1;
            bf16x8 a0 = *(const bf16x8*)&XtS[(ptile * 16 + lr) * 72 + lg * 8];
            bf16x8 a1 = *(const bf16x8*)&XtS[(ptile * 16 + lr) * 72 + 32 + lg * 8];
            #pragma unroll
            for (int j = 0; j < 2; j++) {
                int nt = (wave >> 1) * 2 + j;
                bf16x8 b0 = *(const bf16x8*)&BdS[(nt * 16 + lr) * 72 + lg * 8];
                bf16x8 b1 = *(const bf16x8*)&BdS[(nt * 16 + lr) * 72 + 32 + lg * 8];
                f32x4 z = {0.f, 0.f, 0.f, 0.f};
                z = __builtin_amdgcn_mfma_f32_16x16x32_bf16(a0, b0, z, 0, 0, 0);
                z = __builtin_amdgcn_mfma_f32_16x16x32_bf16(a1, b1, z, 0, 0, 0);
                #pragma unroll
                for (int r = 0; r < 4; r++) {
                    int p = ptile * 16 + lg * 4 + r;
                    states[((size_t)bc * NH + h) * 2048 + p * 64 + nt * 16 + lr] = z[r];
                }
            }
        }
        __syncthreads();
    }
}

// ---------------- K4b: sequential inter-chunk scan (1 elem/thread) ----------------
__global__ __launch_bounds__(256) void k_scan(float* __restrict__ states, const float* __restrict__ cdec) {
    int bid = blockIdx.x;           // BATCH*NH*8
    int bh = bid >> 3, seg = bid & 7;
    int b = bh >> 4, h = bh & 15;
    int off = seg * 256 + threadIdx.x;
    float prev = 0.f;
    for (int c = 0; c < 64; c++) {
        float dec = cdec[bh * 64 + c];
        size_t idx = ((((size_t)b * 64 + c) * NH) + h) * 2048 + off;
        float st = states[idx];
        states[idx] = prev;
        prev = fmaf(dec, prev, st);
    }
}

// ---------------- K4c: Y += exp(acs[q]) * (C . prev^T) + D*x, via MFMA ----------------
__global__ __launch_bounds__(256) void k_yoff(const short* __restrict__ xbc, const float* __restrict__ states,
                                              const float* __restrict__ acs_g, const float* __restrict__ D_skip,
                                              float* __restrict__ Y) {
    __shared__ short CsB[64 * 72];
    __shared__ short Pt[32 * 72];
    int tid = threadIdx.x;
    int bid = blockIdx.x;
    int hg = bid & 3;
    int bc = bid >> 2;
    int b = bc >> 6, c = bc & 63;
    size_t tbase = (size_t)b * SEQ + (size_t)c * 64;
    int wave = tid >> 6, lane = tid & 63;
    int lr = lane & 15, lg = lane >> 4;
    for (int i = tid; i < 64 * 64; i += 256) {
        int q = i >> 6, n = i & 63;
        CsB[q * 72 + n] = xbc[(tbase + q) * CONVD + DINNER + DSTATE + n];
    }
    for (int hh = 0; hh < HGRP; hh++) {
        int h = hg * HGRP + hh;
        size_t sbase = ((size_t)bc * NH + h) * 2048;
        for (int i = tid; i < 2048; i += 256)
            Pt[(i >> 6) * 72 + (i & 63)] = (short)f2bf(states[sbase + i]);
        __syncthreads();
        const float* arow = acs_g + (((size_t)(b * NH + h)) * 64 + c) * 64;
        float eq[4];
        #pragma unroll
        for (int r = 0; r < 4; r++) eq[r] = expf(arow[wave * 16 + lg * 4 + r]);
        float dsk = D_skip[h];
        bf16x8 a0 = *(const bf16x8*)&CsB[(wave * 16 + lr) * 72 + lg * 8];
        bf16x8 a1 = *(const bf16x8*)&CsB[(wave * 16 + lr) * 72 + 32 + lg * 8];
        #pragma unroll
        for (int pt = 0; pt < 2; pt++) {
            bf16x8 b0 = *(const bf16x8*)&Pt[(pt * 16 + lr) * 72 + lg * 8];
            bf16x8 b1 = *(const bf16x8*)&Pt[(pt * 16 + lr) * 72 + 32 + lg * 8];
            f32x4 z = {0.f, 0.f, 0.f, 0.f};
            z = __builtin_amdgcn_mfma_f32_16x16x32_bf16(a0, b0, z, 0, 0, 0);
            z = __builtin_amdgcn_mfma_f32_16x16x32_bf16(a1, b1, z, 0, 0, 0);
            #pragma unroll
            for (int r = 0; r < 4; r++) {
                int q = wave * 16 + lg * 4 + r;
                int p = pt * 16 + lr;
                size_t yi = ((tbase + q) * NH + h) * HD + p;
                float xv = bf2f(xbc[(tbase + q) * CONVD + h * HD + p]);
                Y[yi] += eq[r] * z[r] + dsk * xv;
            }
        }
        __syncthreads();
    }
}

// ---------------- gate: Yb = bf16( rmsnorm(Y * silu(z16), gw, 1e-5) ) ----------------
__global__ void k_gate(const float* __restrict__ Y, const short* __restrict__ z16,
                       const float* __restrict__ gw, short* __restrict__ Yb) {
    int t = blockIdx.x;
    int lane = threadIdx.x;  // 64
    const float* yr = Y + (size_t)t * DINNER + lane * 8;
    union { int4 v; short s[8]; } zu;
    zu.v = *(const int4*)(z16 + (size_t)t * DINNER + lane * 8);
    float4 y0 = *(const float4*)yr;
    float4 y1 = *(const float4*)(yr + 4);
    float yv[8] = {y0.x, y0.y, y0.z, y0.w, y1.x, y1.y, y1.z, y1.w};
    float g[8];
    float ss = 0.f;
    #pragma unroll
    for (int i = 0; i < 8; i++) {
        float zf = bf2f(zu.s[i]);
        g[i] = yv[i] * zf / (1.f + expf(-zf));
        ss += g[i] * g[i];
    }
    #pragma unroll
    for (int o = 32; o > 0; o >>= 1) ss += __shfl_down(ss, o);
    ss = __shfl(ss, 0);
    float rr = rsqrtf(ss * (1.0f / DINNER) + 1e-5f);
    const float* wr = gw + lane * 8;
    float4 w0 = *(const float4*)wr;
    float4 w1 = *(const float4*)(wr + 4);
    float wv[8] = {w0.x, w0.y, w0.z, w0.w, w1.x, w1.y, w1.z, w1.w};
    union { int4 v; unsigned short s[8]; } ou;
    #pragma unroll
    for (int i = 0; i < 8; i++) ou.s[i] = f2bf(g[i] * rr * wv[i]);
    *(int4*)(Yb + (size_t)t * DINNER + lane * 8) = ou.v;
}

extern "C" void kernel_launch(void* const* d_in, const int* in_sizes, int n_in,
                              void* d_out, int out_size, void* d_ws, size_t ws_size,
                              hipStream_t stream) {
    const int*   ids        = (const int*)d_in[0];
    const float* embed_w    = (const float*)d_in[1];
    const float* in_proj_w  = (const float*)d_in[2];
    const float* conv_w     = (const float*)d_in[3];
    const float* conv_b     = (const float*)d_in[4];
    const float* A_log      = (const float*)d_in[5];
    const float* D_skip     = (const float*)d_in[6];
    const float* dt_bias    = (const float*)d_in[7];
    const float* gate_w     = (const float*)d_in[8];
    const float* out_proj_w = (const float*)d_in[9];
    const float* norm_w     = (const float*)d_in[10];
    float* out = (float*)d_out;

    if (ws_size < WS_FLOATS * sizeof(float)) {
        k_diag<<<1, 64, 0, stream>>>(out, (float)(ws_size >> 20));
        return;
    }

    float* ws   = (float*)d_ws;
    short* u16  = (short*)(ws + U16_OFF);
    short* z16  = (short*)(ws + Z16_OFF);
    short* xbc  = (short*)(ws + XBC_OFF);
    float* dts  = ws + DTS_OFF;
    float* acs  = ws + ACS_OFF;
    float* cdec = ws + CDEC_OFF;
    short* Wp   = (short*)(ws + WP_OFF);
    short* Wo   = (short*)(ws + WO_OFF);
    short* We   = (short*)(ws + WE_OFF);
    float* st   = ws + UNION_OFF;
    short* Yb   = (short*)(ws + UNION_OFF);
    short* xf16 = (short*)(ws + UNION_OFF + XF_SUB);
    float* Y    = out;

    k_cvt<<<(NPAD * DMODEL + 255) / 256, 256, 0, stream>>>(in_proj_w, Wp, DPROJ * DMODEL, NPAD * DMODEL);
    k_cvt<<<(DMODEL * DINNER + 255) / 256, 256, 0, stream>>>(out_proj_w, Wo, DMODEL * DINNER, DMODEL * DINNER);
    k_cvt<<<(VOCAB * DMODEL + 255) / 256, 256, 0, stream>>>(embed_w, We, VOCAB * DMODEL, VOCAB * DMODEL);
    k_embed<<<TOK, 64, 0, stream>>>(ids, embed_w, norm_w, u16);
    k_gemm_mfma<0><<<dim3(NPAD / 128, TOK / 128), 256, 0, stream>>>(
        u16, Wp, DMODEL, nullptr, z16, xbc, dts, dt_bias, nullptr, nullptr, conv_w, conv_b);
    k_chunk<<<BATCH * 64 * 4, 256, 0, stream>>>(xbc, dts, A_log, Y, st, acs, cdec);
    k_scan<<<BATCH * NH * 8, 256, 0, stream>>>(st, cdec);
    k_yoff<<<BATCH * 64 * 4, 256, 0, stream>>>(xbc, st, acs, D_skip, Y);
    k_gate<<<TOK, 64, 0, stream>>>(Y, z16, gate_w, Yb);
    k_gemm_mfma<1><<<dim3(DMODEL / 128, TOK / 128), 256, 0, stream>>>(
        Yb, Wo, DINNER, nullptr, xf16, nullptr, nullptr, nullptr, ids, embed_w, nullptr, nullptr);
    k_gemm_mfma<2><<<dim3(VOCAB / 128, TOK / 128), 256, 0, stream>>>(
        xf16, We, DMODEL, out, nullptr, nullptr, nullptr, nullptr, nullptr, nullptr, nullptr, nullptr);
}

// Round 8
// 324.428 us; speedup vs baseline: 1.3215x; 1.3215x over previous
//
#include <hip/hip_runtime.h>
#include <cstdint>
#include <cstddef>

#define TOK    32768   // B*L
#define BATCH  8
#define SEQ    4096
#define DMODEL 256
#define DINNER 512
#define DSTATE 64
#define NH     16
#define HD     32
#define DPROJ  1168
#define NPAD   1280    // in_proj N padded to 10*128
#define CONVD  640
#define VOCAB  512
#define HGRP   4       // heads per chunk/yoff block
#define TS     132     // conv tile LDS stride (shorts)

typedef __attribute__((ext_vector_type(8))) short bf16x8;
typedef __attribute__((ext_vector_type(4))) float f32x4;

__device__ __forceinline__ unsigned short f2bf(float f) {
    unsigned u = __float_as_uint(f);
    u += 0x7fffu + ((u >> 16) & 1u);       // RNE
    return (unsigned short)(u >> 16);
}
__device__ __forceinline__ float bf2f(short s) {
    return __uint_as_float(((unsigned)(unsigned short)s) << 16);
}
__device__ __forceinline__ float sp(float v) { return v > 20.f ? v : log1pf(expf(v)); }

// async global->LDS, 16B per lane; dst must be wave-uniform base (linear lane fill)
__device__ __forceinline__ void gload16(const short* src, short* dst) {
    __builtin_amdgcn_global_load_lds((const __attribute__((address_space(1))) void*)src,
                                     (__attribute__((address_space(3))) void*)dst, 16, 0, 0);
}

// ---------------- ws layout (floats, all 16B aligned) ----------------
#define U16_OFF   0                                    // TOK*256 bf16
#define Z16_OFF   (U16_OFF  + (size_t)TOK*128)         // TOK*512 bf16
#define XBC_OFF   (Z16_OFF  + (size_t)TOK*256)         // TOK*640 bf16
#define DTS_OFF   (XBC_OFF  + (size_t)TOK*320)         // TOK*16 fp32
#define ACS_OFF   (DTS_OFF  + (size_t)TOK*16)
#define CDEC_OFF  (ACS_OFF  + (size_t)BATCH*NH*64*64)
#define WP_OFF    (CDEC_OFF + (size_t)BATCH*NH*64)
#define WO_OFF    (WP_OFF   + 163840)
#define WE_OFF    (WO_OFF   + 65536)
#define UNION_OFF (WE_OFF   + 65536)
// union: st fp32 8*64*16*2048 | Yb bf16 TOK*512 + xf16 bf16 TOK*256
#define UNION_FL  ((size_t)BATCH*64*NH*2048)
#define XF_SUB    ((size_t)TOK*256)
#define WS_FLOATS (UNION_OFF + UNION_FL)

__global__ void k_diag(float* out, float wsmb) {
    if (blockIdx.x == 0 && threadIdx.x == 0) out[0] = wsmb;
}

// ---------------- weight fp32 -> bf16 (+ zero pad) ----------------
__global__ void k_cvt(const float* __restrict__ s, short* __restrict__ d, int nsrc, int ntot) {
    int i = blockIdx.x * 256 + threadIdx.x;
    if (i < ntot) d[i] = (i < nsrc) ? (short)f2bf(s[i]) : (short)0;
}

// ---------------- embed gather + rmsnorm -> u16 (bf16) ----------------
__global__ void k_embed(const int* __restrict__ ids, const float* __restrict__ embed,
                        const float* __restrict__ norm_w, short* __restrict__ u16) {
    int t = blockIdx.x;
    int lane = threadIdx.x;   // 64
    int id = ids[t];
    float4 v = ((const float4*)(embed + (size_t)id * DMODEL))[lane];
    float ss = v.x*v.x + v.y*v.y + v.z*v.z + v.w*v.w;
    #pragma unroll
    for (int o = 32; o > 0; o >>= 1) ss += __shfl_down(ss, o);
    ss = __shfl(ss, 0);
    float r = rsqrtf(ss * (1.0f / DMODEL) + 1e-6f);
    float4 w = ((const float4*)norm_w)[lane];
    unsigned p0 = (unsigned)f2bf(v.x * r * w.x) | ((unsigned)f2bf(v.y * r * w.y) << 16);
    unsigned p1 = (unsigned)f2bf(v.z * r * w.z) | ((unsigned)f2bf(v.w * r * w.w) << 16);
    ((uint2*)(u16 + (size_t)t * DMODEL))[lane] = make_uint2(p0, p1);
}

// ---------------- bf16 MFMA GEMM, BK=64, global_load_lds double-buffer, swizzled LDS ----------------
// LDS swizzle (rule #21 both-sides): linear LDS dest, inverse-swizzled global SOURCE, swizzled ds_read.
// slot s of row r holds source k-chunk s^(r&7); read fetches chunk kb at slot kb^(r&7). Conflicts = 0 (R7).
// MODE 0: in_proj: cols<512 -> z16 ; 512..1151 -> fused conv+silu -> xbc (halo via MFMA) ; 1152.. -> dt
// MODE 1: out_proj: + embed[ids] residual -> xf16 (via z16 param)
// MODE 2: logits: fp32 -> outF
template<int MODE>
__global__ __launch_bounds__(256) void k_gemm_mfma(
    const short* __restrict__ A, const short* __restrict__ B, int K,
    float* __restrict__ outF, short* __restrict__ z16, short* __restrict__ xbc,
    float* __restrict__ dts, const float* __restrict__ dt_bias,
    const int* __restrict__ ids, const float* __restrict__ embed,
    const float* __restrict__ cw, const float* __restrict__ cb) {
    // [A buf0 | A buf1 | B buf0 | B buf1], each 128x64 shorts = 8192; conv Tile aliases front 17292
    __shared__ __align__(16) short SM[32768];
    int tid = threadIdx.x;
    int m0 = blockIdx.y << 7;
    int n0 = blockIdx.x << 7;
    int wave = tid >> 6, lane = tid & 63;
    int wm = wave >> 1, wn = wave & 1;
    int lr = lane & 15, lg = lane >> 4;
    const f32x4 zer = {0.f, 0.f, 0.f, 0.f};
    f32x4 acc[4][4];
    #pragma unroll
    for (int i = 0; i < 4; i++)
        #pragma unroll
        for (int j = 0; j < 4; j++) acc[i][j] = zer;

    const bool isXBC = (MODE == 0) && (n0 >= 512) && (n0 < 1152);
    const bool atStart = (m0 & (SEQ - 1)) == 0;
    const bool haloLane = isXBC && (wm == 0) && !atStart && (lr < 3);
    f32x4 hacc[4];
    #pragma unroll
    for (int j = 0; j < 4; j++) hacc[j] = zer;
    const bf16x8 hz = {0, 0, 0, 0, 0, 0, 0, 0};
    bf16x8 hc0 = hz, hc1 = hz, hn0 = hz, hn1 = hz;

    const int nK = K >> 6;
    const int srow = (wave * 4) * 8;           // this wave's first staged row (per j: +8)
    const int slo  = lane >> 3;                // row within 8-row group
    const int skb  = ((lane & 7) ^ slo) << 3;  // inverse-swizzled source k-chunk (shorts)

    // prologue: stage tile 0 into buf0, prefetch halo tile 0
    #pragma unroll
    for (int j = 0; j < 4; j++) {
        int row = srow + j * 8 + slo;
        gload16(A + (size_t)(m0 + row) * K + skb, SM + (wave * 4 + j) * 512);
        gload16(B + (size_t)(n0 + row) * K + skb, SM + 16384 + (wave * 4 + j) * 512);
    }
    if (haloLane) {
        hc0 = *(const bf16x8*)(A + (size_t)(m0 - 3 + lr) * K + lg * 8);
        hc1 = *(const bf16x8*)(A + (size_t)(m0 - 3 + lr) * K + 32 + lg * 8);
    }
    __syncthreads();   // drains vmcnt(0): tile 0 ready

    int buf = 0;
    for (int kt = 0; kt < nK; ++kt) {
        bool pre = (kt + 1 < nK);
        if (pre) {                              // stage next tile into other buffer
            int k0 = (kt + 1) << 6;
            int nb = (buf ^ 1) * 8192;
            #pragma unroll
            for (int j = 0; j < 4; j++) {
                int row = srow + j * 8 + slo;
                gload16(A + (size_t)(m0 + row) * K + k0 + skb, SM + nb + (wave * 4 + j) * 512);
                gload16(B + (size_t)(n0 + row) * K + k0 + skb, SM + 16384 + nb + (wave * 4 + j) * 512);
            }
            if (haloLane) {
                hn0 = *(const bf16x8*)(A + (size_t)(m0 - 3 + lr) * K + k0 + lg * 8);
                hn1 = *(const bf16x8*)(A + (size_t)(m0 - 3 + lr) * K + k0 + 32 + lg * 8);
            }
        }
        const short* CA = SM + buf * 8192;
        const short* CB = SM + 16384 + buf * 8192;
        #pragma unroll
        for (int kk = 0; kk < 2; kk++) {
            int sw = (((kk << 2) + lg) ^ (lr & 7)) << 3;
            bf16x8 af[4], bfr[4];
            #pragma unroll
            for (int mi = 0; mi < 4; mi++)
                af[mi] = *(const bf16x8*)&CA[(wm * 64 + mi * 16 + lr) * 64 + sw];
            #pragma unroll
            for (int ni = 0; ni < 4; ni++)
                bfr[ni] = *(const bf16x8*)&CB[(wn * 64 + ni * 16 + lr) * 64 + sw];
            #pragma unroll
            for (int mi = 0; mi < 4; mi++)
                #pragma unroll
                for (int ni = 0; ni < 4; ni++)
                    acc[mi][ni] = __builtin_amdgcn_mfma_f32_16x16x32_bf16(af[mi], bfr[ni], acc[mi][ni], 0, 0, 0);
            if (isXBC && wm == 0) {
                bf16x8 h = (kk == 0) ? hc0 : hc1;
                #pragma unroll
                for (int ni = 0; ni < 4; ni++)
                    hacc[ni] = __builtin_amdgcn_mfma_f32_16x16x32_bf16(h, bfr[ni], hacc[ni], 0, 0, 0);
            }
        }
        __syncthreads();   // vmcnt(0)+lgkmcnt(0)+barrier: next tile ready, this tile's reads retired
        buf ^= 1;
        hc0 = hn0; hc1 = hn1;
    }

    if (isXBC) {
        // ---- fused causal conv(k=4) + SiLU, sliding-window epilogue ----
        short* Tile = SM;   // [131][TS]: rows 0-2 = halo, 3+row = token m0+row
        #pragma unroll
        for (int mi = 0; mi < 4; mi++)
            #pragma unroll
            for (int ni = 0; ni < 4; ni++)
                #pragma unroll
                for (int r = 0; r < 4; r++) {
                    int row = wm * 64 + mi * 16 + lg * 4 + r;
                    int col = wn * 64 + ni * 16 + lr;
                    unsigned mv = f2bf(acc[mi][ni][r]);
                    unsigned ov = (unsigned)__shfl_xor((int)mv, 1);
                    if (!(lr & 1))
                        *(unsigned*)&Tile[(3 + row) * TS + col] = (mv & 0xffffu) | (ov << 16);
                }
        if (wm == 0 && lg == 0) {
            #pragma unroll
            for (int ni = 0; ni < 4; ni++)
                #pragma unroll
                for (int r = 0; r < 3; r++)
                    Tile[r * TS + wn * 64 + ni * 16 + lr] = (short)f2bf(hacc[ni][r]);
        }
        __syncthreads();
        int cp = tid & 63, rg = tid >> 6;
        int colb = cp * 2;
        int ch = (n0 - 512) + colb;
        float c0w0 = cw[ch * 4], c0w1 = cw[ch * 4 + 1], c0w2 = cw[ch * 4 + 2], c0w3 = cw[ch * 4 + 3];
        float c1w0 = cw[ch * 4 + 4], c1w1 = cw[ch * 4 + 5], c1w2 = cw[ch * 4 + 6], c1w3 = cw[ch * 4 + 7];
        float b0v = cb[ch], b1v = cb[ch + 1];
        int rbase = rg * 32;
        unsigned w0 = *(const unsigned*)&Tile[(rbase + 0) * TS + colb];
        unsigned w1 = *(const unsigned*)&Tile[(rbase + 1) * TS + colb];
        unsigned w2 = *(const unsigned*)&Tile[(rbase + 2) * TS + colb];
        for (int i = 0; i < 32; i++) {
            unsigned w3 = *(const unsigned*)&Tile[(rbase + i + 3) * TS + colb];
            float s0 = b0v, s1 = b1v;
            s0 = fmaf(bf2f((short)(w0 & 0xffffu)), c0w0, s0); s1 = fmaf(bf2f((short)(w0 >> 16)), c1w0, s1);
            s0 = fmaf(bf2f((short)(w1 & 0xffffu)), c0w1, s0); s1 = fmaf(bf2f((short)(w1 >> 16)), c1w1, s1);
            s0 = fmaf(bf2f((short)(w2 & 0xffffu)), c0w2, s0); s1 = fmaf(bf2f((short)(w2 >> 16)), c1w2, s1);
            s0 = fmaf(bf2f((short)(w3 & 0xffffu)), c0w3, s0); s1 = fmaf(bf2f((short)(w3 >> 16)), c1w3, s1);
            s0 = s0 / (1.f + expf(-s0));
            s1 = s1 / (1.f + expf(-s1));
            *(unsigned*)&xbc[(size_t)(m0 + rbase + i) * CONVD + ch] =
                (unsigned)f2bf(s0) | ((unsigned)f2bf(s1) << 16);
            w0 = w1; w1 = w2; w2 = w3;
        }
        return;
    }

    #pragma unroll
    for (int mi = 0; mi < 4; mi++) {
        #pragma unroll
        for (int r = 0; r < 4; r++) {
            int row = m0 + wm * 64 + mi * 16 + lg * 4 + r;
            int id = 0;
            if (MODE == 1) id = ids[row];
            #pragma unroll
            for (int ni = 0; ni < 4; ni++) {
                int col = n0 + wn * 64 + ni * 16 + lr;
                float v = acc[mi][ni][r];
                if (MODE == 0) {
                    if (n0 < 512) {
                        unsigned mv = f2bf(v);
                        unsigned ov = (unsigned)__shfl_xor((int)mv, 1);
                        if (!(lr & 1))
                            *(unsigned*)&z16[(size_t)row * DINNER + col] = (mv & 0xffffu) | (ov << 16);
                    } else if (wn == 0 && ni == 0) {   // dt cols 1152..1167
                        dts[(size_t)row * NH + lr] = sp(v + dt_bias[lr]);
                    }
                } else if (MODE == 1) {
                    float vo = __shfl_xor(v, 1);
                    if (!(lr & 1)) {
                        float2 res = *(const float2*)&embed[(size_t)id * DMODEL + col];
                        *(unsigned*)&z16[(size_t)row * DMODEL + col] =
                            (unsigned)f2bf(v + res.x) | ((unsigned)f2bf(vo + res.y) << 16);
                    }
                } else {
                    outF[(size_t)row * VOCAB + col] = v;
                }
            }
        }
    }
}

// ---------------- K4a: per-(b,c,headgroup): M via MFMA, Y_diag + states via MFMA ----------------
__global__ __launch_bounds__(256) void k_chunk(const short* __restrict__ xbc, const float* __restrict__ dts,
                                               const float* __restrict__ A_log,
                                               float* __restrict__ Y, float* __restrict__ states,
                                               float* __restrict__ acs_g, float* __restrict__ cdec) {
    __shared__ short CsB[64 * 72];   // C[q][n]
    __shared__ short BsB[64 * 72];   // B[k][n]
    __shared__ short Wsh[64 * 72];   // W[q][k] per head
    __shared__ short XtS[32 * 72];   // Xt[p][k] per head
    __shared__ short BdS[64 * 72];   // Bd[n][k] per head
    __shared__ float acsS[HGRP][64];
    __shared__ float dkS[HGRP][64];
    int tid = threadIdx.x;
    int bid = blockIdx.x;
    int hg = bid & 3;
    int bc = bid >> 2;
    int b = bc >> 6, c = bc & 63;
    int h0 = hg * HGRP;
    size_t tbase = (size_t)b * SEQ + (size_t)c * 64;
    int wave = tid >> 6, lane = tid & 63;
    int lr = lane & 15, lg = lane >> 4;

    for (int i = tid; i < 64 * 64; i += 256) {
        int q = i >> 6, n = i & 63;
        const short* rowp = xbc + (tbase + q) * CONVD + DINNER;
        BsB[q * 72 + n] = rowp[n];
        CsB[q * 72 + n] = rowp[DSTATE + n];
    }
    {
        int h = h0 + wave;
        float Ah = -expf(A_log[h]);
        float v = dts[(tbase + lane) * NH + h] * Ah;
        #pragma unroll
        for (int off = 1; off < 64; off <<= 1) {
            float o = __shfl_up(v, off);
            if (lane >= off) v += o;
        }
        acsS[wave][lane] = v;
        acs_g[(((size_t)(b * NH + h)) * 64 + c) * 64 + lane] = v;
        float alast = __shfl(v, 63);
        dkS[wave][lane] = expf(alast - v);
        if (lane == 0) cdec[(b * NH + h) * 64 + c] = expf(alast);
    }
    __syncthreads();

    f32x4 macc[4];
    {
        bf16x8 aw0 = *(const bf16x8*)&CsB[(wave * 16 + lr) * 72 + lg * 8];
        bf16x8 aw1 = *(const bf16x8*)&CsB[(wave * 16 + lr) * 72 + 32 + lg * 8];
        #pragma unroll
        for (int ct = 0; ct < 4; ct++) {
            bf16x8 b0 = *(const bf16x8*)&BsB[(ct * 16 + lr) * 72 + lg * 8];
            bf16x8 b1 = *(const bf16x8*)&BsB[(ct * 16 + lr) * 72 + 32 + lg * 8];
            f32x4 z = {0.f, 0.f, 0.f, 0.f};
            z = __builtin_amdgcn_mfma_f32_16x16x32_bf16(aw0, b0, z, 0, 0, 0);
            z = __builtin_amdgcn_mfma_f32_16x16x32_bf16(aw1, b1, z, 0, 0, 0);
            macc[ct] = z;
        }
    }

    for (int hh = 0; hh < HGRP; hh++) {
        int h = h0 + hh;
        #pragma unroll
        for (int ct = 0; ct < 4; ct++) {
            int k = ct * 16 + lr;
            #pragma unroll
            for (int r = 0; r < 4; r++) {
                int q = wave * 16 + lg * 4 + r;
                float wv = 0.f;
                if (k <= q) wv = macc[ct][r] * expf(acsS[hh][q] - acsS[hh][k]);
                Wsh[q * 72 + k] = (short)f2bf(wv);
            }
        }
        for (int i = tid; i < 2048; i += 256) {
            int p = i & 31, k = i >> 5;
            float xv = bf2f(xbc[(tbase + k) * CONVD + h * HD + p]);
            XtS[p * 72 + k] = (short)f2bf(xv * dts[(tbase + k) * NH + h]);
        }
        for (int i = tid; i < 4096; i += 256) {
            int n = i & 63, k = i >> 6;
            BdS[n * 72 + k] = (short)f2bf(bf2f(BsB[k * 72 + n]) * dkS[hh][k]);
        }
        __syncthreads();
        {
            bf16x8 a0 = *(const bf16x8*)&Wsh[(wave * 16 + lr) * 72 + lg * 8];
            bf16x8 a1 = *(const bf16x8*)&Wsh[(wave * 16 + lr) * 72 + 32 + lg * 8];
            #pragma unroll
            for (int pt = 0; pt < 2; pt++) {
                bf16x8 b0 = *(const bf16x8*)&XtS[(pt * 16 + lr) * 72 + lg * 8];
                bf16x8 b1 = *(const bf16x8*)&XtS[(pt * 16 + lr) * 72 + 32 + lg * 8];
                f32x4 z = {0.f, 0.f, 0.f, 0.f};
                z = __builtin_amdgcn_mfma_f32_16x16x32_bf16(a0, b0, z, 0, 0, 0);
                z = __builtin_amdgcn_mfma_f32_16x16x32_bf16(a1, b1, z, 0, 0, 0);
                #pragma unroll
                for (int r = 0; r < 4; r++) {
                    int q = wave * 16 + lg * 4 + r;
                    Y[((tbase + q) * NH + h) * HD + pt * 16 + lr] = z[r];
                }
            }
        }
        {
            int ptile = wave & 1;
            bf16x8 a0 = *(const bf16x8*)&XtS[(ptile * 16 + lr) * 72 + lg * 8];
            bf16x8 a1 = *(const bf16x8*)&XtS[(ptile * 16 + lr) * 72 + 32 + lg * 8];
            #pragma unroll
            for (int j = 0; j < 2; j++) {
                int nt = (wave >> 1) * 2 + j;
                bf16x8 b0 = *(const bf16x8*)&BdS[(nt * 16 + lr) * 72 + lg * 8];
                bf16x8 b1 = *(const bf16x8*)&BdS[(nt * 16 + lr) * 72 + 32 + lg * 8];
                f32x4 z = {0.f, 0.f, 0.f, 0.f};
                z = __builtin_amdgcn_mfma_f32_16x16x32_bf16(a0, b0, z, 0, 0, 0);
                z = __builtin_amdgcn_mfma_f32_16x16x32_bf16(a1, b1, z, 0, 0, 0);
                #pragma unroll
                for (int r = 0; r < 4; r++) {
                    int p = ptile * 16 + lg * 4 + r;
                    states[((size_t)bc * NH + h) * 2048 + p * 64 + nt * 16 + lr] = z[r];
                }
            }
        }
        __syncthreads();
    }
}

// ---------------- K4b: sequential inter-chunk scan (1 elem/thread) ----------------
__global__ __launch_bounds__(256) void k_scan(float* __restrict__ states, const float* __restrict__ cdec) {
    int bid = blockIdx.x;           // BATCH*NH*8
    int bh = bid >> 3, seg = bid & 7;
    int b = bh >> 4, h = bh & 15;
    int off = seg * 256 + threadIdx.x;
    float prev = 0.f;
    for (int c = 0; c < 64; c++) {
        float dec = cdec[bh * 64 + c];
        size_t idx = ((((size_t)b * 64 + c) * NH) + h) * 2048 + off;
        float st = states[idx];
        states[idx] = prev;
        prev = fmaf(dec, prev, st);
    }
}

// ---------------- K4c: Y += exp(acs[q]) * (C . prev^T) + D*x, via MFMA ----------------
__global__ __launch_bounds__(256) void k_yoff(const short* __restrict__ xbc, const float* __restrict__ states,
                                              const float* __restrict__ acs_g, const float* __restrict__ D_skip,
                                              float* __restrict__ Y) {
    __shared__ short CsB[64 * 72];
    __shared__ short Pt[32 * 72];
    int tid = threadIdx.x;
    int bid = blockIdx.x;
    int hg = bid & 3;
    int bc = bid >> 2;
    int b = bc >> 6, c = bc & 63;
    size_t tbase = (size_t)b * SEQ + (size_t)c * 64;
    int wave = tid >> 6, lane = tid & 63;
    int lr = lane & 15, lg = lane >> 4;
    for (int i = tid; i < 64 * 64; i += 256) {
        int q = i >> 6, n = i & 63;
        CsB[q * 72 + n] = xbc[(tbase + q) * CONVD + DINNER + DSTATE + n];
    }
    for (int hh = 0; hh < HGRP; hh++) {
        int h = hg * HGRP + hh;
        size_t sbase = ((size_t)bc * NH + h) * 2048;
        for (int i = tid; i < 2048; i += 256)
            Pt[(i >> 6) * 72 + (i & 63)] = (short)f2bf(states[sbase + i]);
        __syncthreads();
        const float* arow = acs_g + (((size_t)(b * NH + h)) * 64 + c) * 64;
        float eq[4];
        #pragma unroll
        for (int r = 0; r < 4; r++) eq[r] = expf(arow[wave * 16 + lg * 4 + r]);
        float dsk = D_skip[h];
        bf16x8 a0 = *(const bf16x8*)&CsB[(wave * 16 + lr) * 72 + lg * 8];
        bf16x8 a1 = *(const bf16x8*)&CsB[(wave * 16 + lr) * 72 + 32 + lg * 8];
        #pragma unroll
        for (int pt = 0; pt < 2; pt++) {
            bf16x8 b0 = *(const bf16x8*)&Pt[(pt * 16 + lr) * 72 + lg * 8];
            bf16x8 b1 = *(const bf16x8*)&Pt[(pt * 16 + lr) * 72 + 32 + lg * 8];
            f32x4 z = {0.f, 0.f, 0.f, 0.f};
            z = __builtin_amdgcn_mfma_f32_16x16x32_bf16(a0, b0, z, 0, 0, 0);
            z = __builtin_amdgcn_mfma_f32_16x16x32_bf16(a1, b1, z, 0, 0, 0);
            #pragma unroll
            for (int r = 0; r < 4; r++) {
                int q = wave * 16 + lg * 4 + r;
                int p = pt * 16 + lr;
                size_t yi = ((tbase + q) * NH + h) * HD + p;
                float xv = bf2f(xbc[(tbase + q) * CONVD + h * HD + p]);
                Y[yi] += eq[r] * z[r] + dsk * xv;
            }
        }
        __syncthreads();
    }
}

// ---------------- gate: Yb = bf16( rmsnorm(Y * silu(z16), gw, 1e-5) ) ----------------
__global__ void k_gate(const float* __restrict__ Y, const short* __restrict__ z16,
                       const float* __restrict__ gw, short* __restrict__ Yb) {
    int t = blockIdx.x;
    int lane = threadIdx.x;  // 64
    const float* yr = Y + (size_t)t * DINNER + lane * 8;
    union { int4 v; short s[8]; } zu;
    zu.v = *(const int4*)(z16 + (size_t)t * DINNER + lane * 8);
    float4 y0 = *(const float4*)yr;
    float4 y1 = *(const float4*)(yr + 4);
    float yv[8] = {y0.x, y0.y, y0.z, y0.w, y1.x, y1.y, y1.z, y1.w};
    float g[8];
    float ss = 0.f;
    #pragma unroll
    for (int i = 0; i < 8; i++) {
        float zf = bf2f(zu.s[i]);
        g[i] = yv[i] * zf / (1.f + expf(-zf));
        ss += g[i] * g[i];
    }
    #pragma unroll
    for (int o = 32; o > 0; o >>= 1) ss += __shfl_down(ss, o);
    ss = __shfl(ss, 0);
    float rr = rsqrtf(ss * (1.0f / DINNER) + 1e-5f);
    const float* wr = gw + lane * 8;
    float4 w0 = *(const float4*)wr;
    float4 w1 = *(const float4*)(wr + 4);
    float wv[8] = {w0.x, w0.y, w0.z, w0.w, w1.x, w1.y, w1.z, w1.w};
    union { int4 v; unsigned short s[8]; } ou;
    #pragma unroll
    for (int i = 0; i < 8; i++) ou.s[i] = f2bf(g[i] * rr * wv[i]);
    *(int4*)(Yb + (size_t)t * DINNER + lane * 8) = ou.v;
}

extern "C" void kernel_launch(void* const* d_in, const int* in_sizes, int n_in,
                              void* d_out, int out_size, void* d_ws, size_t ws_size,
                              hipStream_t stream) {
    const int*   ids        = (const int*)d_in[0];
    const float* embed_w    = (const float*)d_in[1];
    const float* in_proj_w  = (const float*)d_in[2];
    const float* conv_w     = (const float*)d_in[3];
    const float* conv_b     = (const float*)d_in[4];
    const float* A_log      = (const float*)d_in[5];
    const float* D_skip     = (const float*)d_in[6];
    const float* dt_bias    = (const float*)d_in[7];
    const float* gate_w     = (const float*)d_in[8];
    const float* out_proj_w = (const float*)d_in[9];
    const float* norm_w     = (const float*)d_in[10];
    float* out = (float*)d_out;

    if (ws_size < WS_FLOATS * sizeof(float)) {
        k_diag<<<1, 64, 0, stream>>>(out, (float)(ws_size >> 20));
        return;
    }

    float* ws   = (float*)d_ws;
    short* u16  = (short*)(ws + U16_OFF);
    short* z16  = (short*)(ws + Z16_OFF);
    short* xbc  = (short*)(ws + XBC_OFF);
    float* dts  = ws + DTS_OFF;
    float* acs  = ws + ACS_OFF;
    float* cdec = ws + CDEC_OFF;
    short* Wp   = (short*)(ws + WP_OFF);
    short* Wo   = (short*)(ws + WO_OFF);
    short* We   = (short*)(ws + WE_OFF);
    float* st   = ws + UNION_OFF;
    short* Yb   = (short*)(ws + UNION_OFF);
    short* xf16 = (short*)(ws + UNION_OFF + XF_SUB);
    float* Y    = out;

    k_cvt<<<(NPAD * DMODEL + 255) / 256, 256, 0, stream>>>(in_proj_w, Wp, DPROJ * DMODEL, NPAD * DMODEL);
    k_cvt<<<(DMODEL * DINNER + 255) / 256, 256, 0, stream>>>(out_proj_w, Wo, DMODEL * DINNER, DMODEL * DINNER);
    k_cvt<<<(VOCAB * DMODEL + 255) / 256, 256, 0, stream>>>(embed_w, We, VOCAB * DMODEL, VOCAB * DMODEL);
    k_embed<<<TOK, 64, 0, stream>>>(ids, embed_w, norm_w, u16);
    k_gemm_mfma<0><<<dim3(NPAD / 128, TOK / 128), 256, 0, stream>>>(
        u16, Wp, DMODEL, nullptr, z16, xbc, dts, dt_bias, nullptr, nullptr, conv_w, conv_b);
    k_chunk<<<BATCH * 64 * 4, 256, 0, stream>>>(xbc, dts, A_log, Y, st, acs, cdec);
    k_scan<<<BATCH * NH * 8, 256, 0, stream>>>(st, cdec);
    k_yoff<<<BATCH * 64 * 4, 256, 0, stream>>>(xbc, st, acs, D_skip, Y);
    k_gate<<<TOK, 64, 0, stream>>>(Y, z16, gate_w, Yb);
    k_gemm_mfma<1><<<dim3(DMODEL / 128, TOK / 128), 256, 0, stream>>>(
        Yb, Wo, DINNER, nullptr, xf16, nullptr, nullptr, nullptr, ids, embed_w, nullptr, nullptr);
    k_gemm_mfma<2><<<dim3(VOCAB / 128, TOK / 128), 256, 0, stream>>>(
        xf16, We, DMODEL, out, nullptr, nullptr, nullptr, nullptr, nullptr, nullptr, nullptr, nullptr);
}

// Round 9
// 296.058 us; speedup vs baseline: 1.4481x; 1.0958x over previous
//
#include <hip/hip_runtime.h>
#include <cstdint>
#include <cstddef>

#define TOK    32768   // B*L
#define BATCH  8
#define SEQ    4096
#define DMODEL 256
#define DINNER 512
#define DSTATE 64
#define NH     16
#define HD     32
#define DPROJ  1168
#define NPAD   1280    // in_proj N padded to 10*128
#define CONVD  640
#define VOCAB  512
#define HGRP   4       // heads per chunk/yoff block
#define TS     132     // conv tile LDS stride (shorts)

typedef __attribute__((ext_vector_type(8))) short bf16x8;
typedef __attribute__((ext_vector_type(4))) float f32x4;

__device__ __forceinline__ unsigned short f2bf(float f) {
    unsigned u = __float_as_uint(f);
    u += 0x7fffu + ((u >> 16) & 1u);       // RNE
    return (unsigned short)(u >> 16);
}
__device__ __forceinline__ float bf2f(short s) {
    return __uint_as_float(((unsigned)(unsigned short)s) << 16);
}
// pack two f32 -> two bf16 (RNE) in one instruction
__device__ __forceinline__ unsigned cvtpk(float lo, float hi) {
    unsigned r;
    asm("v_cvt_pk_bf16_f32 %0, %1, %2" : "=v"(r) : "v"(lo), "v"(hi));
    return r;
}
__device__ __forceinline__ float fsilu(float s) {
    return s * __builtin_amdgcn_rcpf(1.f + __expf(-s));
}
__device__ __forceinline__ float sp(float v) {
    return v > 20.f ? v : __logf(1.f + __expf(v));
}

// async global->LDS, 16B per lane; dst must be wave-uniform base (linear lane fill)
__device__ __forceinline__ void gload16(const short* src, short* dst) {
    __builtin_amdgcn_global_load_lds((const __attribute__((address_space(1))) void*)src,
                                     (__attribute__((address_space(3))) void*)dst, 16, 0, 0);
}

// ---------------- ws layout (floats, all 16B aligned) ----------------
#define U16_OFF   0                                    // TOK*256 bf16
#define Z16_OFF   (U16_OFF  + (size_t)TOK*128)         // TOK*512 bf16
#define XBC_OFF   (Z16_OFF  + (size_t)TOK*256)         // TOK*640 bf16
#define DTS_OFF   (XBC_OFF  + (size_t)TOK*320)         // TOK*16 fp32
#define ACS_OFF   (DTS_OFF  + (size_t)TOK*16)
#define CDEC_OFF  (ACS_OFF  + (size_t)BATCH*NH*64*64)
#define WP_OFF    (CDEC_OFF + (size_t)BATCH*NH*64)
#define WO_OFF    (WP_OFF   + 163840)
#define WE_OFF    (WO_OFF   + 65536)
#define UNION_OFF (WE_OFF   + 65536)
// union: st fp32 8*64*16*2048 | Yb bf16 TOK*512 + xf16 bf16 TOK*256
#define UNION_FL  ((size_t)BATCH*64*NH*2048)
#define XF_SUB    ((size_t)TOK*256)
#define WS_FLOATS (UNION_OFF + UNION_FL)

__global__ void k_diag(float* out, float wsmb) {
    if (blockIdx.x == 0 && threadIdx.x == 0) out[0] = wsmb;
}

// ---------------- weight fp32 -> bf16 (+ zero pad) ----------------
__global__ void k_cvt(const float* __restrict__ s, short* __restrict__ d, int nsrc, int ntot) {
    int i = blockIdx.x * 256 + threadIdx.x;
    if (i < ntot) d[i] = (i < nsrc) ? (short)f2bf(s[i]) : (short)0;
}

// ---------------- embed gather + rmsnorm -> u16 (bf16) ----------------
__global__ void k_embed(const int* __restrict__ ids, const float* __restrict__ embed,
                        const float* __restrict__ norm_w, short* __restrict__ u16) {
    int t = blockIdx.x;
    int lane = threadIdx.x;   // 64
    int id = ids[t];
    float4 v = ((const float4*)(embed + (size_t)id * DMODEL))[lane];
    float ss = v.x*v.x + v.y*v.y + v.z*v.z + v.w*v.w;
    #pragma unroll
    for (int o = 32; o > 0; o >>= 1) ss += __shfl_down(ss, o);
    ss = __shfl(ss, 0);
    float r = rsqrtf(ss * (1.0f / DMODEL) + 1e-6f);
    float4 w = ((const float4*)norm_w)[lane];
    unsigned p0 = cvtpk(v.x * r * w.x, v.y * r * w.y);
    unsigned p1 = cvtpk(v.z * r * w.z, v.w * r * w.w);
    ((uint2*)(u16 + (size_t)t * DMODEL))[lane] = make_uint2(p0, p1);
}

// ---------------- bf16 MFMA GEMM, BK=64, single-buffer gload_lds, swizzled LDS ----------------
// LDS swizzle (rule #21 both-sides): linear LDS dest, inverse-swizzled global SOURCE, swizzled ds_read.
// MODE 0: in_proj: cols<512 -> z16 ; 512..1151 -> fused conv+silu -> xbc (halo via MFMA) ; 1152.. -> dt
// MODE 1: out_proj: + embed[ids] residual -> xf16 (via z16 param)
// MODE 2: logits: fp32 -> outF
template<int MODE>
__global__ __launch_bounds__(256) void k_gemm_mfma(
    const short* __restrict__ A, const short* __restrict__ B, int K,
    float* __restrict__ outF, short* __restrict__ z16, short* __restrict__ xbc,
    float* __restrict__ dts, const float* __restrict__ dt_bias,
    const int* __restrict__ ids, const float* __restrict__ embed,
    const float* __restrict__ cw, const float* __restrict__ cb) {
    // As (8192 shorts) | Bs (8192 shorts); MODE 0 also aliases conv Tile [131][TS]
    __shared__ __align__(16) short SM[MODE == 0 ? (131 * TS) : 16384];
    int tid = threadIdx.x;
    int m0 = blockIdx.y << 7;
    int n0 = blockIdx.x << 7;
    int wave = tid >> 6, lane = tid & 63;
    int wm = wave >> 1, wn = wave & 1;
    int lr = lane & 15, lg = lane >> 4;
    const f32x4 zer = {0.f, 0.f, 0.f, 0.f};
    f32x4 acc[4][4];
    #pragma unroll
    for (int i = 0; i < 4; i++)
        #pragma unroll
        for (int j = 0; j < 4; j++) acc[i][j] = zer;

    const bool isXBC = (MODE == 0) && (n0 >= 512) && (n0 < 1152);
    const bool atStart = (m0 & (SEQ - 1)) == 0;
    const bool haloLane = isXBC && (wm == 0) && !atStart && (lr < 3);
    f32x4 hacc[4];
    #pragma unroll
    for (int j = 0; j < 4; j++) hacc[j] = zer;
    const bf16x8 hz = {0, 0, 0, 0, 0, 0, 0, 0};
    bf16x8 hc0 = hz, hc1 = hz;

    const int nK = K >> 6;
    const int slo = lane >> 3;                 // row within 8-row group
    const int skb = ((lane & 7) ^ slo) << 3;   // inverse-swizzled source k-chunk (shorts)

    // stage tile 0
    {
        #pragma unroll
        for (int j = 0; j < 4; j++) {
            int row = wave * 32 + j * 8 + slo;
            gload16(A + (size_t)(m0 + row) * K + skb, SM + (wave * 4 + j) * 512);
            gload16(B + (size_t)(n0 + row) * K + skb, SM + 8192 + (wave * 4 + j) * 512);
        }
        if (haloLane) {
            hc0 = *(const bf16x8*)(A + (size_t)(m0 - 3 + lr) * K + lg * 8);
            hc1 = *(const bf16x8*)(A + (size_t)(m0 - 3 + lr) * K + 32 + lg * 8);
        }
    }

    for (int kt = 0; kt < nK; ++kt) {
        __syncthreads();   // drains vmcnt(0): tile kt (and halo regs) ready
        #pragma unroll
        for (int kk = 0; kk < 2; kk++) {
            int sw = (((kk << 2) + lg) ^ (lr & 7)) << 3;
            bf16x8 af[4], bfr[4];
            #pragma unroll
            for (int mi = 0; mi < 4; mi++)
                af[mi] = *(const bf16x8*)&SM[(wm * 64 + mi * 16 + lr) * 64 + sw];
            #pragma unroll
            for (int ni = 0; ni < 4; ni++)
                bfr[ni] = *(const bf16x8*)&SM[8192 + (wn * 64 + ni * 16 + lr) * 64 + sw];
            #pragma unroll
            for (int mi = 0; mi < 4; mi++)
                #pragma unroll
                for (int ni = 0; ni < 4; ni++)
                    acc[mi][ni] = __builtin_amdgcn_mfma_f32_16x16x32_bf16(af[mi], bfr[ni], acc[mi][ni], 0, 0, 0);
            if (isXBC && wm == 0) {
                bf16x8 h = (kk == 0) ? hc0 : hc1;
                #pragma unroll
                for (int ni = 0; ni < 4; ni++)
                    hacc[ni] = __builtin_amdgcn_mfma_f32_16x16x32_bf16(h, bfr[ni], hacc[ni], 0, 0, 0);
            }
        }
        if (kt + 1 < nK) {
            __syncthreads();   // all reads of tile kt retired
            int k0 = (kt + 1) << 6;
            #pragma unroll
            for (int j = 0; j < 4; j++) {
                int row = wave * 32 + j * 8 + slo;
                gload16(A + (size_t)(m0 + row) * K + k0 + skb, SM + (wave * 4 + j) * 512);
                gload16(B + (size_t)(n0 + row) * K + k0 + skb, SM + 8192 + (wave * 4 + j) * 512);
            }
            if (haloLane) {
                hc0 = *(const bf16x8*)(A + (size_t)(m0 - 3 + lr) * K + k0 + lg * 8);
                hc1 = *(const bf16x8*)(A + (size_t)(m0 - 3 + lr) * K + k0 + 32 + lg * 8);
            }
        }
    }

    if (isXBC) {
        // ---- fused causal conv(k=4) + SiLU, sliding-window epilogue ----
        short* Tile = SM;   // [131][TS]: rows 0-2 = halo, 3+row = token m0+row
        __syncthreads();    // last tile's ds_reads done before aliasing
        #pragma unroll
        for (int mi = 0; mi < 4; mi++)
            #pragma unroll
            for (int ni = 0; ni < 4; ni++)
                #pragma unroll
                for (int r = 0; r < 4; r++) {
                    int row = wm * 64 + mi * 16 + lg * 4 + r;
                    int col = wn * 64 + ni * 16 + lr;
                    float v = acc[mi][ni][r];
                    float vo = __shfl_xor(v, 1);
                    if (!(lr & 1))
                        *(unsigned*)&Tile[(3 + row) * TS + col] = cvtpk(v, vo);
                }
        if (wm == 0 && lg == 0) {
            #pragma unroll
            for (int ni = 0; ni < 4; ni++)
                #pragma unroll
                for (int r = 0; r < 3; r++)
                    Tile[r * TS + wn * 64 + ni * 16 + lr] = (short)f2bf(hacc[ni][r]);
        }
        __syncthreads();
        int cp = tid & 63, rg = tid >> 6;
        int colb = cp * 2;
        int ch = (n0 - 512) + colb;
        float c0w0 = cw[ch * 4], c0w1 = cw[ch * 4 + 1], c0w2 = cw[ch * 4 + 2], c0w3 = cw[ch * 4 + 3];
        float c1w0 = cw[ch * 4 + 4], c1w1 = cw[ch * 4 + 5], c1w2 = cw[ch * 4 + 6], c1w3 = cw[ch * 4 + 7];
        float b0v = cb[ch], b1v = cb[ch + 1];
        int rbase = rg * 32;
        unsigned w0 = *(const unsigned*)&Tile[(rbase + 0) * TS + colb];
        unsigned w1 = *(const unsigned*)&Tile[(rbase + 1) * TS + colb];
        unsigned w2 = *(const unsigned*)&Tile[(rbase + 2) * TS + colb];
        for (int i = 0; i < 32; i++) {
            unsigned w3 = *(const unsigned*)&Tile[(rbase + i + 3) * TS + colb];
            float s0 = b0v, s1 = b1v;
            s0 = fmaf(bf2f((short)(w0 & 0xffffu)), c0w0, s0); s1 = fmaf(bf2f((short)(w0 >> 16)), c1w0, s1);
            s0 = fmaf(bf2f((short)(w1 & 0xffffu)), c0w1, s0); s1 = fmaf(bf2f((short)(w1 >> 16)), c1w1, s1);
            s0 = fmaf(bf2f((short)(w2 & 0xffffu)), c0w2, s0); s1 = fmaf(bf2f((short)(w2 >> 16)), c1w2, s1);
            s0 = fmaf(bf2f((short)(w3 & 0xffffu)), c0w3, s0); s1 = fmaf(bf2f((short)(w3 >> 16)), c1w3, s1);
            s0 = fsilu(s0);
            s1 = fsilu(s1);
            *(unsigned*)&xbc[(size_t)(m0 + rbase + i) * CONVD + ch] = cvtpk(s0, s1);
            w0 = w1; w1 = w2; w2 = w3;
        }
        return;
    }

    #pragma unroll
    for (int mi = 0; mi < 4; mi++) {
        #pragma unroll
        for (int r = 0; r < 4; r++) {
            int row = m0 + wm * 64 + mi * 16 + lg * 4 + r;
            int id = 0;
            if (MODE == 1) id = ids[row];
            #pragma unroll
            for (int ni = 0; ni < 4; ni++) {
                int col = n0 + wn * 64 + ni * 16 + lr;
                float v = acc[mi][ni][r];
                if (MODE == 0) {
                    if (n0 < 512) {
                        float vo = __shfl_xor(v, 1);
                        if (!(lr & 1))
                            *(unsigned*)&z16[(size_t)row * DINNER + col] = cvtpk(v, vo);
                    } else if (wn == 0 && ni == 0) {   // dt cols 1152..1167
                        dts[(size_t)row * NH + lr] = sp(v + dt_bias[lr]);
                    }
                } else if (MODE == 1) {
                    float vo = __shfl_xor(v, 1);
                    if (!(lr & 1)) {
                        float2 res = *(const float2*)&embed[(size_t)id * DMODEL + col];
                        *(unsigned*)&z16[(size_t)row * DMODEL + col] = cvtpk(v + res.x, vo + res.y);
                    }
                } else {
                    outF[(size_t)row * VOCAB + col] = v;
                }
            }
        }
    }
}

// ---------------- K4a: per-(b,c,headgroup): M via MFMA, Y_diag + states via MFMA ----------------
__global__ __launch_bounds__(256) void k_chunk(const short* __restrict__ xbc, const float* __restrict__ dts,
                                               const float* __restrict__ A_log,
                                               float* __restrict__ Y, float* __restrict__ states,
                                               float* __restrict__ acs_g, float* __restrict__ cdec) {
    __shared__ short CsB[64 * 72];   // C[q][n]
    __shared__ short BsB[64 * 72];   // B[k][n]
    __shared__ short Wsh[64 * 72];   // W[q][k] per head
    __shared__ short XtS[32 * 72];   // Xt[p][k] per head
    __shared__ short BdS[64 * 72];   // Bd[n][k] per head
    __shared__ float acsS[HGRP][64];
    __shared__ float dkS[HGRP][64];
    int tid = threadIdx.x;
    int bid = blockIdx.x;
    int hg = bid & 3;
    int bc = bid >> 2;
    int b = bc >> 6, c = bc & 63;
    int h0 = hg * HGRP;
    size_t tbase = (size_t)b * SEQ + (size_t)c * 64;
    int wave = tid >> 6, lane = tid & 63;
    int lr = lane & 15, lg = lane >> 4;

    for (int i = tid; i < 64 * 64; i += 256) {
        int q = i >> 6, n = i & 63;
        const short* rowp = xbc + (tbase + q) * CONVD + DINNER;
        BsB[q * 72 + n] = rowp[n];
        CsB[q * 72 + n] = rowp[DSTATE + n];
    }
    {
        int h = h0 + wave;
        float Ah = -__expf(A_log[h]);
        float v = dts[(tbase + lane) * NH + h] * Ah;
        #pragma unroll
        for (int off = 1; off < 64; off <<= 1) {
            float o = __shfl_up(v, off);
            if (lane >= off) v += o;
        }
        acsS[wave][lane] = v;
        acs_g[(((size_t)(b * NH + h)) * 64 + c) * 64 + lane] = v;
        float alast = __shfl(v, 63);
        dkS[wave][lane] = __expf(alast - v);
        if (lane == 0) cdec[(b * NH + h) * 64 + c] = __expf(alast);
    }
    __syncthreads();

    f32x4 macc[4];
    {
        bf16x8 aw0 = *(const bf16x8*)&CsB[(wave * 16 + lr) * 72 + lg * 8];
        bf16x8 aw1 = *(const bf16x8*)&CsB[(wave * 16 + lr) * 72 + 32 + lg * 8];
        #pragma unroll
        for (int ct = 0; ct < 4; ct++) {
            bf16x8 b0 = *(const bf16x8*)&BsB[(ct * 16 + lr) * 72 + lg * 8];
            bf16x8 b1 = *(const bf16x8*)&BsB[(ct * 16 + lr) * 72 + 32 + lg * 8];
            f32x4 z = {0.f, 0.f, 0.f, 0.f};
            z = __builtin_amdgcn_mfma_f32_16x16x32_bf16(aw0, b0, z, 0, 0, 0);
            z = __builtin_amdgcn_mfma_f32_16x16x32_bf16(aw1, b1, z, 0, 0, 0);
            macc[ct] = z;
        }
    }

    for (int hh = 0; hh < HGRP; hh++) {
        int h = h0 + hh;
        #pragma unroll
        for (int ct = 0; ct < 4; ct++) {
            int k = ct * 16 + lr;
            #pragma unroll
            for (int r = 0; r < 4; r++) {
                int q = wave * 16 + lg * 4 + r;
                float wv = 0.f;
                if (k <= q) wv = macc[ct][r] * __expf(acsS[hh][q] - acsS[hh][k]);
                float wo = __shfl_xor(wv, 1);
                if (!(lr & 1))
                    *(unsigned*)&Wsh[q * 72 + k] = cvtpk(wv, wo);
            }
        }
        for (int i = tid; i < 2048; i += 256) {
            int p = i & 31, k = i >> 5;
            float xv = bf2f(xbc[(tbase + k) * CONVD + h * HD + p]);
            XtS[p * 72 + k] = (short)f2bf(xv * dts[(tbase + k) * NH + h]);
        }
        for (int i = tid; i < 4096; i += 256) {
            int n = i & 63, k = i >> 6;
            BdS[n * 72 + k] = (short)f2bf(bf2f(BsB[k * 72 + n]) * dkS[hh][k]);
        }
        __syncthreads();
        {
            bf16x8 a0 = *(const bf16x8*)&Wsh[(wave * 16 + lr) * 72 + lg * 8];
            bf16x8 a1 = *(const bf16x8*)&Wsh[(wave * 16 + lr) * 72 + 32 + lg * 8];
            #pragma unroll
            for (int pt = 0; pt < 2; pt++) {
                bf16x8 b0 = *(const bf16x8*)&XtS[(pt * 16 + lr) * 72 + lg * 8];
                bf16x8 b1 = *(const bf16x8*)&XtS[(pt * 16 + lr) * 72 + 32 + lg * 8];
                f32x4 z = {0.f, 0.f, 0.f, 0.f};
                z = __builtin_amdgcn_mfma_f32_16x16x32_bf16(a0, b0, z, 0, 0, 0);
                z = __builtin_amdgcn_mfma_f32_16x16x32_bf16(a1, b1, z, 0, 0, 0);
                #pragma unroll
                for (int r = 0; r < 4; r++) {
                    int q = wave * 16 + lg * 4 + r;
                    Y[((tbase + q) * NH + h) * HD + pt * 16 + lr] = z[r];
                }
            }
        }
        {
            int ptile = wave & 1;
            bf16x8 a0 = *(const bf16x8*)&XtS[(ptile * 16 + lr) * 72 + lg * 8];
            bf16x8 a1 = *(const bf16x8*)&XtS[(ptile * 16 + lr) * 72 + 32 + lg * 8];
            #pragma unroll
            for (int j = 0; j < 2; j++) {
                int nt = (wave >> 1) * 2 + j;
                bf16x8 b0 = *(const bf16x8*)&BdS[(nt * 16 + lr) * 72 + lg * 8];
                bf16x8 b1 = *(const bf16x8*)&BdS[(nt * 16 + lr) * 72 + 32 + lg * 8];
                f32x4 z = {0.f, 0.f, 0.f, 0.f};
                z = __builtin_amdgcn_mfma_f32_16x16x32_bf16(a0, b0, z, 0, 0, 0);
                z = __builtin_amdgcn_mfma_f32_16x16x32_bf16(a1, b1, z, 0, 0, 0);
                #pragma unroll
                for (int r = 0; r < 4; r++) {
                    int p = ptile * 16 + lg * 4 + r;
                    states[((size_t)bc * NH + h) * 2048 + p * 64 + nt * 16 + lr] = z[r];
                }
            }
        }
        __syncthreads();
    }
}

// ---------------- K4b: sequential inter-chunk scan (1 elem/thread) ----------------
__global__ __launch_bounds__(256) void k_scan(float* __restrict__ states, const float* __restrict__ cdec) {
    int bid = blockIdx.x;           // BATCH*NH*8
    int bh = bid >> 3, seg = bid & 7;
    int b = bh >> 4, h = bh & 15;
    int off = seg * 256 + threadIdx.x;
    float prev = 0.f;
    for (int c = 0; c < 64; c++) {
        float dec = cdec[bh * 64 + c];
        size_t idx = ((((size_t)b * 64 + c) * NH) + h) * 2048 + off;
        float st = states[idx];
        states[idx] = prev;
        prev = fmaf(dec, prev, st);
    }
}

// ---------------- K4c: Y += exp(acs[q]) * (C . prev^T) + D*x, via MFMA ----------------
__global__ __launch_bounds__(256) void k_yoff(const short* __restrict__ xbc, const float* __restrict__ states,
                                              const float* __restrict__ acs_g, const float* __restrict__ D_skip,
                                              float* __restrict__ Y) {
    __shared__ short CsB[64 * 72];
    __shared__ short Pt[32 * 72];
    int tid = threadIdx.x;
    int bid = blockIdx.x;
    int hg = bid & 3;
    int bc = bid >> 2;
    int b = bc >> 6, c = bc & 63;
    size_t tbase = (size_t)b * SEQ + (size_t)c * 64;
    int wave = tid >> 6, lane = tid & 63;
    int lr = lane & 15, lg = lane >> 4;
    for (int i = tid; i < 64 * 64; i += 256) {
        int q = i >> 6, n = i & 63;
        CsB[q * 72 + n] = xbc[(tbase + q) * CONVD + DINNER + DSTATE + n];
    }
    for (int hh = 0; hh < HGRP; hh++) {
        int h = hg * HGRP + hh;
        size_t sbase = ((size_t)bc * NH + h) * 2048;
        for (int i = tid; i < 2048; i += 256)
            Pt[(i >> 6) * 72 + (i & 63)] = (short)f2bf(states[sbase + i]);
        __syncthreads();
        const float* arow = acs_g + (((size_t)(b * NH + h)) * 64 + c) * 64;
        float eq[4];
        #pragma unroll
        for (int r = 0; r < 4; r++) eq[r] = __expf(arow[wave * 16 + lg * 4 + r]);
        float dsk = D_skip[h];
        bf16x8 a0 = *(const bf16x8*)&CsB[(wave * 16 + lr) * 72 + lg * 8];
        bf16x8 a1 = *(const bf16x8*)&CsB[(wave * 16 + lr) * 72 + 32 + lg * 8];
        #pragma unroll
        for (int pt = 0; pt < 2; pt++) {
            bf16x8 b0 = *(const bf16x8*)&Pt[(pt * 16 + lr) * 72 + lg * 8];
            bf16x8 b1 = *(const bf16x8*)&Pt[(pt * 16 + lr) * 72 + 32 + lg * 8];
            f32x4 z = {0.f, 0.f, 0.f, 0.f};
            z = __builtin_amdgcn_mfma_f32_16x16x32_bf16(a0, b0, z, 0, 0, 0);
            z = __builtin_amdgcn_mfma_f32_16x16x32_bf16(a1, b1, z, 0, 0, 0);
            #pragma unroll
            for (int r = 0; r < 4; r++) {
                int q = wave * 16 + lg * 4 + r;
                int p = pt * 16 + lr;
                size_t yi = ((tbase + q) * NH + h) * HD + p;
                float xv = bf2f(xbc[(tbase + q) * CONVD + h * HD + p]);
                Y[yi] += eq[r] * z[r] + dsk * xv;
            }
        }
        __syncthreads();
    }
}

// ---------------- gate: Yb = bf16( rmsnorm(Y * silu(z16), gw, 1e-5) ) ----------------
__global__ void k_gate(const float* __restrict__ Y, const short* __restrict__ z16,
                       const float* __restrict__ gw, short* __restrict__ Yb) {
    int t = blockIdx.x;
    int lane = threadIdx.x;  // 64
    const float* yr = Y + (size_t)t * DINNER + lane * 8;
    union { int4 v; short s[8]; } zu;
    zu.v = *(const int4*)(z16 + (size_t)t * DINNER + lane * 8);
    float4 y0 = *(const float4*)yr;
    float4 y1 = *(const float4*)(yr + 4);
    float yv[8] = {y0.x, y0.y, y0.z, y0.w, y1.x, y1.y, y1.z, y1.w};
    float g[8];
    float ss = 0.f;
    #pragma unroll
    for (int i = 0; i < 8; i++) {
        float zf = bf2f(zu.s[i]);
        g[i] = yv[i] * fsilu(zf);
        ss += g[i] * g[i];
    }
    #pragma unroll
    for (int o = 32; o > 0; o >>= 1) ss += __shfl_down(ss, o);
    ss = __shfl(ss, 0);
    float rr = rsqrtf(ss * (1.0f / DINNER) + 1e-5f);
    const float* wr = gw + lane * 8;
    float4 w0 = *(const float4*)wr;
    float4 w1 = *(const float4*)(wr + 4);
    float wv[8] = {w0.x, w0.y, w0.z, w0.w, w1.x, w1.y, w1.z, w1.w};
    union { uint4 v; unsigned u[4]; } ou;
    #pragma unroll
    for (int i = 0; i < 4; i++)
        ou.u[i] = cvtpk(g[2*i] * rr * wv[2*i], g[2*i+1] * rr * wv[2*i+1]);
    *(uint4*)(Yb + (size_t)t * DINNER + lane * 8) = ou.v;
}

extern "C" void kernel_launch(void* const* d_in, const int* in_sizes, int n_in,
                              void* d_out, int out_size, void* d_ws, size_t ws_size,
                              hipStream_t stream) {
    const int*   ids        = (const int*)d_in[0];
    const float* embed_w    = (const float*)d_in[1];
    const float* in_proj_w  = (const float*)d_in[2];
    const float* conv_w     = (const float*)d_in[3];
    const float* conv_b     = (const float*)d_in[4];
    const float* A_log      = (const float*)d_in[5];
    const float* D_skip     = (const float*)d_in[6];
    const float* dt_bias    = (const float*)d_in[7];
    const float* gate_w     = (const float*)d_in[8];
    const float* out_proj_w = (const float*)d_in[9];
    const float* norm_w     = (const float*)d_in[10];
    float* out = (float*)d_out;

    if (ws_size < WS_FLOATS * sizeof(float)) {
        k_diag<<<1, 64, 0, stream>>>(out, (float)(ws_size >> 20));
        return;
    }

    float* ws   = (float*)d_ws;
    short* u16  = (short*)(ws + U16_OFF);
    short* z16  = (short*)(ws + Z16_OFF);
    short* xbc  = (short*)(ws + XBC_OFF);
    float* dts  = ws + DTS_OFF;
    float* acs  = ws + ACS_OFF;
    float* cdec = ws + CDEC_OFF;
    short* Wp   = (short*)(ws + WP_OFF);
    short* Wo   = (short*)(ws + WO_OFF);
    short* We   = (short*)(ws + WE_OFF);
    float* st   = ws + UNION_OFF;
    short* Yb   = (short*)(ws + UNION_OFF);
    short* xf16 = (short*)(ws + UNION_OFF + XF_SUB);
    float* Y    = out;

    k_cvt<<<(NPAD * DMODEL + 255) / 256, 256, 0, stream>>>(in_proj_w, Wp, DPROJ * DMODEL, NPAD * DMODEL);
    k_cvt<<<(DMODEL * DINNER + 255) / 256, 256, 0, stream>>>(out_proj_w, Wo, DMODEL * DINNER, DMODEL * DINNER);
    k_cvt<<<(VOCAB * DMODEL + 255) / 256, 256, 0, stream>>>(embed_w, We, VOCAB * DMODEL, VOCAB * DMODEL);
    k_embed<<<TOK, 64, 0, stream>>>(ids, embed_w, norm_w, u16);
    k_gemm_mfma<0><<<dim3(NPAD / 128, TOK / 128), 256, 0, stream>>>(
        u16, Wp, DMODEL, nullptr, z16, xbc, dts, dt_bias, nullptr, nullptr, conv_w, conv_b);
    k_chunk<<<BATCH * 64 * 4, 256, 0, stream>>>(xbc, dts, A_log, Y, st, acs, cdec);
    k_scan<<<BATCH * NH * 8, 256, 0, stream>>>(st, cdec);
    k_yoff<<<BATCH * 64 * 4, 256, 0, stream>>>(xbc, st, acs, D_skip, Y);
    k_gate<<<TOK, 64, 0, stream>>>(Y, z16, gate_w, Yb);
    k_gemm_mfma<1><<<dim3(DMODEL / 128, TOK / 128), 256, 0, stream>>>(
        Yb, Wo, DINNER, nullptr, xf16, nullptr, nullptr, nullptr, ids, embed_w, nullptr, nullptr);
    k_gemm_mfma<2><<<dim3(VOCAB / 128, TOK / 128), 256, 0, stream>>>(
        xf16, We, DMODEL, out, nullptr, nullptr, nullptr, nullptr, nullptr, nullptr, nullptr, nullptr);
}

// Round 10
// 277.984 us; speedup vs baseline: 1.5422x; 1.0650x over previous
//
#include <hip/hip_runtime.h>
#include <cstdint>
#include <cstddef>

#define TOK    32768   // B*L
#define BATCH  8
#define SEQ    4096
#define DMODEL 256
#define DINNER 512
#define DSTATE 64
#define NH     16
#define HD     32
#define DPROJ  1168
#define NPAD   1280    // in_proj N padded to 10*128
#define CONVD  640
#define VOCAB  512
#define HGRP   4       // heads per chunk/yoff block
#define TS     132     // conv tile LDS stride (shorts)

typedef __attribute__((ext_vector_type(8))) short bf16x8;
typedef __attribute__((ext_vector_type(4))) float f32x4;

__device__ __forceinline__ unsigned short f2bf(float f) {
    unsigned u = __float_as_uint(f);
    u += 0x7fffu + ((u >> 16) & 1u);       // RNE
    return (unsigned short)(u >> 16);
}
__device__ __forceinline__ float bf2f(short s) {
    return __uint_as_float(((unsigned)(unsigned short)s) << 16);
}
// pack two f32 -> two bf16 (RNE) in one instruction
__device__ __forceinline__ unsigned cvtpk(float lo, float hi) {
    unsigned r;
    asm("v_cvt_pk_bf16_f32 %0, %1, %2" : "=v"(r) : "v"(lo), "v"(hi));
    return r;
}
__device__ __forceinline__ float fsilu(float s) {
    return s * __builtin_amdgcn_rcpf(1.f + __expf(-s));
}
__device__ __forceinline__ float sp(float v) {
    return v > 20.f ? v : __logf(1.f + __expf(v));
}

// async global->LDS, 16B per lane; dst must be wave-uniform base (linear lane fill)
__device__ __forceinline__ void gload16(const short* src, short* dst) {
    __builtin_amdgcn_global_load_lds((const __attribute__((address_space(1))) void*)src,
                                     (__attribute__((address_space(3))) void*)dst, 16, 0, 0);
}

// ---------------- ws layout (floats, all 16B aligned) ----------------
#define U16_OFF   0                                    // TOK*256 bf16
#define Z16_OFF   (U16_OFF  + (size_t)TOK*128)         // TOK*512 bf16
#define XBC_OFF   (Z16_OFF  + (size_t)TOK*256)         // TOK*640 bf16
#define DTS_OFF   (XBC_OFF  + (size_t)TOK*320)         // TOK*16 fp32
#define ACS_OFF   (DTS_OFF  + (size_t)TOK*16)
#define CDEC_OFF  (ACS_OFF  + (size_t)BATCH*NH*64*64)
#define WP_OFF    (CDEC_OFF + (size_t)BATCH*NH*64)
#define WO_OFF    (WP_OFF   + 163840)
#define WE_OFF    (WO_OFF   + 65536)
#define UNION_OFF (WE_OFF   + 65536)
// union: st fp32 8*64*16*2048 | Yb bf16 TOK*512 + xf16 bf16 TOK*256
#define UNION_FL  ((size_t)BATCH*64*NH*2048)
#define XF_SUB    ((size_t)TOK*256)
#define WS_FLOATS (UNION_OFF + UNION_FL)

__global__ void k_diag(float* out, float wsmb) {
    if (blockIdx.x == 0 && threadIdx.x == 0) out[0] = wsmb;
}

// ---------------- weight fp32 -> bf16 (+ zero pad) ----------------
__global__ void k_cvt(const float* __restrict__ s, short* __restrict__ d, int nsrc, int ntot) {
    int i = blockIdx.x * 256 + threadIdx.x;
    if (i < ntot) d[i] = (i < nsrc) ? (short)f2bf(s[i]) : (short)0;
}

// ---------------- embed gather + rmsnorm -> u16 (bf16) ----------------
__global__ void k_embed(const int* __restrict__ ids, const float* __restrict__ embed,
                        const float* __restrict__ norm_w, short* __restrict__ u16) {
    int t = blockIdx.x;
    int lane = threadIdx.x;   // 64
    int id = ids[t];
    float4 v = ((const float4*)(embed + (size_t)id * DMODEL))[lane];
    float ss = v.x*v.x + v.y*v.y + v.z*v.z + v.w*v.w;
    #pragma unroll
    for (int o = 32; o > 0; o >>= 1) ss += __shfl_down(ss, o);
    ss = __shfl(ss, 0);
    float r = rsqrtf(ss * (1.0f / DMODEL) + 1e-6f);
    float4 w = ((const float4*)norm_w)[lane];
    unsigned p0 = cvtpk(v.x * r * w.x, v.y * r * w.y);
    unsigned p1 = cvtpk(v.z * r * w.z, v.w * r * w.w);
    ((uint2*)(u16 + (size_t)t * DMODEL))[lane] = make_uint2(p0, p1);
}

// ---------------- bf16 MFMA GEMM: 512 threads (8 waves), 128x128 tile, BK=64 ----------------
// Double-buffered gload_lds (one barrier/iter); LDS swizzle per rule #21:
// linear LDS dest, inverse-swizzled global SOURCE, swizzled ds_read.
// Wave w: wm=w>>1 (row strip of 32), wn=w&1 (col strip of 64); acc[2][4] = 32 AGPR.
// MODE 0: in_proj: cols<512 -> z16 ; 512..1151 -> fused conv+silu -> xbc (halo via MFMA) ; 1152.. -> dt
// MODE 1: out_proj: + embed[ids] residual -> xf16 (via z16 param)
// MODE 2: logits: fp32 -> outF
template<int MODE>
__global__ __launch_bounds__(512) void k_gemm_mfma(
    const short* __restrict__ A, const short* __restrict__ B, int K,
    float* __restrict__ outF, short* __restrict__ z16, short* __restrict__ xbc,
    float* __restrict__ dts, const float* __restrict__ dt_bias,
    const int* __restrict__ ids, const float* __restrict__ embed,
    const float* __restrict__ cw, const float* __restrict__ cb) {
    // A buf0 | A buf1 | B buf0 | B buf1, each 8192 shorts (128 rows x 64); conv Tile aliases front
    __shared__ __align__(16) short SM[32768];
    int tid = threadIdx.x;
    int m0 = blockIdx.y << 7;
    int n0 = blockIdx.x << 7;
    int wave = tid >> 6, lane = tid & 63;
    int wm = wave >> 1, wn = wave & 1;
    int lr = lane & 15, lg = lane >> 4;
    const f32x4 zer = {0.f, 0.f, 0.f, 0.f};
    f32x4 acc[2][4];
    #pragma unroll
    for (int i = 0; i < 2; i++)
        #pragma unroll
        for (int j = 0; j < 4; j++) acc[i][j] = zer;

    const bool isXBC = (MODE == 0) && (n0 >= 512) && (n0 < 1152);
    const bool atStart = (m0 & (SEQ - 1)) == 0;
    const bool haloLane = isXBC && (wm == 0) && !atStart && (lr < 3);
    f32x4 hacc[4];
    #pragma unroll
    for (int j = 0; j < 4; j++) hacc[j] = zer;
    const bf16x8 hz = {0, 0, 0, 0, 0, 0, 0, 0};
    bf16x8 hc0 = hz, hc1 = hz, hn0 = hz, hn1 = hz;

    const int nK = K >> 6;
    const int slo = lane >> 3;                 // row within 8-row group
    const int skb = ((lane & 7) ^ slo) << 3;   // inverse-swizzled source k-chunk (shorts)

    // prologue: stage tile 0 into buf0 (+halo regs)
    {
        #pragma unroll
        for (int j = 0; j < 2; j++) {
            int row = wave * 16 + j * 8 + slo;
            gload16(A + (size_t)(m0 + row) * K + skb, SM + (wave * 2 + j) * 512);
            gload16(B + (size_t)(n0 + row) * K + skb, SM + 16384 + (wave * 2 + j) * 512);
        }
        if (haloLane) {
            hc0 = *(const bf16x8*)(A + (size_t)(m0 - 3 + lr) * K + lg * 8);
            hc1 = *(const bf16x8*)(A + (size_t)(m0 - 3 + lr) * K + 32 + lg * 8);
        }
    }
    __syncthreads();   // drains vmcnt: tile 0 (and halo regs) ready

    for (int kt = 0; kt < nK; ++kt) {
        if (kt + 1 < nK) {                      // stage next tile into other buffer
            int k0 = (kt + 1) << 6;
            int nb = ((kt + 1) & 1) * 8192;
            #pragma unroll
            for (int j = 0; j < 2; j++) {
                int row = wave * 16 + j * 8 + slo;
                gload16(A + (size_t)(m0 + row) * K + k0 + skb, SM + nb + (wave * 2 + j) * 512);
                gload16(B + (size_t)(n0 + row) * K + k0 + skb, SM + 16384 + nb + (wave * 2 + j) * 512);
            }
            if (haloLane) {
                hn0 = *(const bf16x8*)(A + (size_t)(m0 - 3 + lr) * K + k0 + lg * 8);
                hn1 = *(const bf16x8*)(A + (size_t)(m0 - 3 + lr) * K + k0 + 32 + lg * 8);
            }
        }
        const short* CA = SM + (kt & 1) * 8192;
        const short* CB = SM + 16384 + (kt & 1) * 8192;
        #pragma unroll
        for (int kk = 0; kk < 2; kk++) {
            int sw = (((kk << 2) + lg) ^ (lr & 7)) << 3;
            bf16x8 af[2], bfr[4];
            #pragma unroll
            for (int mi = 0; mi < 2; mi++)
                af[mi] = *(const bf16x8*)&CA[(wm * 32 + mi * 16 + lr) * 64 + sw];
            #pragma unroll
            for (int ni = 0; ni < 4; ni++)
                bfr[ni] = *(const bf16x8*)&CB[(wn * 64 + ni * 16 + lr) * 64 + sw];
            #pragma unroll
            for (int mi = 0; mi < 2; mi++)
                #pragma unroll
                for (int ni = 0; ni < 4; ni++)
                    acc[mi][ni] = __builtin_amdgcn_mfma_f32_16x16x32_bf16(af[mi], bfr[ni], acc[mi][ni], 0, 0, 0);
            if (isXBC && wm == 0) {
                bf16x8 h = (kk == 0) ? hc0 : hc1;
                #pragma unroll
                for (int ni = 0; ni < 4; ni++)
                    hacc[ni] = __builtin_amdgcn_mfma_f32_16x16x32_bf16(h, bfr[ni], hacc[ni], 0, 0, 0);
            }
        }
        __syncthreads();   // drains next-tile staging; all reads of this tile retired
        hc0 = hn0; hc1 = hn1;
    }

    if (isXBC) {
        // ---- fused causal conv(k=4) + SiLU, sliding-window epilogue ----
        short* Tile = SM;   // [131][TS]: rows 0-2 = halo, 3+row = token m0+row
        #pragma unroll
        for (int mi = 0; mi < 2; mi++)
            #pragma unroll
            for (int ni = 0; ni < 4; ni++)
                #pragma unroll
                for (int r = 0; r < 4; r++) {
                    int row = wm * 32 + mi * 16 + lg * 4 + r;
                    int col = wn * 64 + ni * 16 + lr;
                    float v = acc[mi][ni][r];
                    float vo = __shfl_xor(v, 1);
                    if (!(lr & 1))
                        *(unsigned*)&Tile[(3 + row) * TS + col] = cvtpk(v, vo);
                }
        if (wm == 0 && lg == 0) {
            #pragma unroll
            for (int ni = 0; ni < 4; ni++)
                #pragma unroll
                for (int r = 0; r < 3; r++)
                    Tile[r * TS + wn * 64 + ni * 16 + lr] = (short)f2bf(hacc[ni][r]);
        }
        __syncthreads();
        int cp = tid & 63, rg = tid >> 6;   // 64 col-pairs x 8 row groups of 16
        int colb = cp * 2;
        int ch = (n0 - 512) + colb;
        float c0w0 = cw[ch * 4], c0w1 = cw[ch * 4 + 1], c0w2 = cw[ch * 4 + 2], c0w3 = cw[ch * 4 + 3];
        float c1w0 = cw[ch * 4 + 4], c1w1 = cw[ch * 4 + 5], c1w2 = cw[ch * 4 + 6], c1w3 = cw[ch * 4 + 7];
        float b0v = cb[ch], b1v = cb[ch + 1];
        int rbase = rg * 16;
        unsigned w0 = *(const unsigned*)&Tile[(rbase + 0) * TS + colb];
        unsigned w1 = *(const unsigned*)&Tile[(rbase + 1) * TS + colb];
        unsigned w2 = *(const unsigned*)&Tile[(rbase + 2) * TS + colb];
        for (int i = 0; i < 16; i++) {
            unsigned w3 = *(const unsigned*)&Tile[(rbase + i + 3) * TS + colb];
            float s0 = b0v, s1 = b1v;
            s0 = fmaf(bf2f((short)(w0 & 0xffffu)), c0w0, s0); s1 = fmaf(bf2f((short)(w0 >> 16)), c1w0, s1);
            s0 = fmaf(bf2f((short)(w1 & 0xffffu)), c0w1, s0); s1 = fmaf(bf2f((short)(w1 >> 16)), c1w1, s1);
            s0 = fmaf(bf2f((short)(w2 & 0xffffu)), c0w2, s0); s1 = fmaf(bf2f((short)(w2 >> 16)), c1w2, s1);
            s0 = fmaf(bf2f((short)(w3 & 0xffffu)), c0w3, s0); s1 = fmaf(bf2f((short)(w3 >> 16)), c1w3, s1);
            s0 = fsilu(s0);
            s1 = fsilu(s1);
            *(unsigned*)&xbc[(size_t)(m0 + rbase + i) * CONVD + ch] = cvtpk(s0, s1);
            w0 = w1; w1 = w2; w2 = w3;
        }
        return;
    }

    #pragma unroll
    for (int mi = 0; mi < 2; mi++) {
        #pragma unroll
        for (int r = 0; r < 4; r++) {
            int row = m0 + wm * 32 + mi * 16 + lg * 4 + r;
            int id = 0;
            if (MODE == 1) id = ids[row];
            #pragma unroll
            for (int ni = 0; ni < 4; ni++) {
                int col = n0 + wn * 64 + ni * 16 + lr;
                float v = acc[mi][ni][r];
                if (MODE == 0) {
                    if (n0 < 512) {
                        float vo = __shfl_xor(v, 1);
                        if (!(lr & 1))
                            *(unsigned*)&z16[(size_t)row * DINNER + col] = cvtpk(v, vo);
                    } else if (wn == 0 && ni == 0) {   // dt cols 1152..1167
                        dts[(size_t)row * NH + lr] = sp(v + dt_bias[lr]);
                    }
                } else if (MODE == 1) {
                    float vo = __shfl_xor(v, 1);
                    if (!(lr & 1)) {
                        float2 res = *(const float2*)&embed[(size_t)id * DMODEL + col];
                        *(unsigned*)&z16[(size_t)row * DMODEL + col] = cvtpk(v + res.x, vo + res.y);
                    }
                } else {
                    outF[(size_t)row * VOCAB + col] = v;
                }
            }
        }
    }
}

// ---------------- K4a: per-(b,c,headgroup): M via MFMA, Y_diag + states via MFMA ----------------
__global__ __launch_bounds__(256) void k_chunk(const short* __restrict__ xbc, const float* __restrict__ dts,
                                               const float* __restrict__ A_log,
                                               float* __restrict__ Y, float* __restrict__ states,
                                               float* __restrict__ acs_g, float* __restrict__ cdec) {
    __shared__ short CsB[64 * 72];   // C[q][n]
    __shared__ short BsB[64 * 72];   // B[k][n]
    __shared__ short Wsh[64 * 72];   // W[q][k] per head
    __shared__ short XtS[32 * 72];   // Xt[p][k] per head
    __shared__ short BdS[64 * 72];   // Bd[n][k] per head
    __shared__ float acsS[HGRP][64];
    __shared__ float dkS[HGRP][64];
    int tid = threadIdx.x;
    int bid = blockIdx.x;
    int hg = bid & 3;
    int bc = bid >> 2;
    int b = bc >> 6, c = bc & 63;
    int h0 = hg * HGRP;
    size_t tbase = (size_t)b * SEQ + (size_t)c * 64;
    int wave = tid >> 6, lane = tid & 63;
    int lr = lane & 15, lg = lane >> 4;

    for (int i = tid; i < 64 * 64; i += 256) {
        int q = i >> 6, n = i & 63;
        const short* rowp = xbc + (tbase + q) * CONVD + DINNER;
        BsB[q * 72 + n] = rowp[n];
        CsB[q * 72 + n] = rowp[DSTATE + n];
    }
    {
        int h = h0 + wave;
        float Ah = -__expf(A_log[h]);
        float v = dts[(tbase + lane) * NH + h] * Ah;
        #pragma unroll
        for (int off = 1; off < 64; off <<= 1) {
            float o = __shfl_up(v, off);
            if (lane >= off) v += o;
        }
        acsS[wave][lane] = v;
        acs_g[(((size_t)(b * NH + h)) * 64 + c) * 64 + lane] = v;
        float alast = __shfl(v, 63);
        dkS[wave][lane] = __expf(alast - v);
        if (lane == 0) cdec[(b * NH + h) * 64 + c] = __expf(alast);
    }
    __syncthreads();

    f32x4 macc[4];
    {
        bf16x8 aw0 = *(const bf16x8*)&CsB[(wave * 16 + lr) * 72 + lg * 8];
        bf16x8 aw1 = *(const bf16x8*)&CsB[(wave * 16 + lr) * 72 + 32 + lg * 8];
        #pragma unroll
        for (int ct = 0; ct < 4; ct++) {
            bf16x8 b0 = *(const bf16x8*)&BsB[(ct * 16 + lr) * 72 + lg * 8];
            bf16x8 b1 = *(const bf16x8*)&BsB[(ct * 16 + lr) * 72 + 32 + lg * 8];
            f32x4 z = {0.f, 0.f, 0.f, 0.f};
            z = __builtin_amdgcn_mfma_f32_16x16x32_bf16(aw0, b0, z, 0, 0, 0);
            z = __builtin_amdgcn_mfma_f32_16x16x32_bf16(aw1, b1, z, 0, 0, 0);
            macc[ct] = z;
        }
    }

    for (int hh = 0; hh < HGRP; hh++) {
        int h = h0 + hh;
        #pragma unroll
        for (int ct = 0; ct < 4; ct++) {
            int k = ct * 16 + lr;
            #pragma unroll
            for (int r = 0; r < 4; r++) {
                int q = wave * 16 + lg * 4 + r;
                float wv = 0.f;
                if (k <= q) wv = macc[ct][r] * __expf(acsS[hh][q] - acsS[hh][k]);
                float wo = __shfl_xor(wv, 1);
                if (!(lr & 1))
                    *(unsigned*)&Wsh[q * 72 + k] = cvtpk(wv, wo);
            }
        }
        for (int i = tid; i < 2048; i += 256) {
            int p = i & 31, k = i >> 5;
            float xv = bf2f(xbc[(tbase + k) * CONVD + h * HD + p]);
            XtS[p * 72 + k] = (short)f2bf(xv * dts[(tbase + k) * NH + h]);
        }
        for (int i = tid; i < 4096; i += 256) {
            int n = i & 63, k = i >> 6;
            BdS[n * 72 + k] = (short)f2bf(bf2f(BsB[k * 72 + n]) * dkS[hh][k]);
        }
        __syncthreads();
        {
            bf16x8 a0 = *(const bf16x8*)&Wsh[(wave * 16 + lr) * 72 + lg * 8];
            bf16x8 a1 = *(const bf16x8*)&Wsh[(wave * 16 + lr) * 72 + 32 + lg * 8];
            #pragma unroll
            for (int pt = 0; pt < 2; pt++) {
                bf16x8 b0 = *(const bf16x8*)&XtS[(pt * 16 + lr) * 72 + lg * 8];
                bf16x8 b1 = *(const bf16x8*)&XtS[(pt * 16 + lr) * 72 + 32 + lg * 8];
                f32x4 z = {0.f, 0.f, 0.f, 0.f};
                z = __builtin_amdgcn_mfma_f32_16x16x32_bf16(a0, b0, z, 0, 0, 0);
                z = __builtin_amdgcn_mfma_f32_16x16x32_bf16(a1, b1, z, 0, 0, 0);
                #pragma unroll
                for (int r = 0; r < 4; r++) {
                    int q = wave * 16 + lg * 4 + r;
                    Y[((tbase + q) * NH + h) * HD + pt * 16 + lr] = z[r];
                }
            }
        }
        {
            int ptile = wave & 1;
            bf16x8 a0 = *(const bf16x8*)&XtS[(ptile * 16 + lr) * 72 + lg * 8];
            bf16x8 a1 = *(const bf16x8*)&XtS[(ptile * 16 + lr) * 72 + 32 + lg * 8];
            #pragma unroll
            for (int j = 0; j < 2; j++) {
                int nt = (wave >> 1) * 2 + j;
                bf16x8 b0 = *(const bf16x8*)&BdS[(nt * 16 + lr) * 72 + lg * 8];
                bf16x8 b1 = *(const bf16x8*)&BdS[(nt * 16 + lr) * 72 + 32 + lg * 8];
                f32x4 z = {0.f, 0.f, 0.f, 0.f};
                z = __builtin_amdgcn_mfma_f32_16x16x32_bf16(a0, b0, z, 0, 0, 0);
                z = __builtin_amdgcn_mfma_f32_16x16x32_bf16(a1, b1, z, 0, 0, 0);
                #pragma unroll
                for (int r = 0; r < 4; r++) {
                    int p = ptile * 16 + lg * 4 + r;
                    states[((size_t)bc * NH + h) * 2048 + p * 64 + nt * 16 + lr] = z[r];
                }
            }
        }
        __syncthreads();
    }
}

// ---------------- K4b: sequential inter-chunk scan (1 elem/thread) ----------------
__global__ __launch_bounds__(256) void k_scan(float* __restrict__ states, const float* __restrict__ cdec) {
    int bid = blockIdx.x;           // BATCH*NH*8
    int bh = bid >> 3, seg = bid & 7;
    int b = bh >> 4, h = bh & 15;
    int off = seg * 256 + threadIdx.x;
    float prev = 0.f;
    for (int c = 0; c < 64; c++) {
        float dec = cdec[bh * 64 + c];
        size_t idx = ((((size_t)b * 64 + c) * NH) + h) * 2048 + off;
        float st = states[idx];
        states[idx] = prev;
        prev = fmaf(dec, prev, st);
    }
}

// ---------------- K4c: Y += exp(acs[q]) * (C . prev^T) + D*x, via MFMA ----------------
__global__ __launch_bounds__(256) void k_yoff(const short* __restrict__ xbc, const float* __restrict__ states,
                                              const float* __restrict__ acs_g, const float* __restrict__ D_skip,
                                              float* __restrict__ Y) {
    __shared__ short CsB[64 * 72];
    __shared__ short Pt[32 * 72];
    int tid = threadIdx.x;
    int bid = blockIdx.x;
    int hg = bid & 3;
    int bc = bid >> 2;
    int b = bc >> 6, c = bc & 63;
    size_t tbase = (size_t)b * SEQ + (size_t)c * 64;
    int wave = tid >> 6, lane = tid & 63;
    int lr = lane & 15, lg = lane >> 4;
    for (int i = tid; i < 64 * 64; i += 256) {
        int q = i >> 6, n = i & 63;
        CsB[q * 72 + n] = xbc[(tbase + q) * CONVD + DINNER + DSTATE + n];
    }
    for (int hh = 0; hh < HGRP; hh++) {
        int h = hg * HGRP + hh;
        size_t sbase = ((size_t)bc * NH + h) * 2048;
        for (int i = tid; i < 2048; i += 256)
            Pt[(i >> 6) * 72 + (i & 63)] = (short)f2bf(states[sbase + i]);
        __syncthreads();
        const float* arow = acs_g + (((size_t)(b * NH + h)) * 64 + c) * 64;
        float eq[4];
        #pragma unroll
        for (int r = 0; r < 4; r++) eq[r] = __expf(arow[wave * 16 + lg * 4 + r]);
        float dsk = D_skip[h];
        bf16x8 a0 = *(const bf16x8*)&CsB[(wave * 16 + lr) * 72 + lg * 8];
        bf16x8 a1 = *(const bf16x8*)&CsB[(wave * 16 + lr) * 72 + 32 + lg * 8];
        #pragma unroll
        for (int pt = 0; pt < 2; pt++) {
            bf16x8 b0 = *(const bf16x8*)&Pt[(pt * 16 + lr) * 72 + lg * 8];
            bf16x8 b1 = *(const bf16x8*)&Pt[(pt * 16 + lr) * 72 + 32 + lg * 8];
            f32x4 z = {0.f, 0.f, 0.f, 0.f};
            z = __builtin_amdgcn_mfma_f32_16x16x32_bf16(a0, b0, z, 0, 0, 0);
            z = __builtin_amdgcn_mfma_f32_16x16x32_bf16(a1, b1, z, 0, 0, 0);
            #pragma unroll
            for (int r = 0; r < 4; r++) {
                int q = wave * 16 + lg * 4 + r;
                int p = pt * 16 + lr;
                size_t yi = ((tbase + q) * NH + h) * HD + p;
                float xv = bf2f(xbc[(tbase + q) * CONVD + h * HD + p]);
                Y[yi] += eq[r] * z[r] + dsk * xv;
            }
        }
        __syncthreads();
    }
}

// ---------------- gate: Yb = bf16( rmsnorm(Y * silu(z16), gw, 1e-5) ) ----------------
__global__ void k_gate(const float* __restrict__ Y, const short* __restrict__ z16,
                       const float* __restrict__ gw, short* __restrict__ Yb) {
    int t = blockIdx.x;
    int lane = threadIdx.x;  // 64
    const float* yr = Y + (size_t)t * DINNER + lane * 8;
    union { int4 v; short s[8]; } zu;
    zu.v = *(const int4*)(z16 + (size_t)t * DINNER + lane * 8);
    float4 y0 = *(const float4*)yr;
    float4 y1 = *(const float4*)(yr + 4);
    float yv[8] = {y0.x, y0.y, y0.z, y0.w, y1.x, y1.y, y1.z, y1.w};
    float g[8];
    float ss = 0.f;
    #pragma unroll
    for (int i = 0; i < 8; i++) {
        float zf = bf2f(zu.s[i]);
        g[i] = yv[i] * fsilu(zf);
        ss += g[i] * g[i];
    }
    #pragma unroll
    for (int o = 32; o > 0; o >>= 1) ss += __shfl_down(ss, o);
    ss = __shfl(ss, 0);
    float rr = rsqrtf(ss * (1.0f / DINNER) + 1e-5f);
    const float* wr = gw + lane * 8;
    float4 w0 = *(const float4*)wr;
    float4 w1 = *(const float4*)(wr + 4);
    float wv[8] = {w0.x, w0.y, w0.z, w0.w, w1.x, w1.y, w1.z, w1.w};
    union { uint4 v; unsigned u[4]; } ou;
    #pragma unroll
    for (int i = 0; i < 4; i++)
        ou.u[i] = cvtpk(g[2*i] * rr * wv[2*i], g[2*i+1] * rr * wv[2*i+1]);
    *(uint4*)(Yb + (size_t)t * DINNER + lane * 8) = ou.v;
}

extern "C" void kernel_launch(void* const* d_in, const int* in_sizes, int n_in,
                              void* d_out, int out_size, void* d_ws, size_t ws_size,
                              hipStream_t stream) {
    const int*   ids        = (const int*)d_in[0];
    const float* embed_w    = (const float*)d_in[1];
    const float* in_proj_w  = (const float*)d_in[2];
    const float* conv_w     = (const float*)d_in[3];
    const float* conv_b     = (const float*)d_in[4];
    const float* A_log      = (const float*)d_in[5];
    const float* D_skip     = (const float*)d_in[6];
    const float* dt_bias    = (const float*)d_in[7];
    const float* gate_w     = (const float*)d_in[8];
    const float* out_proj_w = (const float*)d_in[9];
    const float* norm_w     = (const float*)d_in[10];
    float* out = (float*)d_out;

    if (ws_size < WS_FLOATS * sizeof(float)) {
        k_diag<<<1, 64, 0, stream>>>(out, (float)(ws_size >> 20));
        return;
    }

    float* ws   = (float*)d_ws;
    short* u16  = (short*)(ws + U16_OFF);
    short* z16  = (short*)(ws + Z16_OFF);
    short* xbc  = (short*)(ws + XBC_OFF);
    float* dts  = ws + DTS_OFF;
    float* acs  = ws + ACS_OFF;
    float* cdec = ws + CDEC_OFF;
    short* Wp   = (short*)(ws + WP_OFF);
    short* Wo   = (short*)(ws + WO_OFF);
    short* We   = (short*)(ws + WE_OFF);
    float* st   = ws + UNION_OFF;
    short* Yb   = (short*)(ws + UNION_OFF);
    short* xf16 = (short*)(ws + UNION_OFF + XF_SUB);
    float* Y    = out;

    k_cvt<<<(NPAD * DMODEL + 255) / 256, 256, 0, stream>>>(in_proj_w, Wp, DPROJ * DMODEL, NPAD * DMODEL);
    k_cvt<<<(DMODEL * DINNER + 255) / 256, 256, 0, stream>>>(out_proj_w, Wo, DMODEL * DINNER, DMODEL * DINNER);
    k_cvt<<<(VOCAB * DMODEL + 255) / 256, 256, 0, stream>>>(embed_w, We, VOCAB * DMODEL, VOCAB * DMODEL);
    k_embed<<<TOK, 64, 0, stream>>>(ids, embed_w, norm_w, u16);
    k_gemm_mfma<0><<<dim3(NPAD / 128, TOK / 128), 512, 0, stream>>>(
        u16, Wp, DMODEL, nullptr, z16, xbc, dts, dt_bias, nullptr, nullptr, conv_w, conv_b);
    k_chunk<<<BATCH * 64 * 4, 256, 0, stream>>>(xbc, dts, A_log, Y, st, acs, cdec);
    k_scan<<<BATCH * NH * 8, 256, 0, stream>>>(st, cdec);
    k_yoff<<<BATCH * 64 * 4, 256, 0, stream>>>(xbc, st, acs, D_skip, Y);
    k_gate<<<TOK, 64, 0, stream>>>(Y, z16, gate_w, Yb);
    k_gemm_mfma<1><<<dim3(DMODEL / 128, TOK / 128), 512, 0, stream>>>(
        Yb, Wo, DINNER, nullptr, xf16, nullptr, nullptr, nullptr, ids, embed_w, nullptr, nullptr);
    k_gemm_mfma<2><<<dim3(VOCAB / 128, TOK / 128), 512, 0, stream>>>(
        xf16, We, DMODEL, out, nullptr, nullptr, nullptr, nullptr, nullptr, nullptr, nullptr, nullptr);
}

// Round 11
// 255.483 us; speedup vs baseline: 1.6781x; 1.0881x over previous
//
#include <hip/hip_runtime.h>
#include <cstdint>
#include <cstddef>

#define TOK    32768   // B*L
#define BATCH  8
#define SEQ    4096
#define DMODEL 256
#define DINNER 512
#define DSTATE 64
#define NH     16
#define HD     32
#define DPROJ  1168
#define NPAD   1280    // in_proj N padded to 10*128
#define CONVD  640
#define VOCAB  512
#define HGRP   4       // heads per states/y block
#define TS     132     // conv tile LDS stride (shorts)

typedef __attribute__((ext_vector_type(8))) short bf16x8;
typedef __attribute__((ext_vector_type(4))) float f32x4;

__device__ __forceinline__ unsigned short f2bf(float f) {
    unsigned u = __float_as_uint(f);
    u += 0x7fffu + ((u >> 16) & 1u);       // RNE
    return (unsigned short)(u >> 16);
}
__device__ __forceinline__ float bf2f(short s) {
    return __uint_as_float(((unsigned)(unsigned short)s) << 16);
}
// pack two f32 -> two bf16 (RNE) in one instruction
__device__ __forceinline__ unsigned cvtpk(float lo, float hi) {
    unsigned r;
    asm("v_cvt_pk_bf16_f32 %0, %1, %2" : "=v"(r) : "v"(lo), "v"(hi));
    return r;
}
__device__ __forceinline__ float fsilu(float s) {
    return s * __builtin_amdgcn_rcpf(1.f + __expf(-s));
}
__device__ __forceinline__ float sp(float v) {
    return v > 20.f ? v : __logf(1.f + __expf(v));
}

// async global->LDS, 16B per lane; dst must be wave-uniform base (linear lane fill)
__device__ __forceinline__ void gload16(const short* src, short* dst) {
    __builtin_amdgcn_global_load_lds((const __attribute__((address_space(1))) void*)src,
                                     (__attribute__((address_space(3))) void*)dst, 16, 0, 0);
}

// ---------------- ws layout (floats, all 16B aligned) ----------------
#define U16_OFF   0                                    // TOK*256 bf16
#define Z16_OFF   (U16_OFF  + (size_t)TOK*128)         // TOK*512 bf16
#define XBC_OFF   (Z16_OFF  + (size_t)TOK*256)         // TOK*640 bf16
#define DTS_OFF   (XBC_OFF  + (size_t)TOK*320)         // TOK*16 fp32
#define ACS_OFF   (DTS_OFF  + (size_t)TOK*16)
#define CDEC_OFF  (ACS_OFF  + (size_t)BATCH*NH*64*64)
#define WP_OFF    (CDEC_OFF + (size_t)BATCH*NH*64)
#define WO_OFF    (WP_OFF   + 163840)
#define WE_OFF    (WO_OFF   + 65536)
#define UNION_OFF (WE_OFF   + 65536)
// union: st bf16 8*64*16*2048 (33.5MB) | Yb bf16 TOK*512 + xf16 bf16 TOK*256
#define UNION_FL  ((size_t)BATCH*64*NH*2048)           // sized for old fp32; bf16 uses half
#define XF_SUB    ((size_t)TOK*256)
#define WS_FLOATS (UNION_OFF + UNION_FL)

__global__ void k_diag(float* out, float wsmb) {
    if (blockIdx.x == 0 && threadIdx.x == 0) out[0] = wsmb;
}

// ---------------- weight fp32 -> bf16 (+ zero pad) ----------------
__global__ void k_cvt(const float* __restrict__ s, short* __restrict__ d, int nsrc, int ntot) {
    int i = blockIdx.x * 256 + threadIdx.x;
    if (i < ntot) d[i] = (i < nsrc) ? (short)f2bf(s[i]) : (short)0;
}

// ---------------- embed gather + rmsnorm -> u16 (bf16) ----------------
__global__ void k_embed(const int* __restrict__ ids, const float* __restrict__ embed,
                        const float* __restrict__ norm_w, short* __restrict__ u16) {
    int t = blockIdx.x;
    int lane = threadIdx.x;   // 64
    int id = ids[t];
    float4 v = ((const float4*)(embed + (size_t)id * DMODEL))[lane];
    float ss = v.x*v.x + v.y*v.y + v.z*v.z + v.w*v.w;
    #pragma unroll
    for (int o = 32; o > 0; o >>= 1) ss += __shfl_down(ss, o);
    ss = __shfl(ss, 0);
    float r = rsqrtf(ss * (1.0f / DMODEL) + 1e-6f);
    float4 w = ((const float4*)norm_w)[lane];
    unsigned p0 = cvtpk(v.x * r * w.x, v.y * r * w.y);
    unsigned p1 = cvtpk(v.z * r * w.z, v.w * r * w.w);
    ((uint2*)(u16 + (size_t)t * DMODEL))[lane] = make_uint2(p0, p1);
}

// ---------------- bf16 MFMA GEMM: 512 threads (8 waves), 128x128 tile, BK=64 ----------------
// (unchanged from R10 — double-buffered gload_lds, rule-#21 swizzle)
template<int MODE>
__global__ __launch_bounds__(512) void k_gemm_mfma(
    const short* __restrict__ A, const short* __restrict__ B, int K,
    float* __restrict__ outF, short* __restrict__ z16, short* __restrict__ xbc,
    float* __restrict__ dts, const float* __restrict__ dt_bias,
    const int* __restrict__ ids, const float* __restrict__ embed,
    const float* __restrict__ cw, const float* __restrict__ cb) {
    __shared__ __align__(16) short SM[32768];
    int tid = threadIdx.x;
    int m0 = blockIdx.y << 7;
    int n0 = blockIdx.x << 7;
    int wave = tid >> 6, lane = tid & 63;
    int wm = wave >> 1, wn = wave & 1;
    int lr = lane & 15, lg = lane >> 4;
    const f32x4 zer = {0.f, 0.f, 0.f, 0.f};
    f32x4 acc[2][4];
    #pragma unroll
    for (int i = 0; i < 2; i++)
        #pragma unroll
        for (int j = 0; j < 4; j++) acc[i][j] = zer;

    const bool isXBC = (MODE == 0) && (n0 >= 512) && (n0 < 1152);
    const bool atStart = (m0 & (SEQ - 1)) == 0;
    const bool haloLane = isXBC && (wm == 0) && !atStart && (lr < 3);
    f32x4 hacc[4];
    #pragma unroll
    for (int j = 0; j < 4; j++) hacc[j] = zer;
    const bf16x8 hz = {0, 0, 0, 0, 0, 0, 0, 0};
    bf16x8 hc0 = hz, hc1 = hz, hn0 = hz, hn1 = hz;

    const int nK = K >> 6;
    const int slo = lane >> 3;
    const int skb = ((lane & 7) ^ slo) << 3;

    {
        #pragma unroll
        for (int j = 0; j < 2; j++) {
            int row = wave * 16 + j * 8 + slo;
            gload16(A + (size_t)(m0 + row) * K + skb, SM + (wave * 2 + j) * 512);
            gload16(B + (size_t)(n0 + row) * K + skb, SM + 16384 + (wave * 2 + j) * 512);
        }
        if (haloLane) {
            hc0 = *(const bf16x8*)(A + (size_t)(m0 - 3 + lr) * K + lg * 8);
            hc1 = *(const bf16x8*)(A + (size_t)(m0 - 3 + lr) * K + 32 + lg * 8);
        }
    }
    __syncthreads();

    for (int kt = 0; kt < nK; ++kt) {
        if (kt + 1 < nK) {
            int k0 = (kt + 1) << 6;
            int nb = ((kt + 1) & 1) * 8192;
            #pragma unroll
            for (int j = 0; j < 2; j++) {
                int row = wave * 16 + j * 8 + slo;
                gload16(A + (size_t)(m0 + row) * K + k0 + skb, SM + nb + (wave * 2 + j) * 512);
                gload16(B + (size_t)(n0 + row) * K + k0 + skb, SM + 16384 + nb + (wave * 2 + j) * 512);
            }
            if (haloLane) {
                hn0 = *(const bf16x8*)(A + (size_t)(m0 - 3 + lr) * K + k0 + lg * 8);
                hn1 = *(const bf16x8*)(A + (size_t)(m0 - 3 + lr) * K + k0 + 32 + lg * 8);
            }
        }
        const short* CA = SM + (kt & 1) * 8192;
        const short* CB = SM + 16384 + (kt & 1) * 8192;
        #pragma unroll
        for (int kk = 0; kk < 2; kk++) {
            int sw = (((kk << 2) + lg) ^ (lr & 7)) << 3;
            bf16x8 af[2], bfr[4];
            #pragma unroll
            for (int mi = 0; mi < 2; mi++)
                af[mi] = *(const bf16x8*)&CA[(wm * 32 + mi * 16 + lr) * 64 + sw];
            #pragma unroll
            for (int ni = 0; ni < 4; ni++)
                bfr[ni] = *(const bf16x8*)&CB[(wn * 64 + ni * 16 + lr) * 64 + sw];
            #pragma unroll
            for (int mi = 0; mi < 2; mi++)
                #pragma unroll
                for (int ni = 0; ni < 4; ni++)
                    acc[mi][ni] = __builtin_amdgcn_mfma_f32_16x16x32_bf16(af[mi], bfr[ni], acc[mi][ni], 0, 0, 0);
            if (isXBC && wm == 0) {
                bf16x8 h = (kk == 0) ? hc0 : hc1;
                #pragma unroll
                for (int ni = 0; ni < 4; ni++)
                    hacc[ni] = __builtin_amdgcn_mfma_f32_16x16x32_bf16(h, bfr[ni], hacc[ni], 0, 0, 0);
            }
        }
        __syncthreads();
        hc0 = hn0; hc1 = hn1;
    }

    if (isXBC) {
        short* Tile = SM;
        #pragma unroll
        for (int mi = 0; mi < 2; mi++)
            #pragma unroll
            for (int ni = 0; ni < 4; ni++)
                #pragma unroll
                for (int r = 0; r < 4; r++) {
                    int row = wm * 32 + mi * 16 + lg * 4 + r;
                    int col = wn * 64 + ni * 16 + lr;
                    float v = acc[mi][ni][r];
                    float vo = __shfl_xor(v, 1);
                    if (!(lr & 1))
                        *(unsigned*)&Tile[(3 + row) * TS + col] = cvtpk(v, vo);
                }
        if (wm == 0 && lg == 0) {
            #pragma unroll
            for (int ni = 0; ni < 4; ni++)
                #pragma unroll
                for (int r = 0; r < 3; r++)
                    Tile[r * TS + wn * 64 + ni * 16 + lr] = (short)f2bf(hacc[ni][r]);
        }
        __syncthreads();
        int cp = tid & 63, rg = tid >> 6;
        int colb = cp * 2;
        int ch = (n0 - 512) + colb;
        float c0w0 = cw[ch * 4], c0w1 = cw[ch * 4 + 1], c0w2 = cw[ch * 4 + 2], c0w3 = cw[ch * 4 + 3];
        float c1w0 = cw[ch * 4 + 4], c1w1 = cw[ch * 4 + 5], c1w2 = cw[ch * 4 + 6], c1w3 = cw[ch * 4 + 7];
        float b0v = cb[ch], b1v = cb[ch + 1];
        int rbase = rg * 16;
        unsigned w0 = *(const unsigned*)&Tile[(rbase + 0) * TS + colb];
        unsigned w1 = *(const unsigned*)&Tile[(rbase + 1) * TS + colb];
        unsigned w2 = *(const unsigned*)&Tile[(rbase + 2) * TS + colb];
        for (int i = 0; i < 16; i++) {
            unsigned w3 = *(const unsigned*)&Tile[(rbase + i + 3) * TS + colb];
            float s0 = b0v, s1 = b1v;
            s0 = fmaf(bf2f((short)(w0 & 0xffffu)), c0w0, s0); s1 = fmaf(bf2f((short)(w0 >> 16)), c1w0, s1);
            s0 = fmaf(bf2f((short)(w1 & 0xffffu)), c0w1, s0); s1 = fmaf(bf2f((short)(w1 >> 16)), c1w1, s1);
            s0 = fmaf(bf2f((short)(w2 & 0xffffu)), c0w2, s0); s1 = fmaf(bf2f((short)(w2 >> 16)), c1w2, s1);
            s0 = fmaf(bf2f((short)(w3 & 0xffffu)), c0w3, s0); s1 = fmaf(bf2f((short)(w3 >> 16)), c1w3, s1);
            s0 = fsilu(s0);
            s1 = fsilu(s1);
            *(unsigned*)&xbc[(size_t)(m0 + rbase + i) * CONVD + ch] = cvtpk(s0, s1);
            w0 = w1; w1 = w2; w2 = w3;
        }
        return;
    }

    #pragma unroll
    for (int mi = 0; mi < 2; mi++) {
        #pragma unroll
        for (int r = 0; r < 4; r++) {
            int row = m0 + wm * 32 + mi * 16 + lg * 4 + r;
            int id = 0;
            if (MODE == 1) id = ids[row];
            #pragma unroll
            for (int ni = 0; ni < 4; ni++) {
                int col = n0 + wn * 64 + ni * 16 + lr;
                float v = acc[mi][ni][r];
                if (MODE == 0) {
                    if (n0 < 512) {
                        float vo = __shfl_xor(v, 1);
                        if (!(lr & 1))
                            *(unsigned*)&z16[(size_t)row * DINNER + col] = cvtpk(v, vo);
                    } else if (wn == 0 && ni == 0) {
                        dts[(size_t)row * NH + lr] = sp(v + dt_bias[lr]);
                    }
                } else if (MODE == 1) {
                    float vo = __shfl_xor(v, 1);
                    if (!(lr & 1)) {
                        float2 res = *(const float2*)&embed[(size_t)id * DMODEL + col];
                        *(unsigned*)&z16[(size_t)row * DMODEL + col] = cvtpk(v + res.x, vo + res.y);
                    }
                } else {
                    outF[(size_t)row * VOCAB + col] = v;
                }
            }
        }
    }
}

// ---------------- k_states: per (b,c,hg): chunk states (bf16) + cumsums ----------------
__global__ __launch_bounds__(256) void k_states(const short* __restrict__ xbc, const float* __restrict__ dts,
                                                const float* __restrict__ A_log,
                                                short* __restrict__ st16,
                                                float* __restrict__ acs_g, float* __restrict__ cdec) {
    __shared__ short BsB[64 * 72];   // B[k][n]
    __shared__ short BT[64 * 72];    // B^T[n][k], built once
    __shared__ short XdS[32 * 72];   // Xd[p][k] = x*dt*dk per head
    __shared__ float dkS[HGRP][64];
    int tid = threadIdx.x;
    int bid = blockIdx.x;
    int hg = bid & 3;
    int bc = bid >> 2;
    int b = bc >> 6, c = bc & 63;
    int h0 = hg * HGRP;
    size_t tbase = (size_t)b * SEQ + (size_t)c * 64;
    int wave = tid >> 6, lane = tid & 63;
    int lr = lane & 15, lg = lane >> 4;

    for (int i = tid; i < 64 * 64; i += 256) {
        int q = i >> 6, n = i & 63;
        BsB[q * 72 + n] = xbc[(tbase + q) * CONVD + DINNER + n];
    }
    {   // wave w: cumsum for head h0+w
        int h = h0 + wave;
        float Ah = -__expf(A_log[h]);
        float v = dts[(tbase + lane) * NH + h] * Ah;
        #pragma unroll
        for (int off = 1; off < 64; off <<= 1) {
            float o = __shfl_up(v, off);
            if (lane >= off) v += o;
        }
        acs_g[(((size_t)(b * NH + h)) * 64 + c) * 64 + lane] = v;
        float alast = __shfl(v, 63);
        dkS[wave][lane] = __expf(alast - v);
        if (lane == 0) cdec[(b * NH + h) * 64 + c] = __expf(alast);
    }
    __syncthreads();
    // BT[n][k] = B[k][n], built once (reads conflict-free; writes 8-way but one-shot)
    for (int i = tid; i < 64 * 64; i += 256) {
        int k = i >> 6, n = i & 63;
        BT[n * 72 + k] = BsB[k * 72 + n];
    }
    __syncthreads();

    for (int hh = 0; hh < HGRP; hh++) {
        int h = h0 + hh;
        for (int i = tid; i < 2048; i += 256) {
            int p = i & 31, k = i >> 5;
            float xv = bf2f(xbc[(tbase + k) * CONVD + h * HD + p]);
            XdS[p * 72 + k] = (short)f2bf(xv * dts[(tbase + k) * NH + h] * dkS[hh][k]);
        }
        __syncthreads();
        {
            int ptile = wave & 1;
            bf16x8 a0 = *(const bf16x8*)&XdS[(ptile * 16 + lr) * 72 + lg * 8];
            bf16x8 a1 = *(const bf16x8*)&XdS[(ptile * 16 + lr) * 72 + 32 + lg * 8];
            size_t base = ((size_t)bc * NH + h) * 2048;
            #pragma unroll
            for (int j = 0; j < 2; j++) {
                int nt = (wave >> 1) * 2 + j;
                bf16x8 b0 = *(const bf16x8*)&BT[(nt * 16 + lr) * 72 + lg * 8];
                bf16x8 b1 = *(const bf16x8*)&BT[(nt * 16 + lr) * 72 + 32 + lg * 8];
                f32x4 z = {0.f, 0.f, 0.f, 0.f};
                z = __builtin_amdgcn_mfma_f32_16x16x32_bf16(a0, b0, z, 0, 0, 0);
                z = __builtin_amdgcn_mfma_f32_16x16x32_bf16(a1, b1, z, 0, 0, 0);
                #pragma unroll
                for (int r = 0; r < 4; r++) {
                    int p = ptile * 16 + lg * 4 + r;
                    float v = z[r];
                    float vo = __shfl_xor(v, 1);
                    if (!(lr & 1))
                        *(unsigned*)&st16[base + p * 64 + nt * 16 + lr] = cvtpk(v, vo);
                }
            }
        }
        __syncthreads();
    }
}

// ---------------- k_scan: sequential inter-chunk scan on bf16 states (fp32 accum) ----------------
__global__ __launch_bounds__(256) void k_scan(unsigned* __restrict__ st32, const float* __restrict__ cdec) {
    int bid = blockIdx.x;           // BATCH*NH*4
    int bh = bid >> 2, seg = bid & 3;
    int b = bh >> 4, h = bh & 15;
    int off = seg * 256 + threadIdx.x;   // u32 index within 1024
    float p0 = 0.f, p1 = 0.f;
    for (int c = 0; c < 64; c++) {
        float dec = cdec[bh * 64 + c];
        size_t idx = ((((size_t)b * 64 + c) * NH) + h) * 1024 + off;
        unsigned v = st32[idx];
        float s0 = bf2f((short)(v & 0xffffu));
        float s1 = bf2f((short)(v >> 16));
        st32[idx] = cvtpk(p0, p1);
        p0 = fmaf(dec, p0, s0);
        p1 = fmaf(dec, p1, s1);
    }
}

// ---------------- k_y: Y = Y_diag + exp(acs)*(C . prev^T) + D*x (single Y write) ----------------
__global__ __launch_bounds__(256) void k_y(const short* __restrict__ xbc, const float* __restrict__ dts,
                                           const short* __restrict__ st16, const float* __restrict__ acs_g,
                                           const float* __restrict__ D_skip, float* __restrict__ Y) {
    __shared__ short CsB[64 * 72];   // C[q][n]
    __shared__ short BsB[64 * 72];   // B[k][n]
    __shared__ short Wsh[64 * 72];   // W[q][k] per head
    __shared__ short XtS[32 * 72];   // Xt[p][k] per head
    __shared__ short Pt[32 * 72];    // prev[p][n] per head
    __shared__ float acsS[HGRP][64];
    int tid = threadIdx.x;
    int bid = blockIdx.x;
    int hg = bid & 3;
    int bc = bid >> 2;
    int b = bc >> 6, c = bc & 63;
    int h0 = hg * HGRP;
    size_t tbase = (size_t)b * SEQ + (size_t)c * 64;
    int wave = tid >> 6, lane = tid & 63;
    int lr = lane & 15, lg = lane >> 4;

    for (int i = tid; i < 64 * 64; i += 256) {
        int q = i >> 6, n = i & 63;
        const short* rowp = xbc + (tbase + q) * CONVD + DINNER;
        BsB[q * 72 + n] = rowp[n];
        CsB[q * 72 + n] = rowp[DSTATE + n];
    }
    acsS[wave][lane] = acs_g[(((size_t)(b * NH + h0 + wave)) * 64 + c) * 64 + lane];
    __syncthreads();

    // M = C . B^T : wave owns q-strip of 16 rows, kept in regs
    f32x4 macc[4];
    {
        bf16x8 aw0 = *(const bf16x8*)&CsB[(wave * 16 + lr) * 72 + lg * 8];
        bf16x8 aw1 = *(const bf16x8*)&CsB[(wave * 16 + lr) * 72 + 32 + lg * 8];
        #pragma unroll
        for (int ct = 0; ct < 4; ct++) {
            bf16x8 b0 = *(const bf16x8*)&BsB[(ct * 16 + lr) * 72 + lg * 8];
            bf16x8 b1 = *(const bf16x8*)&BsB[(ct * 16 + lr) * 72 + 32 + lg * 8];
            f32x4 z = {0.f, 0.f, 0.f, 0.f};
            z = __builtin_amdgcn_mfma_f32_16x16x32_bf16(aw0, b0, z, 0, 0, 0);
            z = __builtin_amdgcn_mfma_f32_16x16x32_bf16(aw1, b1, z, 0, 0, 0);
            macc[ct] = z;
        }
    }

    for (int hh = 0; hh < HGRP; hh++) {
        int h = h0 + hh;
        // W[q][k] = tril(M) * exp(acs[q]-acs[k])
        #pragma unroll
        for (int ct = 0; ct < 4; ct++) {
            int k = ct * 16 + lr;
            #pragma unroll
            for (int r = 0; r < 4; r++) {
                int q = wave * 16 + lg * 4 + r;
                float wv = 0.f;
                if (k <= q) wv = macc[ct][r] * __expf(acsS[hh][q] - acsS[hh][k]);
                float wo = __shfl_xor(wv, 1);
                if (!(lr & 1))
                    *(unsigned*)&Wsh[q * 72 + k] = cvtpk(wv, wo);
            }
        }
        // Xt[p][k] = x * dt ; Pt[p][n] = prev (bf16 from scan)
        for (int i = tid; i < 2048; i += 256) {
            int p = i & 31, k = i >> 5;
            float xv = bf2f(xbc[(tbase + k) * CONVD + h * HD + p]);
            XtS[p * 72 + k] = (short)f2bf(xv * dts[(tbase + k) * NH + h]);
        }
        size_t sbase = ((size_t)bc * NH + h) * 2048;
        for (int i = tid; i < 2048; i += 256)
            Pt[(i >> 6) * 72 + (i & 63)] = st16[sbase + i];
        __syncthreads();
        float eq[4];
        #pragma unroll
        for (int r = 0; r < 4; r++) eq[r] = __expf(acsS[hh][wave * 16 + lg * 4 + r]);
        float dsk = D_skip[h];
        bf16x8 wa0 = *(const bf16x8*)&Wsh[(wave * 16 + lr) * 72 + lg * 8];
        bf16x8 wa1 = *(const bf16x8*)&Wsh[(wave * 16 + lr) * 72 + 32 + lg * 8];
        bf16x8 ca0 = *(const bf16x8*)&CsB[(wave * 16 + lr) * 72 + lg * 8];
        bf16x8 ca1 = *(const bf16x8*)&CsB[(wave * 16 + lr) * 72 + 32 + lg * 8];
        #pragma unroll
        for (int pt = 0; pt < 2; pt++) {
            bf16x8 xb0 = *(const bf16x8*)&XtS[(pt * 16 + lr) * 72 + lg * 8];
            bf16x8 xb1 = *(const bf16x8*)&XtS[(pt * 16 + lr) * 72 + 32 + lg * 8];
            f32x4 zd = {0.f, 0.f, 0.f, 0.f};
            zd = __builtin_amdgcn_mfma_f32_16x16x32_bf16(wa0, xb0, zd, 0, 0, 0);
            zd = __builtin_amdgcn_mfma_f32_16x16x32_bf16(wa1, xb1, zd, 0, 0, 0);
            bf16x8 pb0 = *(const bf16x8*)&Pt[(pt * 16 + lr) * 72 + lg * 8];
            bf16x8 pb1 = *(const bf16x8*)&Pt[(pt * 16 + lr) * 72 + 32 + lg * 8];
            f32x4 zo = {0.f, 0.f, 0.f, 0.f};
            zo = __builtin_amdgcn_mfma_f32_16x16x32_bf16(ca0, pb0, zo, 0, 0, 0);
            zo = __builtin_amdgcn_mfma_f32_16x16x32_bf16(ca1, pb1, zo, 0, 0, 0);
            #pragma unroll
            for (int r = 0; r < 4; r++) {
                int q = wave * 16 + lg * 4 + r;
                int p = pt * 16 + lr;
                float xv = bf2f(xbc[(tbase + q) * CONVD + h * HD + p]);
                Y[((tbase + q) * NH + h) * HD + p] = zd[r] + eq[r] * zo[r] + dsk * xv;
            }
        }
        __syncthreads();
    }
}

// ---------------- gate: Yb = bf16( rmsnorm(Y * silu(z16), gw, 1e-5) ) ----------------
__global__ void k_gate(const float* __restrict__ Y, const short* __restrict__ z16,
                       const float* __restrict__ gw, short* __restrict__ Yb) {
    int t = blockIdx.x;
    int lane = threadIdx.x;  // 64
    const float* yr = Y + (size_t)t * DINNER + lane * 8;
    union { int4 v; short s[8]; } zu;
    zu.v = *(const int4*)(z16 + (size_t)t * DINNER + lane * 8);
    float4 y0 = *(const float4*)yr;
    float4 y1 = *(const float4*)(yr + 4);
    float yv[8] = {y0.x, y0.y, y0.z, y0.w, y1.x, y1.y, y1.z, y1.w};
    float g[8];
    float ss = 0.f;
    #pragma unroll
    for (int i = 0; i < 8; i++) {
        float zf = bf2f(zu.s[i]);
        g[i] = yv[i] * fsilu(zf);
        ss += g[i] * g[i];
    }
    #pragma unroll
    for (int o = 32; o > 0; o >>= 1) ss += __shfl_down(ss, o);
    ss = __shfl(ss, 0);
    float rr = rsqrtf(ss * (1.0f / DINNER) + 1e-5f);
    const float* wr = gw + lane * 8;
    float4 w0 = *(const float4*)wr;
    float4 w1 = *(const float4*)(wr + 4);
    float wv[8] = {w0.x, w0.y, w0.z, w0.w, w1.x, w1.y, w1.z, w1.w};
    union { uint4 v; unsigned u[4]; } ou;
    #pragma unroll
    for (int i = 0; i < 4; i++)
        ou.u[i] = cvtpk(g[2*i] * rr * wv[2*i], g[2*i+1] * rr * wv[2*i+1]);
    *(uint4*)(Yb + (size_t)t * DINNER + lane * 8) = ou.v;
}

extern "C" void kernel_launch(void* const* d_in, const int* in_sizes, int n_in,
                              void* d_out, int out_size, void* d_ws, size_t ws_size,
                              hipStream_t stream) {
    const int*   ids        = (const int*)d_in[0];
    const float* embed_w    = (const float*)d_in[1];
    const float* in_proj_w  = (const float*)d_in[2];
    const float* conv_w     = (const float*)d_in[3];
    const float* conv_b     = (const float*)d_in[4];
    const float* A_log      = (const float*)d_in[5];
    const float* D_skip     = (const float*)d_in[6];
    const float* dt_bias    = (const float*)d_in[7];
    const float* gate_w     = (const float*)d_in[8];
    const float* out_proj_w = (const float*)d_in[9];
    const float* norm_w     = (const float*)d_in[10];
    float* out = (float*)d_out;

    if (ws_size < WS_FLOATS * sizeof(float)) {
        k_diag<<<1, 64, 0, stream>>>(out, (float)(ws_size >> 20));
        return;
    }

    float* ws   = (float*)d_ws;
    short* u16  = (short*)(ws + U16_OFF);
    short* z16  = (short*)(ws + Z16_OFF);
    short* xbc  = (short*)(ws + XBC_OFF);
    float* dts  = ws + DTS_OFF;
    float* acs  = ws + ACS_OFF;
    float* cdec = ws + CDEC_OFF;
    short* Wp   = (short*)(ws + WP_OFF);
    short* Wo   = (short*)(ws + WO_OFF);
    short* We   = (short*)(ws + WE_OFF);
    short* st16 = (short*)(ws + UNION_OFF);      // bf16 states, 33.5 MB
    short* Yb   = (short*)(ws + UNION_OFF);      // aliases st16 (st dead after k_y)
    short* xf16 = (short*)(ws + UNION_OFF + XF_SUB);
    float* Y    = out;

    k_cvt<<<(NPAD * DMODEL + 255) / 256, 256, 0, stream>>>(in_proj_w, Wp, DPROJ * DMODEL, NPAD * DMODEL);
    k_cvt<<<(DMODEL * DINNER + 255) / 256, 256, 0, stream>>>(out_proj_w, Wo, DMODEL * DINNER, DMODEL * DINNER);
    k_cvt<<<(VOCAB * DMODEL + 255) / 256, 256, 0, stream>>>(embed_w, We, VOCAB * DMODEL, VOCAB * DMODEL);
    k_embed<<<TOK, 64, 0, stream>>>(ids, embed_w, norm_w, u16);
    k_gemm_mfma<0><<<dim3(NPAD / 128, TOK / 128), 512, 0, stream>>>(
        u16, Wp, DMODEL, nullptr, z16, xbc, dts, dt_bias, nullptr, nullptr, conv_w, conv_b);
    k_states<<<BATCH * 64 * 4, 256, 0, stream>>>(xbc, dts, A_log, st16, acs, cdec);
    k_scan<<<BATCH * NH * 4, 256, 0, stream>>>((unsigned*)st16, cdec);
    k_y<<<BATCH * 64 * 4, 256, 0, stream>>>(xbc, dts, st16, acs, D_skip, Y);
    k_gate<<<TOK, 64, 0, stream>>>(Y, z16, gate_w, Yb);
    k_gemm_mfma<1><<<dim3(DMODEL / 128, TOK / 128), 512, 0, stream>>>(
        Yb, Wo, DINNER, nullptr, xf16, nullptr, nullptr, nullptr, ids, embed_w, nullptr, nullptr);
    k_gemm_mfma<2><<<dim3(VOCAB / 128, TOK / 128), 512, 0, stream>>>(
        xf16, We, DMODEL, out, nullptr, nullptr, nullptr, nullptr, nullptr, nullptr, nullptr, nullptr);
}

// Round 12
// 253.379 us; speedup vs baseline: 1.6920x; 1.0083x over previous
//
#include <hip/hip_runtime.h>
#include <cstdint>
#include <cstddef>

#define TOK    32768   // B*L
#define BATCH  8
#define SEQ    4096
#define DMODEL 256
#define DINNER 512
#define DSTATE 64
#define NH     16
#define HD     32
#define DPROJ  1168
#define NPAD   1280    // in_proj N padded to 10*128
#define CONVD  640
#define VOCAB  512
#define HGRP   4       // heads per states/y block
#define TS     132     // conv tile LDS stride (shorts)

typedef __attribute__((ext_vector_type(8))) short bf16x8;
typedef __attribute__((ext_vector_type(4))) float f32x4;

__device__ __forceinline__ unsigned short f2bf(float f) {
    unsigned u = __float_as_uint(f);
    u += 0x7fffu + ((u >> 16) & 1u);       // RNE
    return (unsigned short)(u >> 16);
}
__device__ __forceinline__ float bf2f(short s) {
    return __uint_as_float(((unsigned)(unsigned short)s) << 16);
}
// pack two f32 -> two bf16 (RNE) in one instruction
__device__ __forceinline__ unsigned cvtpk(float lo, float hi) {
    unsigned r;
    asm("v_cvt_pk_bf16_f32 %0, %1, %2" : "=v"(r) : "v"(lo), "v"(hi));
    return r;
}
__device__ __forceinline__ float fsilu(float s) {
    return s * __builtin_amdgcn_rcpf(1.f + __expf(-s));
}
__device__ __forceinline__ float sp(float v) {
    return v > 20.f ? v : __logf(1.f + __expf(v));
}

// async global->LDS, 16B per lane; dst must be wave-uniform base (linear lane fill)
__device__ __forceinline__ void gload16(const short* src, short* dst) {
    __builtin_amdgcn_global_load_lds((const __attribute__((address_space(1))) void*)src,
                                     (__attribute__((address_space(3))) void*)dst, 16, 0, 0);
}

// ---------------- ws layout (floats, all 16B aligned) ----------------
#define U16_OFF   0                                    // TOK*256 bf16
#define Z16_OFF   (U16_OFF  + (size_t)TOK*128)         // TOK*512 bf16
#define XBC_OFF   (Z16_OFF  + (size_t)TOK*256)         // TOK*640 bf16
#define DTS_OFF   (XBC_OFF  + (size_t)TOK*320)         // TOK*16 fp32
#define ACS_OFF   (DTS_OFF  + (size_t)TOK*16)
#define CDEC_OFF  (ACS_OFF  + (size_t)BATCH*NH*64*64)
#define WP_OFF    (CDEC_OFF + (size_t)BATCH*NH*64)
#define WO_OFF    (WP_OFF   + 163840)
#define WE_OFF    (WO_OFF   + 65536)
#define UNION_OFF (WE_OFF   + 65536)
// union, 16.78M floats total:
//   [0, TOK*256)        : st16 bf16 (33.5MB)  -> later Yb bf16 + (overlapping in time) nothing
//   [TOK*256, TOK*512)  : Y16 bf16 (33.5MB)   -> later xf16 (overwrites dead Y16)
#define UNION_FL  ((size_t)BATCH*64*NH*2048)
#define Y16_SUB   ((size_t)TOK*256)
#define XF_SUB    ((size_t)TOK*256)
#define WS_FLOATS (UNION_OFF + UNION_FL)

__global__ void k_diag(float* out, float wsmb) {
    if (blockIdx.x == 0 && threadIdx.x == 0) out[0] = wsmb;
}

// ---------------- weight fp32 -> bf16 (+ zero pad) ----------------
__global__ void k_cvt(const float* __restrict__ s, short* __restrict__ d, int nsrc, int ntot) {
    int i = blockIdx.x * 256 + threadIdx.x;
    if (i < ntot) d[i] = (i < nsrc) ? (short)f2bf(s[i]) : (short)0;
}

// ---------------- embed gather + rmsnorm -> u16 (bf16) ----------------
__global__ void k_embed(const int* __restrict__ ids, const float* __restrict__ embed,
                        const float* __restrict__ norm_w, short* __restrict__ u16) {
    int t = blockIdx.x;
    int lane = threadIdx.x;   // 64
    int id = ids[t];
    float4 v = ((const float4*)(embed + (size_t)id * DMODEL))[lane];
    float ss = v.x*v.x + v.y*v.y + v.z*v.z + v.w*v.w;
    #pragma unroll
    for (int o = 32; o > 0; o >>= 1) ss += __shfl_down(ss, o);
    ss = __shfl(ss, 0);
    float r = rsqrtf(ss * (1.0f / DMODEL) + 1e-6f);
    float4 w = ((const float4*)norm_w)[lane];
    unsigned p0 = cvtpk(v.x * r * w.x, v.y * r * w.y);
    unsigned p1 = cvtpk(v.z * r * w.z, v.w * r * w.w);
    ((uint2*)(u16 + (size_t)t * DMODEL))[lane] = make_uint2(p0, p1);
}

// ---------------- bf16 MFMA GEMM: 512 threads (8 waves), 128x128 tile, BK=64 ----------------
// (unchanged from R10/R11 — double-buffered gload_lds, rule-#21 swizzle)
template<int MODE>
__global__ __launch_bounds__(512) void k_gemm_mfma(
    const short* __restrict__ A, const short* __restrict__ B, int K,
    float* __restrict__ outF, short* __restrict__ z16, short* __restrict__ xbc,
    float* __restrict__ dts, const float* __restrict__ dt_bias,
    const int* __restrict__ ids, const float* __restrict__ embed,
    const float* __restrict__ cw, const float* __restrict__ cb) {
    __shared__ __align__(16) short SM[32768];
    int tid = threadIdx.x;
    int m0 = blockIdx.y << 7;
    int n0 = blockIdx.x << 7;
    int wave = tid >> 6, lane = tid & 63;
    int wm = wave >> 1, wn = wave & 1;
    int lr = lane & 15, lg = lane >> 4;
    const f32x4 zer = {0.f, 0.f, 0.f, 0.f};
    f32x4 acc[2][4];
    #pragma unroll
    for (int i = 0; i < 2; i++)
        #pragma unroll
        for (int j = 0; j < 4; j++) acc[i][j] = zer;

    const bool isXBC = (MODE == 0) && (n0 >= 512) && (n0 < 1152);
    const bool atStart = (m0 & (SEQ - 1)) == 0;
    const bool haloLane = isXBC && (wm == 0) && !atStart && (lr < 3);
    f32x4 hacc[4];
    #pragma unroll
    for (int j = 0; j < 4; j++) hacc[j] = zer;
    const bf16x8 hz = {0, 0, 0, 0, 0, 0, 0, 0};
    bf16x8 hc0 = hz, hc1 = hz, hn0 = hz, hn1 = hz;

    const int nK = K >> 6;
    const int slo = lane >> 3;
    const int skb = ((lane & 7) ^ slo) << 3;

    {
        #pragma unroll
        for (int j = 0; j < 2; j++) {
            int row = wave * 16 + j * 8 + slo;
            gload16(A + (size_t)(m0 + row) * K + skb, SM + (wave * 2 + j) * 512);
            gload16(B + (size_t)(n0 + row) * K + skb, SM + 16384 + (wave * 2 + j) * 512);
        }
        if (haloLane) {
            hc0 = *(const bf16x8*)(A + (size_t)(m0 - 3 + lr) * K + lg * 8);
            hc1 = *(const bf16x8*)(A + (size_t)(m0 - 3 + lr) * K + 32 + lg * 8);
        }
    }
    __syncthreads();

    for (int kt = 0; kt < nK; ++kt) {
        if (kt + 1 < nK) {
            int k0 = (kt + 1) << 6;
            int nb = ((kt + 1) & 1) * 8192;
            #pragma unroll
            for (int j = 0; j < 2; j++) {
                int row = wave * 16 + j * 8 + slo;
                gload16(A + (size_t)(m0 + row) * K + k0 + skb, SM + nb + (wave * 2 + j) * 512);
                gload16(B + (size_t)(n0 + row) * K + k0 + skb, SM + 16384 + nb + (wave * 2 + j) * 512);
            }
            if (haloLane) {
                hn0 = *(const bf16x8*)(A + (size_t)(m0 - 3 + lr) * K + k0 + lg * 8);
                hn1 = *(const bf16x8*)(A + (size_t)(m0 - 3 + lr) * K + k0 + 32 + lg * 8);
            }
        }
        const short* CA = SM + (kt & 1) * 8192;
        const short* CB = SM + 16384 + (kt & 1) * 8192;
        #pragma unroll
        for (int kk = 0; kk < 2; kk++) {
            int sw = (((kk << 2) + lg) ^ (lr & 7)) << 3;
            bf16x8 af[2], bfr[4];
            #pragma unroll
            for (int mi = 0; mi < 2; mi++)
                af[mi] = *(const bf16x8*)&CA[(wm * 32 + mi * 16 + lr) * 64 + sw];
            #pragma unroll
            for (int ni = 0; ni < 4; ni++)
                bfr[ni] = *(const bf16x8*)&CB[(wn * 64 + ni * 16 + lr) * 64 + sw];
            #pragma unroll
            for (int mi = 0; mi < 2; mi++)
                #pragma unroll
                for (int ni = 0; ni < 4; ni++)
                    acc[mi][ni] = __builtin_amdgcn_mfma_f32_16x16x32_bf16(af[mi], bfr[ni], acc[mi][ni], 0, 0, 0);
            if (isXBC && wm == 0) {
                bf16x8 h = (kk == 0) ? hc0 : hc1;
                #pragma unroll
                for (int ni = 0; ni < 4; ni++)
                    hacc[ni] = __builtin_amdgcn_mfma_f32_16x16x32_bf16(h, bfr[ni], hacc[ni], 0, 0, 0);
            }
        }
        __syncthreads();
        hc0 = hn0; hc1 = hn1;
    }

    if (isXBC) {
        short* Tile = SM;
        #pragma unroll
        for (int mi = 0; mi < 2; mi++)
            #pragma unroll
            for (int ni = 0; ni < 4; ni++)
                #pragma unroll
                for (int r = 0; r < 4; r++) {
                    int row = wm * 32 + mi * 16 + lg * 4 + r;
                    int col = wn * 64 + ni * 16 + lr;
                    float v = acc[mi][ni][r];
                    float vo = __shfl_xor(v, 1);
                    if (!(lr & 1))
                        *(unsigned*)&Tile[(3 + row) * TS + col] = cvtpk(v, vo);
                }
        if (wm == 0 && lg == 0) {
            #pragma unroll
            for (int ni = 0; ni < 4; ni++)
                #pragma unroll
                for (int r = 0; r < 3; r++)
                    Tile[r * TS + wn * 64 + ni * 16 + lr] = (short)f2bf(hacc[ni][r]);
        }
        __syncthreads();
        int cp = tid & 63, rg = tid >> 6;
        int colb = cp * 2;
        int ch = (n0 - 512) + colb;
        float c0w0 = cw[ch * 4], c0w1 = cw[ch * 4 + 1], c0w2 = cw[ch * 4 + 2], c0w3 = cw[ch * 4 + 3];
        float c1w0 = cw[ch * 4 + 4], c1w1 = cw[ch * 4 + 5], c1w2 = cw[ch * 4 + 6], c1w3 = cw[ch * 4 + 7];
        float b0v = cb[ch], b1v = cb[ch + 1];
        int rbase = rg * 16;
        unsigned w0 = *(const unsigned*)&Tile[(rbase + 0) * TS + colb];
        unsigned w1 = *(const unsigned*)&Tile[(rbase + 1) * TS + colb];
        unsigned w2 = *(const unsigned*)&Tile[(rbase + 2) * TS + colb];
        for (int i = 0; i < 16; i++) {
            unsigned w3 = *(const unsigned*)&Tile[(rbase + i + 3) * TS + colb];
            float s0 = b0v, s1 = b1v;
            s0 = fmaf(bf2f((short)(w0 & 0xffffu)), c0w0, s0); s1 = fmaf(bf2f((short)(w0 >> 16)), c1w0, s1);
            s0 = fmaf(bf2f((short)(w1 & 0xffffu)), c0w1, s0); s1 = fmaf(bf2f((short)(w1 >> 16)), c1w1, s1);
            s0 = fmaf(bf2f((short)(w2 & 0xffffu)), c0w2, s0); s1 = fmaf(bf2f((short)(w2 >> 16)), c1w2, s1);
            s0 = fmaf(bf2f((short)(w3 & 0xffffu)), c0w3, s0); s1 = fmaf(bf2f((short)(w3 >> 16)), c1w3, s1);
            s0 = fsilu(s0);
            s1 = fsilu(s1);
            *(unsigned*)&xbc[(size_t)(m0 + rbase + i) * CONVD + ch] = cvtpk(s0, s1);
            w0 = w1; w1 = w2; w2 = w3;
        }
        return;
    }

    #pragma unroll
    for (int mi = 0; mi < 2; mi++) {
        #pragma unroll
        for (int r = 0; r < 4; r++) {
            int row = m0 + wm * 32 + mi * 16 + lg * 4 + r;
            int id = 0;
            if (MODE == 1) id = ids[row];
            #pragma unroll
            for (int ni = 0; ni < 4; ni++) {
                int col = n0 + wn * 64 + ni * 16 + lr;
                float v = acc[mi][ni][r];
                if (MODE == 0) {
                    if (n0 < 512) {
                        float vo = __shfl_xor(v, 1);
                        if (!(lr & 1))
                            *(unsigned*)&z16[(size_t)row * DINNER + col] = cvtpk(v, vo);
                    } else if (wn == 0 && ni == 0) {
                        dts[(size_t)row * NH + lr] = sp(v + dt_bias[lr]);
                    }
                } else if (MODE == 1) {
                    float vo = __shfl_xor(v, 1);
                    if (!(lr & 1)) {
                        float2 res = *(const float2*)&embed[(size_t)id * DMODEL + col];
                        *(unsigned*)&z16[(size_t)row * DMODEL + col] = cvtpk(v + res.x, vo + res.y);
                    }
                } else {
                    outF[(size_t)row * VOCAB + col] = v;
                }
            }
        }
    }
}

// ---------------- k_states: per (b,c,hg): chunk states (bf16), head-paired ----------------
__global__ __launch_bounds__(256) void k_states(const short* __restrict__ xbc, const float* __restrict__ dts,
                                                const float* __restrict__ A_log,
                                                short* __restrict__ st16,
                                                float* __restrict__ acs_g, float* __restrict__ cdec) {
    __shared__ short BsB[64 * 72];   // B[k][n]
    __shared__ short BT[64 * 72];    // B^T[n][k], built once
    __shared__ short Xd0[32 * 72];   // Xd[p][k] head A
    __shared__ short Xd1[32 * 72];   // Xd[p][k] head B
    __shared__ float dkS[HGRP][64];
    int tid = threadIdx.x;
    int bid = blockIdx.x;
    int hg = bid & 3;
    int bc = bid >> 2;
    int b = bc >> 6, c = bc & 63;
    int h0 = hg * HGRP;
    size_t tbase = (size_t)b * SEQ + (size_t)c * 64;
    int wave = tid >> 6, lane = tid & 63;
    int lr = lane & 15, lg = lane >> 4;

    for (int i = tid; i < 64 * 64; i += 256) {
        int q = i >> 6, n = i & 63;
        BsB[q * 72 + n] = xbc[(tbase + q) * CONVD + DINNER + n];
    }
    {
        int h = h0 + wave;
        float Ah = -__expf(A_log[h]);
        float v = dts[(tbase + lane) * NH + h] * Ah;
        #pragma unroll
        for (int off = 1; off < 64; off <<= 1) {
            float o = __shfl_up(v, off);
            if (lane >= off) v += o;
        }
        acs_g[(((size_t)(b * NH + h)) * 64 + c) * 64 + lane] = v;
        float alast = __shfl(v, 63);
        dkS[wave][lane] = __expf(alast - v);
        if (lane == 0) cdec[(b * NH + h) * 64 + c] = __expf(alast);
    }
    __syncthreads();
    for (int i = tid; i < 64 * 64; i += 256) {
        int k = i >> 6, n = i & 63;
        BT[n * 72 + k] = BsB[k * 72 + n];
    }
    __syncthreads();

    auto do_head = [&](int h, const short* Xd) {
        int ptile = wave & 1;
        bf16x8 a0 = *(const bf16x8*)&Xd[(ptile * 16 + lr) * 72 + lg * 8];
        bf16x8 a1 = *(const bf16x8*)&Xd[(ptile * 16 + lr) * 72 + 32 + lg * 8];
        size_t base = ((size_t)bc * NH + h) * 2048;
        #pragma unroll
        for (int j = 0; j < 2; j++) {
            int nt = (wave >> 1) * 2 + j;
            bf16x8 b0 = *(const bf16x8*)&BT[(nt * 16 + lr) * 72 + lg * 8];
            bf16x8 b1 = *(const bf16x8*)&BT[(nt * 16 + lr) * 72 + 32 + lg * 8];
            f32x4 z = {0.f, 0.f, 0.f, 0.f};
            z = __builtin_amdgcn_mfma_f32_16x16x32_bf16(a0, b0, z, 0, 0, 0);
            z = __builtin_amdgcn_mfma_f32_16x16x32_bf16(a1, b1, z, 0, 0, 0);
            #pragma unroll
            for (int r = 0; r < 4; r++) {
                int p = ptile * 16 + lg * 4 + r;
                float v = z[r];
                float vo = __shfl_xor(v, 1);
                if (!(lr & 1))
                    *(unsigned*)&st16[base + p * 64 + nt * 16 + lr] = cvtpk(v, vo);
            }
        }
    };

    #pragma unroll
    for (int pr = 0; pr < HGRP / 2; pr++) {
        int hhA = pr * 2, hhB = hhA + 1;
        int hA = h0 + hhA, hB = h0 + hhB;
        for (int i = tid; i < 2048; i += 256) {
            int p = i & 31, k = i >> 5;
            float dtA = dts[(tbase + k) * NH + hA];
            float dtB = dts[(tbase + k) * NH + hB];
            Xd0[p * 72 + k] = (short)f2bf(bf2f(xbc[(tbase + k) * CONVD + hA * HD + p]) * dtA * dkS[hhA][k]);
            Xd1[p * 72 + k] = (short)f2bf(bf2f(xbc[(tbase + k) * CONVD + hB * HD + p]) * dtB * dkS[hhB][k]);
        }
        __syncthreads();
        do_head(hA, Xd0);
        do_head(hB, Xd1);
        __syncthreads();
    }
}

// ---------------- k_scan: sequential inter-chunk scan on bf16 states (fp32 accum) ----------------
__global__ __launch_bounds__(256) void k_scan(unsigned* __restrict__ st32, const float* __restrict__ cdec) {
    int bid = blockIdx.x;           // BATCH*NH*4
    int bh = bid >> 2, seg = bid & 3;
    int b = bh >> 4, h = bh & 15;
    int off = seg * 256 + threadIdx.x;   // u32 index within 1024
    float p0 = 0.f, p1 = 0.f;
    for (int c = 0; c < 64; c++) {
        float dec = cdec[bh * 64 + c];
        size_t idx = ((((size_t)b * 64 + c) * NH) + h) * 1024 + off;
        unsigned v = st32[idx];
        float s0 = bf2f((short)(v & 0xffffu));
        float s1 = bf2f((short)(v >> 16));
        st32[idx] = cvtpk(p0, p1);
        p0 = fmaf(dec, p0, s0);
        p1 = fmaf(dec, p1, s1);
    }
}

// ---------------- k_y: Y16 = Y_diag + exp(acs)*(C . prev^T) + D*x, head-paired ----------------
__global__ __launch_bounds__(256) void k_y(const short* __restrict__ xbc, const float* __restrict__ dts,
                                           const short* __restrict__ st16, const float* __restrict__ acs_g,
                                           const float* __restrict__ D_skip, short* __restrict__ Y16) {
    __shared__ short CsB[64 * 72];   // C[q][n], live throughout
    __shared__ short W0[64 * 72];    // B at load; after M: W of even head
    __shared__ short W1[64 * 72];    // W of odd head
    __shared__ short Xt0[32 * 72], Xt1[32 * 72];
    __shared__ short Pt0[32 * 72], Pt1[32 * 72];
    __shared__ float acsS[HGRP][64];
    int tid = threadIdx.x;
    int bid = blockIdx.x;
    int hg = bid & 3;
    int bc = bid >> 2;
    int b = bc >> 6, c = bc & 63;
    int h0 = hg * HGRP;
    size_t tbase = (size_t)b * SEQ + (size_t)c * 64;
    int wave = tid >> 6, lane = tid & 63;
    int lr = lane & 15, lg = lane >> 4;

    for (int i = tid; i < 64 * 64; i += 256) {
        int q = i >> 6, n = i & 63;
        const short* rowp = xbc + (tbase + q) * CONVD + DINNER;
        W0[q * 72 + n]  = rowp[n];            // B
        CsB[q * 72 + n] = rowp[DSTATE + n];   // C
    }
    acsS[wave][lane] = acs_g[(((size_t)(b * NH + h0 + wave)) * 64 + c) * 64 + lane];
    __syncthreads();

    // M = C . B^T : wave owns q-strip of 16 rows, kept in regs
    f32x4 macc[4];
    bf16x8 ca0 = *(const bf16x8*)&CsB[(wave * 16 + lr) * 72 + lg * 8];
    bf16x8 ca1 = *(const bf16x8*)&CsB[(wave * 16 + lr) * 72 + 32 + lg * 8];
    {
        #pragma unroll
        for (int ct = 0; ct < 4; ct++) {
            bf16x8 b0 = *(const bf16x8*)&W0[(ct * 16 + lr) * 72 + lg * 8];
            bf16x8 b1 = *(const bf16x8*)&W0[(ct * 16 + lr) * 72 + 32 + lg * 8];
            f32x4 z = {0.f, 0.f, 0.f, 0.f};
            z = __builtin_amdgcn_mfma_f32_16x16x32_bf16(ca0, b0, z, 0, 0, 0);
            z = __builtin_amdgcn_mfma_f32_16x16x32_bf16(ca1, b1, z, 0, 0, 0);
            macc[ct] = z;
        }
    }
    __syncthreads();   // all waves done reading B (W0 space) before W build

    auto build_w = [&](int hh, short* Wb) {
        #pragma unroll
        for (int ct = 0; ct < 4; ct++) {
            int k = ct * 16 + lr;
            #pragma unroll
            for (int r = 0; r < 4; r++) {
                int q = wave * 16 + lg * 4 + r;
                float wv = 0.f;
                if (k <= q) wv = macc[ct][r] * __expf(acsS[hh][q] - acsS[hh][k]);
                float wo = __shfl_xor(wv, 1);
                if (!(lr & 1))
                    *(unsigned*)&Wb[q * 72 + k] = cvtpk(wv, wo);
            }
        }
    };
    auto do_head = [&](int h, int hh, const short* Wb, const short* Xt, const short* Pt) {
        float eq[4];
        #pragma unroll
        for (int r = 0; r < 4; r++) eq[r] = __expf(acsS[hh][wave * 16 + lg * 4 + r]);
        float dsk = D_skip[h];
        bf16x8 wa0 = *(const bf16x8*)&Wb[(wave * 16 + lr) * 72 + lg * 8];
        bf16x8 wa1 = *(const bf16x8*)&Wb[(wave * 16 + lr) * 72 + 32 + lg * 8];
        #pragma unroll
        for (int pt = 0; pt < 2; pt++) {
            bf16x8 xb0 = *(const bf16x8*)&Xt[(pt * 16 + lr) * 72 + lg * 8];
            bf16x8 xb1 = *(const bf16x8*)&Xt[(pt * 16 + lr) * 72 + 32 + lg * 8];
            f32x4 zd = {0.f, 0.f, 0.f, 0.f};
            zd = __builtin_amdgcn_mfma_f32_16x16x32_bf16(wa0, xb0, zd, 0, 0, 0);
            zd = __builtin_amdgcn_mfma_f32_16x16x32_bf16(wa1, xb1, zd, 0, 0, 0);
            bf16x8 pb0 = *(const bf16x8*)&Pt[(pt * 16 + lr) * 72 + lg * 8];
            bf16x8 pb1 = *(const bf16x8*)&Pt[(pt * 16 + lr) * 72 + 32 + lg * 8];
            f32x4 zo = {0.f, 0.f, 0.f, 0.f};
            zo = __builtin_amdgcn_mfma_f32_16x16x32_bf16(ca0, pb0, zo, 0, 0, 0);
            zo = __builtin_amdgcn_mfma_f32_16x16x32_bf16(ca1, pb1, zo, 0, 0, 0);
            #pragma unroll
            for (int r = 0; r < 4; r++) {
                int q = wave * 16 + lg * 4 + r;
                int p = pt * 16 + lr;
                float xv = bf2f(xbc[(tbase + q) * CONVD + h * HD + p]);
                float v = zd[r] + eq[r] * zo[r] + dsk * xv;
                float vo = __shfl_xor(v, 1);
                if (!(lr & 1))
                    *(unsigned*)&Y16[((tbase + q) * NH + h) * HD + p] = cvtpk(v, vo);
            }
        }
    };

    #pragma unroll
    for (int pr = 0; pr < HGRP / 2; pr++) {
        int hhA = pr * 2, hhB = hhA + 1;
        int hA = h0 + hhA, hB = h0 + hhB;
        build_w(hhA, W0);
        build_w(hhB, W1);
        for (int i = tid; i < 2048; i += 256) {
            int p = i & 31, k = i >> 5;
            float dtA = dts[(tbase + k) * NH + hA];
            float dtB = dts[(tbase + k) * NH + hB];
            Xt0[p * 72 + k] = (short)f2bf(bf2f(xbc[(tbase + k) * CONVD + hA * HD + p]) * dtA);
            Xt1[p * 72 + k] = (short)f2bf(bf2f(xbc[(tbase + k) * CONVD + hB * HD + p]) * dtB);
        }
        size_t sbA = ((size_t)bc * NH + hA) * 2048;
        for (int i = tid; i < 2048; i += 256) {
            Pt0[(i >> 6) * 72 + (i & 63)] = st16[sbA + i];
            Pt1[(i >> 6) * 72 + (i & 63)] = st16[sbA + 2048 + i];
        }
        __syncthreads();
        do_head(hA, hhA, W0, Xt0, Pt0);
        do_head(hB, hhB, W1, Xt1, Pt1);
        __syncthreads();
    }
}

// ---------------- gate: Yb = bf16( rmsnorm(Y16 * silu(z16), gw, 1e-5) ) ----------------
__global__ void k_gate(const short* __restrict__ Y16, const short* __restrict__ z16,
                       const float* __restrict__ gw, short* __restrict__ Yb) {
    int t = blockIdx.x;
    int lane = threadIdx.x;  // 64
    union { int4 v; short s[8]; } zu, yu;
    zu.v = *(const int4*)(z16 + (size_t)t * DINNER + lane * 8);
    yu.v = *(const int4*)(Y16 + (size_t)t * DINNER + lane * 8);
    float g[8];
    float ss = 0.f;
    #pragma unroll
    for (int i = 0; i < 8; i++) {
        float zf = bf2f(zu.s[i]);
        g[i] = bf2f(yu.s[i]) * fsilu(zf);
        ss += g[i] * g[i];
    }
    #pragma unroll
    for (int o = 32; o > 0; o >>= 1) ss += __shfl_down(ss, o);
    ss = __shfl(ss, 0);
    float rr = rsqrtf(ss * (1.0f / DINNER) + 1e-5f);
    const float* wr = gw + lane * 8;
    float4 w0 = *(const float4*)wr;
    float4 w1 = *(const float4*)(wr + 4);
    float wv[8] = {w0.x, w0.y, w0.z, w0.w, w1.x, w1.y, w1.z, w1.w};
    union { uint4 v; unsigned u[4]; } ou;
    #pragma unroll
    for (int i = 0; i < 4; i++)
        ou.u[i] = cvtpk(g[2*i] * rr * wv[2*i], g[2*i+1] * rr * wv[2*i+1]);
    *(uint4*)(Yb + (size_t)t * DINNER + lane * 8) = ou.v;
}

extern "C" void kernel_launch(void* const* d_in, const int* in_sizes, int n_in,
                              void* d_out, int out_size, void* d_ws, size_t ws_size,
                              hipStream_t stream) {
    const int*   ids        = (const int*)d_in[0];
    const float* embed_w    = (const float*)d_in[1];
    const float* in_proj_w  = (const float*)d_in[2];
    const float* conv_w     = (const float*)d_in[3];
    const float* conv_b     = (const float*)d_in[4];
    const float* A_log      = (const float*)d_in[5];
    const float* D_skip     = (const float*)d_in[6];
    const float* dt_bias    = (const float*)d_in[7];
    const float* gate_w     = (const float*)d_in[8];
    const float* out_proj_w = (const float*)d_in[9];
    const float* norm_w     = (const float*)d_in[10];
    float* out = (float*)d_out;

    if (ws_size < WS_FLOATS * sizeof(float)) {
        k_diag<<<1, 64, 0, stream>>>(out, (float)(ws_size >> 20));
        return;
    }

    float* ws   = (float*)d_ws;
    short* u16  = (short*)(ws + U16_OFF);
    short* z16  = (short*)(ws + Z16_OFF);
    short* xbc  = (short*)(ws + XBC_OFF);
    float* dts  = ws + DTS_OFF;
    float* acs  = ws + ACS_OFF;
    float* cdec = ws + CDEC_OFF;
    short* Wp   = (short*)(ws + WP_OFF);
    short* Wo   = (short*)(ws + WO_OFF);
    short* We   = (short*)(ws + WE_OFF);
    short* st16 = (short*)(ws + UNION_OFF);                 // bf16 states, 33.5 MB
    short* Y16  = (short*)(ws + UNION_OFF + Y16_SUB);       // bf16 Y, 33.5 MB
    short* Yb   = (short*)(ws + UNION_OFF);                 // gate out, aliases dead st16
    short* xf16 = (short*)(ws + UNION_OFF + XF_SUB);        // aliases dead Y16
    float* Y    = out;
    (void)Y;

    k_cvt<<<(NPAD * DMODEL + 255) / 256, 256, 0, stream>>>(in_proj_w, Wp, DPROJ * DMODEL, NPAD * DMODEL);
    k_cvt<<<(DMODEL * DINNER + 255) / 256, 256, 0, stream>>>(out_proj_w, Wo, DMODEL * DINNER, DMODEL * DINNER);
    k_cvt<<<(VOCAB * DMODEL + 255) / 256, 256, 0, stream>>>(embed_w, We, VOCAB * DMODEL, VOCAB * DMODEL);
    k_embed<<<TOK, 64, 0, stream>>>(ids, embed_w, norm_w, u16);
    k_gemm_mfma<0><<<dim3(NPAD / 128, TOK / 128), 512, 0, stream>>>(
        u16, Wp, DMODEL, nullptr, z16, xbc, dts, dt_bias, nullptr, nullptr, conv_w, conv_b);
    k_states<<<BATCH * 64 * 4, 256, 0, stream>>>(xbc, dts, A_log, st16, acs, cdec);
    k_scan<<<BATCH * NH * 4, 256, 0, stream>>>((unsigned*)st16, cdec);
    k_y<<<BATCH * 64 * 4, 256, 0, stream>>>(xbc, dts, st16, acs, D_skip, Y16);
    k_gate<<<TOK, 64, 0, stream>>>(Y16, z16, gate_w, Yb);
    k_gemm_mfma<1><<<dim3(DMODEL / 128, TOK / 128), 512, 0, stream>>>(
        Yb, Wo, DINNER, nullptr, xf16, nullptr, nullptr, nullptr, ids, embed_w, nullptr, nullptr);
    k_gemm_mfma<2><<<dim3(VOCAB / 128, TOK / 128), 512, 0, stream>>>(
        xf16, We, DMODEL, out, nullptr, nullptr, nullptr, nullptr, nullptr, nullptr, nullptr, nullptr);
}

// Round 13
// 246.589 us; speedup vs baseline: 1.7386x; 1.0275x over previous
//
#include <hip/hip_runtime.h>
#include <cstdint>
#include <cstddef>

#define TOK    32768   // B*L
#define BATCH  8
#define SEQ    4096
#define DMODEL 256
#define DINNER 512
#define DSTATE 64
#define NH     16
#define HD     32
#define DPROJ  1168
#define NPAD   1280    // in_proj N padded to 10*128
#define CONVD  640
#define VOCAB  512
#define HGRP   4       // heads per states/y block
#define TS     132     // conv tile LDS stride (shorts)

typedef __attribute__((ext_vector_type(8))) short bf16x8;
typedef __attribute__((ext_vector_type(4))) float f32x4;

__device__ __forceinline__ unsigned short f2bf(float f) {
    unsigned u = __float_as_uint(f);
    u += 0x7fffu + ((u >> 16) & 1u);       // RNE
    return (unsigned short)(u >> 16);
}
__device__ __forceinline__ float bf2f(short s) {
    return __uint_as_float(((unsigned)(unsigned short)s) << 16);
}
// pack two f32 -> two bf16 (RNE) in one instruction
__device__ __forceinline__ unsigned cvtpk(float lo, float hi) {
    unsigned r;
    asm("v_cvt_pk_bf16_f32 %0, %1, %2" : "=v"(r) : "v"(lo), "v"(hi));
    return r;
}
__device__ __forceinline__ float fsilu(float s) {
    return s * __builtin_amdgcn_rcpf(1.f + __expf(-s));
}
__device__ __forceinline__ float sp(float v) {
    return v > 20.f ? v : __logf(1.f + __expf(v));
}

// async global->LDS, 16B per lane; dst must be wave-uniform base (linear lane fill)
__device__ __forceinline__ void gload16(const short* src, short* dst) {
    __builtin_amdgcn_global_load_lds((const __attribute__((address_space(1))) void*)src,
                                     (__attribute__((address_space(3))) void*)dst, 16, 0, 0);
}

// ---------------- ws layout (floats, all 16B aligned) ----------------
#define U16_OFF   0                                    // TOK*256 bf16
#define Z16_OFF   (U16_OFF  + (size_t)TOK*128)         // TOK*512 bf16
#define XBC_OFF   (Z16_OFF  + (size_t)TOK*256)         // TOK*640 bf16
#define DTS_OFF   (XBC_OFF  + (size_t)TOK*320)         // TOK*16 fp32
#define ACS_OFF   (DTS_OFF  + (size_t)TOK*16)
#define CDEC_OFF  (ACS_OFF  + (size_t)BATCH*NH*64*64)
#define WP_OFF    (CDEC_OFF + (size_t)BATCH*NH*64)
#define WO_OFF    (WP_OFF   + 163840)
#define WE_OFF    (WO_OFF   + 65536)
#define UNION_OFF (WE_OFF   + 65536)
// union, 16.78M floats total:
//   [0, TOK*256)        : st16 bf16 (33.5MB)  -> later Yb bf16
//   [TOK*256, TOK*512)  : Y16 bf16 (33.5MB)   -> later xf16 (overwrites dead Y16)
#define UNION_FL  ((size_t)BATCH*64*NH*2048)
#define Y16_SUB   ((size_t)TOK*256)
#define XF_SUB    ((size_t)TOK*256)
#define WS_FLOATS (UNION_OFF + UNION_FL)

__global__ void k_diag(float* out, float wsmb) {
    if (blockIdx.x == 0 && threadIdx.x == 0) out[0] = wsmb;
}

// ---------------- weight fp32 -> bf16 (+ zero pad) ----------------
__global__ void k_cvt(const float* __restrict__ s, short* __restrict__ d, int nsrc, int ntot) {
    int i = blockIdx.x * 256 + threadIdx.x;
    if (i < ntot) d[i] = (i < nsrc) ? (short)f2bf(s[i]) : (short)0;
}

// ---------------- embed gather + rmsnorm -> u16 (bf16) ----------------
__global__ void k_embed(const int* __restrict__ ids, const float* __restrict__ embed,
                        const float* __restrict__ norm_w, short* __restrict__ u16) {
    int t = blockIdx.x;
    int lane = threadIdx.x;   // 64
    int id = ids[t];
    float4 v = ((const float4*)(embed + (size_t)id * DMODEL))[lane];
    float ss = v.x*v.x + v.y*v.y + v.z*v.z + v.w*v.w;
    #pragma unroll
    for (int o = 32; o > 0; o >>= 1) ss += __shfl_down(ss, o);
    ss = __shfl(ss, 0);
    float r = rsqrtf(ss * (1.0f / DMODEL) + 1e-6f);
    float4 w = ((const float4*)norm_w)[lane];
    unsigned p0 = cvtpk(v.x * r * w.x, v.y * r * w.y);
    unsigned p1 = cvtpk(v.z * r * w.z, v.w * r * w.w);
    ((uint2*)(u16 + (size_t)t * DMODEL))[lane] = make_uint2(p0, p1);
}

// ---------------- bf16 MFMA GEMM: 512 threads (8 waves), 128x128 tile, BK=64 ----------------
// (unchanged — double-buffered gload_lds, rule-#21 swizzle)
template<int MODE>
__global__ __launch_bounds__(512) void k_gemm_mfma(
    const short* __restrict__ A, const short* __restrict__ B, int K,
    float* __restrict__ outF, short* __restrict__ z16, short* __restrict__ xbc,
    float* __restrict__ dts, const float* __restrict__ dt_bias,
    const int* __restrict__ ids, const float* __restrict__ embed,
    const float* __restrict__ cw, const float* __restrict__ cb) {
    __shared__ __align__(16) short SM[32768];
    int tid = threadIdx.x;
    int m0 = blockIdx.y << 7;
    int n0 = blockIdx.x << 7;
    int wave = tid >> 6, lane = tid & 63;
    int wm = wave >> 1, wn = wave & 1;
    int lr = lane & 15, lg = lane >> 4;
    const f32x4 zer = {0.f, 0.f, 0.f, 0.f};
    f32x4 acc[2][4];
    #pragma unroll
    for (int i = 0; i < 2; i++)
        #pragma unroll
        for (int j = 0; j < 4; j++) acc[i][j] = zer;

    const bool isXBC = (MODE == 0) && (n0 >= 512) && (n0 < 1152);
    const bool atStart = (m0 & (SEQ - 1)) == 0;
    const bool haloLane = isXBC && (wm == 0) && !atStart && (lr < 3);
    f32x4 hacc[4];
    #pragma unroll
    for (int j = 0; j < 4; j++) hacc[j] = zer;
    const bf16x8 hz = {0, 0, 0, 0, 0, 0, 0, 0};
    bf16x8 hc0 = hz, hc1 = hz, hn0 = hz, hn1 = hz;

    const int nK = K >> 6;
    const int slo = lane >> 3;
    const int skb = ((lane & 7) ^ slo) << 3;

    {
        #pragma unroll
        for (int j = 0; j < 2; j++) {
            int row = wave * 16 + j * 8 + slo;
            gload16(A + (size_t)(m0 + row) * K + skb, SM + (wave * 2 + j) * 512);
            gload16(B + (size_t)(n0 + row) * K + skb, SM + 16384 + (wave * 2 + j) * 512);
        }
        if (haloLane) {
            hc0 = *(const bf16x8*)(A + (size_t)(m0 - 3 + lr) * K + lg * 8);
            hc1 = *(const bf16x8*)(A + (size_t)(m0 - 3 + lr) * K + 32 + lg * 8);
        }
    }
    __syncthreads();

    for (int kt = 0; kt < nK; ++kt) {
        if (kt + 1 < nK) {
            int k0 = (kt + 1) << 6;
            int nb = ((kt + 1) & 1) * 8192;
            #pragma unroll
            for (int j = 0; j < 2; j++) {
                int row = wave * 16 + j * 8 + slo;
                gload16(A + (size_t)(m0 + row) * K + k0 + skb, SM + nb + (wave * 2 + j) * 512);
                gload16(B + (size_t)(n0 + row) * K + k0 + skb, SM + 16384 + nb + (wave * 2 + j) * 512);
            }
            if (haloLane) {
                hn0 = *(const bf16x8*)(A + (size_t)(m0 - 3 + lr) * K + k0 + lg * 8);
                hn1 = *(const bf16x8*)(A + (size_t)(m0 - 3 + lr) * K + k0 + 32 + lg * 8);
            }
        }
        const short* CA = SM + (kt & 1) * 8192;
        const short* CB = SM + 16384 + (kt & 1) * 8192;
        #pragma unroll
        for (int kk = 0; kk < 2; kk++) {
            int sw = (((kk << 2) + lg) ^ (lr & 7)) << 3;
            bf16x8 af[2], bfr[4];
            #pragma unroll
            for (int mi = 0; mi < 2; mi++)
                af[mi] = *(const bf16x8*)&CA[(wm * 32 + mi * 16 + lr) * 64 + sw];
            #pragma unroll
            for (int ni = 0; ni < 4; ni++)
                bfr[ni] = *(const bf16x8*)&CB[(wn * 64 + ni * 16 + lr) * 64 + sw];
            #pragma unroll
            for (int mi = 0; mi < 2; mi++)
                #pragma unroll
                for (int ni = 0; ni < 4; ni++)
                    acc[mi][ni] = __builtin_amdgcn_mfma_f32_16x16x32_bf16(af[mi], bfr[ni], acc[mi][ni], 0, 0, 0);
            if (isXBC && wm == 0) {
                bf16x8 h = (kk == 0) ? hc0 : hc1;
                #pragma unroll
                for (int ni = 0; ni < 4; ni++)
                    hacc[ni] = __builtin_amdgcn_mfma_f32_16x16x32_bf16(h, bfr[ni], hacc[ni], 0, 0, 0);
            }
        }
        __syncthreads();
        hc0 = hn0; hc1 = hn1;
    }

    if (isXBC) {
        short* Tile = SM;
        #pragma unroll
        for (int mi = 0; mi < 2; mi++)
            #pragma unroll
            for (int ni = 0; ni < 4; ni++)
                #pragma unroll
                for (int r = 0; r < 4; r++) {
                    int row = wm * 32 + mi * 16 + lg * 4 + r;
                    int col = wn * 64 + ni * 16 + lr;
                    float v = acc[mi][ni][r];
                    float vo = __shfl_xor(v, 1);
                    if (!(lr & 1))
                        *(unsigned*)&Tile[(3 + row) * TS + col] = cvtpk(v, vo);
                }
        if (wm == 0 && lg == 0) {
            #pragma unroll
            for (int ni = 0; ni < 4; ni++)
                #pragma unroll
                for (int r = 0; r < 3; r++)
                    Tile[r * TS + wn * 64 + ni * 16 + lr] = (short)f2bf(hacc[ni][r]);
        }
        __syncthreads();
        int cp = tid & 63, rg = tid >> 6;
        int colb = cp * 2;
        int ch = (n0 - 512) + colb;
        float c0w0 = cw[ch * 4], c0w1 = cw[ch * 4 + 1], c0w2 = cw[ch * 4 + 2], c0w3 = cw[ch * 4 + 3];
        float c1w0 = cw[ch * 4 + 4], c1w1 = cw[ch * 4 + 5], c1w2 = cw[ch * 4 + 6], c1w3 = cw[ch * 4 + 7];
        float b0v = cb[ch], b1v = cb[ch + 1];
        int rbase = rg * 16;
        unsigned w0 = *(const unsigned*)&Tile[(rbase + 0) * TS + colb];
        unsigned w1 = *(const unsigned*)&Tile[(rbase + 1) * TS + colb];
        unsigned w2 = *(const unsigned*)&Tile[(rbase + 2) * TS + colb];
        for (int i = 0; i < 16; i++) {
            unsigned w3 = *(const unsigned*)&Tile[(rbase + i + 3) * TS + colb];
            float s0 = b0v, s1 = b1v;
            s0 = fmaf(bf2f((short)(w0 & 0xffffu)), c0w0, s0); s1 = fmaf(bf2f((short)(w0 >> 16)), c1w0, s1);
            s0 = fmaf(bf2f((short)(w1 & 0xffffu)), c0w1, s0); s1 = fmaf(bf2f((short)(w1 >> 16)), c1w1, s1);
            s0 = fmaf(bf2f((short)(w2 & 0xffffu)), c0w2, s0); s1 = fmaf(bf2f((short)(w2 >> 16)), c1w2, s1);
            s0 = fmaf(bf2f((short)(w3 & 0xffffu)), c0w3, s0); s1 = fmaf(bf2f((short)(w3 >> 16)), c1w3, s1);
            s0 = fsilu(s0);
            s1 = fsilu(s1);
            *(unsigned*)&xbc[(size_t)(m0 + rbase + i) * CONVD + ch] = cvtpk(s0, s1);
            w0 = w1; w1 = w2; w2 = w3;
        }
        return;
    }

    #pragma unroll
    for (int mi = 0; mi < 2; mi++) {
        #pragma unroll
        for (int r = 0; r < 4; r++) {
            int row = m0 + wm * 32 + mi * 16 + lg * 4 + r;
            int id = 0;
            if (MODE == 1) id = ids[row];
            #pragma unroll
            for (int ni = 0; ni < 4; ni++) {
                int col = n0 + wn * 64 + ni * 16 + lr;
                float v = acc[mi][ni][r];
                if (MODE == 0) {
                    if (n0 < 512) {
                        float vo = __shfl_xor(v, 1);
                        if (!(lr & 1))
                            *(unsigned*)&z16[(size_t)row * DINNER + col] = cvtpk(v, vo);
                    } else if (wn == 0 && ni == 0) {
                        dts[(size_t)row * NH + lr] = sp(v + dt_bias[lr]);
                    }
                } else if (MODE == 1) {
                    float vo = __shfl_xor(v, 1);
                    if (!(lr & 1)) {
                        float2 res = *(const float2*)&embed[(size_t)id * DMODEL + col];
                        *(unsigned*)&z16[(size_t)row * DMODEL + col] = cvtpk(v + res.x, vo + res.y);
                    }
                } else {
                    outF[(size_t)row * VOCAB + col] = v;
                }
            }
        }
    }
}

// ---------------- k_states: per (b,c,hg): chunk states (bf16), head-paired ----------------
__global__ __launch_bounds__(256) void k_states(const short* __restrict__ xbc, const float* __restrict__ dts,
                                                const float* __restrict__ A_log,
                                                short* __restrict__ st16,
                                                float* __restrict__ acs_g, float* __restrict__ cdec) {
    __shared__ short BsB[64 * 72];   // B[k][n]
    __shared__ short BT[64 * 72];    // B^T[n][k], built once
    __shared__ short Xd0[32 * 72];   // Xd[p][k] head A
    __shared__ short Xd1[32 * 72];   // Xd[p][k] head B
    __shared__ float dkS[HGRP][64];
    int tid = threadIdx.x;
    int bid = blockIdx.x;
    int hg = bid & 3;
    int bc = bid >> 2;
    int b = bc >> 6, c = bc & 63;
    int h0 = hg * HGRP;
    size_t tbase = (size_t)b * SEQ + (size_t)c * 64;
    int wave = tid >> 6, lane = tid & 63;
    int lr = lane & 15, lg = lane >> 4;

    for (int i = tid; i < 64 * 64; i += 256) {
        int q = i >> 6, n = i & 63;
        BsB[q * 72 + n] = xbc[(tbase + q) * CONVD + DINNER + n];
    }
    {
        int h = h0 + wave;
        float Ah = -__expf(A_log[h]);
        float v = dts[(tbase + lane) * NH + h] * Ah;
        #pragma unroll
        for (int off = 1; off < 64; off <<= 1) {
            float o = __shfl_up(v, off);
            if (lane >= off) v += o;
        }
        acs_g[(((size_t)(b * NH + h)) * 64 + c) * 64 + lane] = v;
        float alast = __shfl(v, 63);
        dkS[wave][lane] = __expf(alast - v);
        if (lane == 0) cdec[(b * NH + h) * 64 + c] = __expf(alast);
    }
    __syncthreads();
    for (int i = tid; i < 64 * 64; i += 256) {
        int k = i >> 6, n = i & 63;
        BT[n * 72 + k] = BsB[k * 72 + n];
    }
    __syncthreads();

    auto do_head = [&](int h, const short* Xd) {
        int ptile = wave & 1;
        bf16x8 a0 = *(const bf16x8*)&Xd[(ptile * 16 + lr) * 72 + lg * 8];
        bf16x8 a1 = *(const bf16x8*)&Xd[(ptile * 16 + lr) * 72 + 32 + lg * 8];
        size_t base = ((size_t)bc * NH + h) * 2048;
        #pragma unroll
        for (int j = 0; j < 2; j++) {
            int nt = (wave >> 1) * 2 + j;
            bf16x8 b0 = *(const bf16x8*)&BT[(nt * 16 + lr) * 72 + lg * 8];
            bf16x8 b1 = *(const bf16x8*)&BT[(nt * 16 + lr) * 72 + 32 + lg * 8];
            f32x4 z = {0.f, 0.f, 0.f, 0.f};
            z = __builtin_amdgcn_mfma_f32_16x16x32_bf16(a0, b0, z, 0, 0, 0);
            z = __builtin_amdgcn_mfma_f32_16x16x32_bf16(a1, b1, z, 0, 0, 0);
            #pragma unroll
            for (int r = 0; r < 4; r++) {
                int p = ptile * 16 + lg * 4 + r;
                float v = z[r];
                float vo = __shfl_xor(v, 1);
                if (!(lr & 1))
                    *(unsigned*)&st16[base + p * 64 + nt * 16 + lr] = cvtpk(v, vo);
            }
        }
    };

    #pragma unroll
    for (int pr = 0; pr < HGRP / 2; pr++) {
        int hhA = pr * 2, hhB = hhA + 1;
        int hA = h0 + hhA, hB = h0 + hhB;
        for (int i = tid; i < 2048; i += 256) {
            int p = i & 31, k = i >> 5;
            float dtA = dts[(tbase + k) * NH + hA];
            float dtB = dts[(tbase + k) * NH + hB];
            Xd0[p * 72 + k] = (short)f2bf(bf2f(xbc[(tbase + k) * CONVD + hA * HD + p]) * dtA * dkS[hhA][k]);
            Xd1[p * 72 + k] = (short)f2bf(bf2f(xbc[(tbase + k) * CONVD + hB * HD + p]) * dtB * dkS[hhB][k]);
        }
        __syncthreads();
        do_head(hA, Xd0);
        do_head(hB, Xd1);
        __syncthreads();
    }
}

// ---------------- k_scan: sequential inter-chunk scan on bf16 states (fp32 accum) ----------------
__global__ __launch_bounds__(256) void k_scan(unsigned* __restrict__ st32, const float* __restrict__ cdec) {
    int bid = blockIdx.x;           // BATCH*NH*4
    int bh = bid >> 2, seg = bid & 3;
    int b = bh >> 4, h = bh & 15;
    int off = seg * 256 + threadIdx.x;   // u32 index within 1024
    float p0 = 0.f, p1 = 0.f;
    for (int c = 0; c < 64; c++) {
        float dec = cdec[bh * 64 + c];
        size_t idx = ((((size_t)b * 64 + c) * NH) + h) * 1024 + off;
        unsigned v = st32[idx];
        float s0 = bf2f((short)(v & 0xffffu));
        float s1 = bf2f((short)(v >> 16));
        st32[idx] = cvtpk(p0, p1);
        p0 = fmaf(dec, p0, s0);
        p1 = fmaf(dec, p1, s1);
    }
}

// ---------------- k_y: Y16 = Y_diag + exp(acs)*(C . prev^T) + D*x ----------------
// Minimal-LDS single-head loop: W aliases the dead B buffer after M = C.B^T.
// LDS ~28.7 KB -> 5 blocks/CU (occupancy is this kernel's lever, not ILP — R12 lesson).
__global__ __launch_bounds__(256) void k_y(const short* __restrict__ xbc, const float* __restrict__ dts,
                                           const short* __restrict__ st16, const float* __restrict__ acs_g,
                                           const float* __restrict__ D_skip, short* __restrict__ Y16) {
    __shared__ short CsB[64 * 72];   // C[q][n], live throughout
    __shared__ short Wsh[64 * 72];   // B at load; W per head after M
    __shared__ short XtS[32 * 72];   // Xt[p][k] per head
    __shared__ short Pt[32 * 72];    // prev[p][n] per head
    __shared__ float acsS[HGRP][64];
    int tid = threadIdx.x;
    int bid = blockIdx.x;
    int hg = bid & 3;
    int bc = bid >> 2;
    int b = bc >> 6, c = bc & 63;
    int h0 = hg * HGRP;
    size_t tbase = (size_t)b * SEQ + (size_t)c * 64;
    int wave = tid >> 6, lane = tid & 63;
    int lr = lane & 15, lg = lane >> 4;

    for (int i = tid; i < 64 * 64; i += 256) {
        int q = i >> 6, n = i & 63;
        const short* rowp = xbc + (tbase + q) * CONVD + DINNER;
        Wsh[q * 72 + n] = rowp[n];            // B (consumed by M, then reused as W)
        CsB[q * 72 + n] = rowp[DSTATE + n];   // C
    }
    acsS[wave][lane] = acs_g[(((size_t)(b * NH + h0 + wave)) * 64 + c) * 64 + lane];
    __syncthreads();

    // M = C . B^T : wave owns q-strip of 16 rows, kept in regs
    f32x4 macc[4];
    bf16x8 ca0 = *(const bf16x8*)&CsB[(wave * 16 + lr) * 72 + lg * 8];
    bf16x8 ca1 = *(const bf16x8*)&CsB[(wave * 16 + lr) * 72 + 32 + lg * 8];
    {
        #pragma unroll
        for (int ct = 0; ct < 4; ct++) {
            bf16x8 b0 = *(const bf16x8*)&Wsh[(ct * 16 + lr) * 72 + lg * 8];
            bf16x8 b1 = *(const bf16x8*)&Wsh[(ct * 16 + lr) * 72 + 32 + lg * 8];
            f32x4 z = {0.f, 0.f, 0.f, 0.f};
            z = __builtin_amdgcn_mfma_f32_16x16x32_bf16(ca0, b0, z, 0, 0, 0);
            z = __builtin_amdgcn_mfma_f32_16x16x32_bf16(ca1, b1, z, 0, 0, 0);
            macc[ct] = z;
        }
    }
    __syncthreads();   // all waves done reading B before Wsh is overwritten

    for (int hh = 0; hh < HGRP; hh++) {
        int h = h0 + hh;
        // W[q][k] = tril(M) * exp(acs[q]-acs[k])  — wave-local rows of Wsh
        #pragma unroll
        for (int ct = 0; ct < 4; ct++) {
            int k = ct * 16 + lr;
            #pragma unroll
            for (int r = 0; r < 4; r++) {
                int q = wave * 16 + lg * 4 + r;
                float wv = 0.f;
                if (k <= q) wv = macc[ct][r] * __expf(acsS[hh][q] - acsS[hh][k]);
                float wo = __shfl_xor(wv, 1);
                if (!(lr & 1))
                    *(unsigned*)&Wsh[q * 72 + k] = cvtpk(wv, wo);
            }
        }
        // Xt[p][k] = x * dt ; Pt[p][n] = prev (bf16 from scan) — block-wide staging
        for (int i = tid; i < 2048; i += 256) {
            int p = i & 31, k = i >> 5;
            float xv = bf2f(xbc[(tbase + k) * CONVD + h * HD + p]);
            XtS[p * 72 + k] = (short)f2bf(xv * dts[(tbase + k) * NH + h]);
        }
        size_t sbase = ((size_t)bc * NH + h) * 2048;
        for (int i = tid; i < 2048; i += 256)
            Pt[(i >> 6) * 72 + (i & 63)] = st16[sbase + i];
        __syncthreads();
        float eq[4];
        #pragma unroll
        for (int r = 0; r < 4; r++) eq[r] = __expf(acsS[hh][wave * 16 + lg * 4 + r]);
        float dsk = D_skip[h];
        bf16x8 wa0 = *(const bf16x8*)&Wsh[(wave * 16 + lr) * 72 + lg * 8];
        bf16x8 wa1 = *(const bf16x8*)&Wsh[(wave * 16 + lr) * 72 + 32 + lg * 8];
        #pragma unroll
        for (int pt = 0; pt < 2; pt++) {
            bf16x8 xb0 = *(const bf16x8*)&XtS[(pt * 16 + lr) * 72 + lg * 8];
            bf16x8 xb1 = *(const bf16x8*)&XtS[(pt * 16 + lr) * 72 + 32 + lg * 8];
            f32x4 zd = {0.f, 0.f, 0.f, 0.f};
            zd = __builtin_amdgcn_mfma_f32_16x16x32_bf16(wa0, xb0, zd, 0, 0, 0);
            zd = __builtin_amdgcn_mfma_f32_16x16x32_bf16(wa1, xb1, zd, 0, 0, 0);
            bf16x8 pb0 = *(const bf16x8*)&Pt[(pt * 16 + lr) * 72 + lg * 8];
            bf16x8 pb1 = *(const bf16x8*)&Pt[(pt * 16 + lr) * 72 + 32 + lg * 8];
            f32x4 zo = {0.f, 0.f, 0.f, 0.f};
            zo = __builtin_amdgcn_mfma_f32_16x16x32_bf16(ca0, pb0, zo, 0, 0, 0);
            zo = __builtin_amdgcn_mfma_f32_16x16x32_bf16(ca1, pb1, zo, 0, 0, 0);
            #pragma unroll
            for (int r = 0; r < 4; r++) {
                int q = wave * 16 + lg * 4 + r;
                int p = pt * 16 + lr;
                float xv = bf2f(xbc[(tbase + q) * CONVD + h * HD + p]);
                float v = zd[r] + eq[r] * zo[r] + dsk * xv;
                float vo = __shfl_xor(v, 1);
                if (!(lr & 1))
                    *(unsigned*)&Y16[((tbase + q) * NH + h) * HD + p] = cvtpk(v, vo);
            }
        }
        __syncthreads();   // protect Wsh/Xt/Pt overwrite next head
    }
}

// ---------------- gate: Yb = bf16( rmsnorm(Y16 * silu(z16), gw, 1e-5) ) ----------------
__global__ void k_gate(const short* __restrict__ Y16, const short* __restrict__ z16,
                       const float* __restrict__ gw, short* __restrict__ Yb) {
    int t = blockIdx.x;
    int lane = threadIdx.x;  // 64
    union { int4 v; short s[8]; } zu, yu;
    zu.v = *(const int4*)(z16 + (size_t)t * DINNER + lane * 8);
    yu.v = *(const int4*)(Y16 + (size_t)t * DINNER + lane * 8);
    float g[8];
    float ss = 0.f;
    #pragma unroll
    for (int i = 0; i < 8; i++) {
        float zf = bf2f(zu.s[i]);
        g[i] = bf2f(yu.s[i]) * fsilu(zf);
        ss += g[i] * g[i];
    }
    #pragma unroll
    for (int o = 32; o > 0; o >>= 1) ss += __shfl_down(ss, o);
    ss = __shfl(ss, 0);
    float rr = rsqrtf(ss * (1.0f / DINNER) + 1e-5f);
    const float* wr = gw + lane * 8;
    float4 w0 = *(const float4*)wr;
    float4 w1 = *(const float4*)(wr + 4);
    float wv[8] = {w0.x, w0.y, w0.z, w0.w, w1.x, w1.y, w1.z, w1.w};
    union { uint4 v; unsigned u[4]; } ou;
    #pragma unroll
    for (int i = 0; i < 4; i++)
        ou.u[i] = cvtpk(g[2*i] * rr * wv[2*i], g[2*i+1] * rr * wv[2*i+1]);
    *(uint4*)(Yb + (size_t)t * DINNER + lane * 8) = ou.v;
}

extern "C" void kernel_launch(void* const* d_in, const int* in_sizes, int n_in,
                              void* d_out, int out_size, void* d_ws, size_t ws_size,
                              hipStream_t stream) {
    const int*   ids        = (const int*)d_in[0];
    const float* embed_w    = (const float*)d_in[1];
    const float* in_proj_w  = (const float*)d_in[2];
    const float* conv_w     = (const float*)d_in[3];
    const float* conv_b     = (const float*)d_in[4];
    const float* A_log      = (const float*)d_in[5];
    const float* D_skip     = (const float*)d_in[6];
    const float* dt_bias    = (const float*)d_in[7];
    const float* gate_w     = (const float*)d_in[8];
    const float* out_proj_w = (const float*)d_in[9];
    const float* norm_w     = (const float*)d_in[10];
    float* out = (float*)d_out;

    if (ws_size < WS_FLOATS * sizeof(float)) {
        k_diag<<<1, 64, 0, stream>>>(out, (float)(ws_size >> 20));
        return;
    }

    float* ws   = (float*)d_ws;
    short* u16  = (short*)(ws + U16_OFF);
    short* z16  = (short*)(ws + Z16_OFF);
    short* xbc  = (short*)(ws + XBC_OFF);
    float* dts  = ws + DTS_OFF;
    float* acs  = ws + ACS_OFF;
    float* cdec = ws + CDEC_OFF;
    short* Wp   = (short*)(ws + WP_OFF);
    short* Wo   = (short*)(ws + WO_OFF);
    short* We   = (short*)(ws + WE_OFF);
    short* st16 = (short*)(ws + UNION_OFF);                 // bf16 states, 33.5 MB
    short* Y16  = (short*)(ws + UNION_OFF + Y16_SUB);       // bf16 Y, 33.5 MB
    short* Yb   = (short*)(ws + UNION_OFF);                 // gate out, aliases dead st16
    short* xf16 = (short*)(ws + UNION_OFF + XF_SUB);        // aliases dead Y16

    k_cvt<<<(NPAD * DMODEL + 255) / 256, 256, 0, stream>>>(in_proj_w, Wp, DPROJ * DMODEL, NPAD * DMODEL);
    k_cvt<<<(DMODEL * DINNER + 255) / 256, 256, 0, stream>>>(out_proj_w, Wo, DMODEL * DINNER, DMODEL * DINNER);
    k_cvt<<<(VOCAB * DMODEL + 255) / 256, 256, 0, stream>>>(embed_w, We, VOCAB * DMODEL, VOCAB * DMODEL);
    k_embed<<<TOK, 64, 0, stream>>>(ids, embed_w, norm_w, u16);
    k_gemm_mfma<0><<<dim3(NPAD / 128, TOK / 128), 512, 0, stream>>>(
        u16, Wp, DMODEL, nullptr, z16, xbc, dts, dt_bias, nullptr, nullptr, conv_w, conv_b);
    k_states<<<BATCH * 64 * 4, 256, 0, stream>>>(xbc, dts, A_log, st16, acs, cdec);
    k_scan<<<BATCH * NH * 4, 256, 0, stream>>>((unsigned*)st16, cdec);
    k_y<<<BATCH * 64 * 4, 256, 0, stream>>>(xbc, dts, st16, acs, D_skip, Y16);
    k_gate<<<TOK, 64, 0, stream>>>(Y16, z16, gate_w, Yb);
    k_gemm_mfma<1><<<dim3(DMODEL / 128, TOK / 128), 512, 0, stream>>>(
        Yb, Wo, DINNER, nullptr, xf16, nullptr, nullptr, nullptr, ids, embed_w, nullptr, nullptr);
    k_gemm_mfma<2><<<dim3(VOCAB / 128, TOK / 128), 512, 0, stream>>>(
        xf16, We, DMODEL, out, nullptr, nullptr, nullptr, nullptr, nullptr, nullptr, nullptr, nullptr);
}

// Round 14
// 222.051 us; speedup vs baseline: 1.9307x; 1.1105x over previous
//
#include <hip/hip_runtime.h>
#include <cstdint>
#include <cstddef>

#define TOK    32768   // B*L
#define BATCH  8
#define SEQ    4096
#define DMODEL 256
#define DINNER 512
#define DSTATE 64
#define NH     16
#define HD     32
#define DPROJ  1168
#define NPAD   1280    // in_proj N padded to 10*128
#define CONVD  640
#define VOCAB  512
#define HGRP   4       // heads per states/y block
#define TS     132     // conv tile LDS stride (shorts)

typedef __attribute__((ext_vector_type(8))) short bf16x8;
typedef __attribute__((ext_vector_type(4))) float f32x4;

__device__ __forceinline__ unsigned short f2bf(float f) {
    unsigned u = __float_as_uint(f);
    u += 0x7fffu + ((u >> 16) & 1u);       // RNE
    return (unsigned short)(u >> 16);
}
__device__ __forceinline__ float bf2f(short s) {
    return __uint_as_float(((unsigned)(unsigned short)s) << 16);
}
// pack two f32 -> two bf16 (RNE) in one instruction
__device__ __forceinline__ unsigned cvtpk(float lo, float hi) {
    unsigned r;
    asm("v_cvt_pk_bf16_f32 %0, %1, %2" : "=v"(r) : "v"(lo), "v"(hi));
    return r;
}
__device__ __forceinline__ float fsilu(float s) {
    return s * __builtin_amdgcn_rcpf(1.f + __expf(-s));
}
__device__ __forceinline__ float sp(float v) {
    return v > 20.f ? v : __logf(1.f + __expf(v));
}

// async global->LDS, 16B per lane; dst wave-uniform base, lane fills dst+lane*16B
__device__ __forceinline__ void gload16(const short* src, short* dst) {
    __builtin_amdgcn_global_load_lds((const __attribute__((address_space(1))) void*)src,
                                     (__attribute__((address_space(3))) void*)dst, 16, 0, 0);
}

// ---------------- ws layout (floats, all 16B aligned) ----------------
#define U16_OFF   0                                    // TOK*256 bf16
#define Z16_OFF   (U16_OFF  + (size_t)TOK*128)         // TOK*512 bf16
#define XBC_OFF   (Z16_OFF  + (size_t)TOK*256)         // TOK*640 bf16
#define DTS_OFF   (XBC_OFF  + (size_t)TOK*320)         // TOK*16 fp32
#define ACS_OFF   (DTS_OFF  + (size_t)TOK*16)
#define CDEC_OFF  (ACS_OFF  + (size_t)BATCH*NH*64*64)
#define WP_OFF    (CDEC_OFF + (size_t)BATCH*NH*64)
#define WO_OFF    (WP_OFF   + 163840)
#define WE_OFF    (WO_OFF   + 65536)
#define UNION_OFF (WE_OFF   + 65536)
// union: st16 bf16 (33.5MB) -> later Yb ; Y16 bf16 (33.5MB) -> later xf16
#define UNION_FL  ((size_t)BATCH*64*NH*2048)
#define Y16_SUB   ((size_t)TOK*256)
#define XF_SUB    ((size_t)TOK*256)
#define WS_FLOATS (UNION_OFF + UNION_FL)

__global__ void k_diag(float* out, float wsmb) {
    if (blockIdx.x == 0 && threadIdx.x == 0) out[0] = wsmb;
}

// ---------------- weight fp32 -> bf16 (+ zero pad) ----------------
__global__ void k_cvt(const float* __restrict__ s, short* __restrict__ d, int nsrc, int ntot) {
    int i = blockIdx.x * 256 + threadIdx.x;
    if (i < ntot) d[i] = (i < nsrc) ? (short)f2bf(s[i]) : (short)0;
}

// ---------------- embed gather + rmsnorm -> u16 (bf16) ----------------
__global__ void k_embed(const int* __restrict__ ids, const float* __restrict__ embed,
                        const float* __restrict__ norm_w, short* __restrict__ u16) {
    int t = blockIdx.x;
    int lane = threadIdx.x;   // 64
    int id = ids[t];
    float4 v = ((const float4*)(embed + (size_t)id * DMODEL))[lane];
    float ss = v.x*v.x + v.y*v.y + v.z*v.z + v.w*v.w;
    #pragma unroll
    for (int o = 32; o > 0; o >>= 1) ss += __shfl_down(ss, o);
    ss = __shfl(ss, 0);
    float r = rsqrtf(ss * (1.0f / DMODEL) + 1e-6f);
    float4 w = ((const float4*)norm_w)[lane];
    unsigned p0 = cvtpk(v.x * r * w.x, v.y * r * w.y);
    unsigned p1 = cvtpk(v.z * r * w.z, v.w * r * w.w);
    ((uint2*)(u16 + (size_t)t * DMODEL))[lane] = make_uint2(p0, p1);
}

// ---------------- bf16 MFMA GEMM: 512 threads (8 waves), 128x128 tile, BK=64 ----------------
// (unchanged — double-buffered gload_lds, rule-#21 swizzle)
template<int MODE>
__global__ __launch_bounds__(512) void k_gemm_mfma(
    const short* __restrict__ A, const short* __restrict__ B, int K,
    float* __restrict__ outF, short* __restrict__ z16, short* __restrict__ xbc,
    float* __restrict__ dts, const float* __restrict__ dt_bias,
    const int* __restrict__ ids, const float* __restrict__ embed,
    const float* __restrict__ cw, const float* __restrict__ cb) {
    __shared__ __align__(16) short SM[32768];
    int tid = threadIdx.x;
    int m0 = blockIdx.y << 7;
    int n0 = blockIdx.x << 7;
    int wave = tid >> 6, lane = tid & 63;
    int wm = wave >> 1, wn = wave & 1;
    int lr = lane & 15, lg = lane >> 4;
    const f32x4 zer = {0.f, 0.f, 0.f, 0.f};
    f32x4 acc[2][4];
    #pragma unroll
    for (int i = 0; i < 2; i++)
        #pragma unroll
        for (int j = 0; j < 4; j++) acc[i][j] = zer;

    const bool isXBC = (MODE == 0) && (n0 >= 512) && (n0 < 1152);
    const bool atStart = (m0 & (SEQ - 1)) == 0;
    const bool haloLane = isXBC && (wm == 0) && !atStart && (lr < 3);
    f32x4 hacc[4];
    #pragma unroll
    for (int j = 0; j < 4; j++) hacc[j] = zer;
    const bf16x8 hz = {0, 0, 0, 0, 0, 0, 0, 0};
    bf16x8 hc0 = hz, hc1 = hz, hn0 = hz, hn1 = hz;

    const int nK = K >> 6;
    const int slo = lane >> 3;
    const int skb = ((lane & 7) ^ slo) << 3;

    {
        #pragma unroll
        for (int j = 0; j < 2; j++) {
            int row = wave * 16 + j * 8 + slo;
            gload16(A + (size_t)(m0 + row) * K + skb, SM + (wave * 2 + j) * 512);
            gload16(B + (size_t)(n0 + row) * K + skb, SM + 16384 + (wave * 2 + j) * 512);
        }
        if (haloLane) {
            hc0 = *(const bf16x8*)(A + (size_t)(m0 - 3 + lr) * K + lg * 8);
            hc1 = *(const bf16x8*)(A + (size_t)(m0 - 3 + lr) * K + 32 + lg * 8);
        }
    }
    __syncthreads();

    for (int kt = 0; kt < nK; ++kt) {
        if (kt + 1 < nK) {
            int k0 = (kt + 1) << 6;
            int nb = ((kt + 1) & 1) * 8192;
            #pragma unroll
            for (int j = 0; j < 2; j++) {
                int row = wave * 16 + j * 8 + slo;
                gload16(A + (size_t)(m0 + row) * K + k0 + skb, SM + nb + (wave * 2 + j) * 512);
                gload16(B + (size_t)(n0 + row) * K + k0 + skb, SM + 16384 + nb + (wave * 2 + j) * 512);
            }
            if (haloLane) {
                hn0 = *(const bf16x8*)(A + (size_t)(m0 - 3 + lr) * K + k0 + lg * 8);
                hn1 = *(const bf16x8*)(A + (size_t)(m0 - 3 + lr) * K + k0 + 32 + lg * 8);
            }
        }
        const short* CA = SM + (kt & 1) * 8192;
        const short* CB = SM + 16384 + (kt & 1) * 8192;
        #pragma unroll
        for (int kk = 0; kk < 2; kk++) {
            int sw = (((kk << 2) + lg) ^ (lr & 7)) << 3;
            bf16x8 af[2], bfr[4];
            #pragma unroll
            for (int mi = 0; mi < 2; mi++)
                af[mi] = *(const bf16x8*)&CA[(wm * 32 + mi * 16 + lr) * 64 + sw];
            #pragma unroll
            for (int ni = 0; ni < 4; ni++)
                bfr[ni] = *(const bf16x8*)&CB[(wn * 64 + ni * 16 + lr) * 64 + sw];
            #pragma unroll
            for (int mi = 0; mi < 2; mi++)
                #pragma unroll
                for (int ni = 0; ni < 4; ni++)
                    acc[mi][ni] = __builtin_amdgcn_mfma_f32_16x16x32_bf16(af[mi], bfr[ni], acc[mi][ni], 0, 0, 0);
            if (isXBC && wm == 0) {
                bf16x8 h = (kk == 0) ? hc0 : hc1;
                #pragma unroll
                for (int ni = 0; ni < 4; ni++)
                    hacc[ni] = __builtin_amdgcn_mfma_f32_16x16x32_bf16(h, bfr[ni], hacc[ni], 0, 0, 0);
            }
        }
        __syncthreads();
        hc0 = hn0; hc1 = hn1;
    }

    if (isXBC) {
        short* Tile = SM;
        #pragma unroll
        for (int mi = 0; mi < 2; mi++)
            #pragma unroll
            for (int ni = 0; ni < 4; ni++)
                #pragma unroll
                for (int r = 0; r < 4; r++) {
                    int row = wm * 32 + mi * 16 + lg * 4 + r;
                    int col = wn * 64 + ni * 16 + lr;
                    float v = acc[mi][ni][r];
                    float vo = __shfl_xor(v, 1);
                    if (!(lr & 1))
                        *(unsigned*)&Tile[(3 + row) * TS + col] = cvtpk(v, vo);
                }
        if (wm == 0 && lg == 0) {
            #pragma unroll
            for (int ni = 0; ni < 4; ni++)
                #pragma unroll
                for (int r = 0; r < 3; r++)
                    Tile[r * TS + wn * 64 + ni * 16 + lr] = (short)f2bf(hacc[ni][r]);
        }
        __syncthreads();
        int cp = tid & 63, rg = tid >> 6;
        int colb = cp * 2;
        int ch = (n0 - 512) + colb;
        float c0w0 = cw[ch * 4], c0w1 = cw[ch * 4 + 1], c0w2 = cw[ch * 4 + 2], c0w3 = cw[ch * 4 + 3];
        float c1w0 = cw[ch * 4 + 4], c1w1 = cw[ch * 4 + 5], c1w2 = cw[ch * 4 + 6], c1w3 = cw[ch * 4 + 7];
        float b0v = cb[ch], b1v = cb[ch + 1];
        int rbase = rg * 16;
        unsigned w0 = *(const unsigned*)&Tile[(rbase + 0) * TS + colb];
        unsigned w1 = *(const unsigned*)&Tile[(rbase + 1) * TS + colb];
        unsigned w2 = *(const unsigned*)&Tile[(rbase + 2) * TS + colb];
        for (int i = 0; i < 16; i++) {
            unsigned w3 = *(const unsigned*)&Tile[(rbase + i + 3) * TS + colb];
            float s0 = b0v, s1 = b1v;
            s0 = fmaf(bf2f((short)(w0 & 0xffffu)), c0w0, s0); s1 = fmaf(bf2f((short)(w0 >> 16)), c1w0, s1);
            s0 = fmaf(bf2f((short)(w1 & 0xffffu)), c0w1, s0); s1 = fmaf(bf2f((short)(w1 >> 16)), c1w1, s1);
            s0 = fmaf(bf2f((short)(w2 & 0xffffu)), c0w2, s0); s1 = fmaf(bf2f((short)(w2 >> 16)), c1w2, s1);
            s0 = fmaf(bf2f((short)(w3 & 0xffffu)), c0w3, s0); s1 = fmaf(bf2f((short)(w3 >> 16)), c1w3, s1);
            s0 = fsilu(s0);
            s1 = fsilu(s1);
            *(unsigned*)&xbc[(size_t)(m0 + rbase + i) * CONVD + ch] = cvtpk(s0, s1);
            w0 = w1; w1 = w2; w2 = w3;
        }
        return;
    }

    #pragma unroll
    for (int mi = 0; mi < 2; mi++) {
        #pragma unroll
        for (int r = 0; r < 4; r++) {
            int row = m0 + wm * 32 + mi * 16 + lg * 4 + r;
            int id = 0;
            if (MODE == 1) id = ids[row];
            #pragma unroll
            for (int ni = 0; ni < 4; ni++) {
                int col = n0 + wn * 64 + ni * 16 + lr;
                float v = acc[mi][ni][r];
                if (MODE == 0) {
                    if (n0 < 512) {
                        float vo = __shfl_xor(v, 1);
                        if (!(lr & 1))
                            *(unsigned*)&z16[(size_t)row * DINNER + col] = cvtpk(v, vo);
                    } else if (wn == 0 && ni == 0) {
                        dts[(size_t)row * NH + lr] = sp(v + dt_bias[lr]);
                    }
                } else if (MODE == 1) {
                    float vo = __shfl_xor(v, 1);
                    if (!(lr & 1)) {
                        float2 res = *(const float2*)&embed[(size_t)id * DMODEL + col];
                        *(unsigned*)&z16[(size_t)row * DMODEL + col] = cvtpk(v + res.x, vo + res.y);
                    }
                } else {
                    outF[(size_t)row * VOCAB + col] = v;
                }
            }
        }
    }
}

// ---------------- k_states: per (b,c,hg): chunk states, bulk-staged x, swizzled st16 write ----------------
// st16 element (p,n) stored at base + p*64 + ((n>>3)^(p&7))*8 + (n&7)  (rule-#21 pre-swizzle;
// k_scan is elementwise so the permutation is transparent; k_y reads fragments with the same XOR).
__global__ __launch_bounds__(256) void k_states(const short* __restrict__ xbc, const float* __restrict__ dts,
                                                const float* __restrict__ A_log,
                                                short* __restrict__ st16,
                                                float* __restrict__ acs_g, float* __restrict__ cdec) {
    __shared__ short BsB[64 * 72];   // B[k][n]
    __shared__ short BT[64 * 72];    // B^T[n][k], built once
    __shared__ short XdS[32 * 72];   // Xd[p][k] per head (padded, MFMA operand)
    __shared__ __align__(16) short XKP[64 * 32];  // raw x tile [k][p], gload16 target
    __shared__ float dkS[HGRP][64];
    __shared__ float dtS[64];
    int tid = threadIdx.x;
    int bid = blockIdx.x;
    int hg = bid & 3;
    int bc = bid >> 2;
    int b = bc >> 6, c = bc & 63;
    int h0 = hg * HGRP;
    size_t tbase = (size_t)b * SEQ + (size_t)c * 64;
    int wave = tid >> 6, lane = tid & 63;
    int lr = lane & 15, lg = lane >> 4;

    for (int i = tid; i < 64 * 64; i += 256) {
        int q = i >> 6, n = i & 63;
        BsB[q * 72 + n] = xbc[(tbase + q) * CONVD + DINNER + n];
    }
    {
        int h = h0 + wave;
        float Ah = -__expf(A_log[h]);
        float v = dts[(tbase + lane) * NH + h] * Ah;
        #pragma unroll
        for (int off = 1; off < 64; off <<= 1) {
            float o = __shfl_up(v, off);
            if (lane >= off) v += o;
        }
        acs_g[(((size_t)(b * NH + h)) * 64 + c) * 64 + lane] = v;
        float alast = __shfl(v, 63);
        dkS[wave][lane] = __expf(alast - v);
        if (lane == 0) cdec[(b * NH + h) * 64 + c] = __expf(alast);
    }
    __syncthreads();
    for (int i = tid; i < 64 * 64; i += 256) {
        int k = i >> 6, n = i & 63;
        BT[n * 72 + k] = BsB[k * 72 + n];
    }

    for (int hh = 0; hh < HGRP; hh++) {
        int h = h0 + hh;
        {   // bulk stage x head-tile: seg s = wave*64+lane -> k = s>>2, pseg = s&3
            int s = wave * 64 + lane;
            gload16(xbc + (tbase + (s >> 2)) * CONVD + h * HD + (s & 3) * 8, XKP + wave * 512);
        }
        if (tid < 64) dtS[tid] = dts[(tbase + tid) * NH + h];
        __syncthreads();   // drains gload (and first iter: BT build done)
        for (int i = tid; i < 2048; i += 256) {
            int p = i & 31, k = i >> 5;
            XdS[p * 72 + k] = (short)f2bf(bf2f(XKP[k * 32 + p]) * dtS[k] * dkS[hh][k]);
        }
        __syncthreads();
        {
            int ptile = wave & 1;
            bf16x8 a0 = *(const bf16x8*)&XdS[(ptile * 16 + lr) * 72 + lg * 8];
            bf16x8 a1 = *(const bf16x8*)&XdS[(ptile * 16 + lr) * 72 + 32 + lg * 8];
            size_t base = ((size_t)bc * NH + h) * 2048;
            #pragma unroll
            for (int j = 0; j < 2; j++) {
                int nt = (wave >> 1) * 2 + j;
                bf16x8 b0 = *(const bf16x8*)&BT[(nt * 16 + lr) * 72 + lg * 8];
                bf16x8 b1 = *(const bf16x8*)&BT[(nt * 16 + lr) * 72 + 32 + lg * 8];
                f32x4 z = {0.f, 0.f, 0.f, 0.f};
                z = __builtin_amdgcn_mfma_f32_16x16x32_bf16(a0, b0, z, 0, 0, 0);
                z = __builtin_amdgcn_mfma_f32_16x16x32_bf16(a1, b1, z, 0, 0, 0);
                #pragma unroll
                for (int r = 0; r < 4; r++) {
                    int p = ptile * 16 + lg * 4 + r;
                    float v = z[r];
                    float vo = __shfl_xor(v, 1);
                    if (!(lr & 1)) {
                        int chunk = (nt << 1) | (lr >> 3);
                        *(unsigned*)&st16[base + p * 64 + ((chunk ^ (p & 7)) << 3) + (lr & 7)] = cvtpk(v, vo);
                    }
                }
            }
        }
        __syncthreads();
    }
}

// ---------------- k_scan: sequential inter-chunk scan on bf16 states (fp32 accum) ----------------
__global__ __launch_bounds__(256) void k_scan(unsigned* __restrict__ st32, const float* __restrict__ cdec) {
    int bid = blockIdx.x;           // BATCH*NH*4
    int bh = bid >> 2, seg = bid & 3;
    int b = bh >> 4, h = bh & 15;
    int off = seg * 256 + threadIdx.x;   // u32 index within 1024
    float p0 = 0.f, p1 = 0.f;
    for (int c = 0; c < 64; c++) {
        float dec = cdec[bh * 64 + c];
        size_t idx = ((((size_t)b * 64 + c) * NH) + h) * 1024 + off;
        unsigned v = st32[idx];
        float s0 = bf2f((short)(v & 0xffffu));
        float s1 = bf2f((short)(v >> 16));
        st32[idx] = cvtpk(p0, p1);
        p0 = fmaf(dec, p0, s0);
        p1 = fmaf(dec, p1, s1);
    }
}

// ---------------- k_y: Y16 = Y_diag + exp(acs)*(C . prev^T) + D*x ----------------
// Bulk-staged per head: gload16 x-tile [k][p] + prev-tile (linear, XOR-swizzled fragments).
// Per-head phases: {issue gloads, stage acs/dt} bar {W build + transpose} bar {MFMA + Y} bar.
__global__ __launch_bounds__(256) void k_y(const short* __restrict__ xbc, const float* __restrict__ dts,
                                           const short* __restrict__ st16, const float* __restrict__ acs_g,
                                           const float* __restrict__ D_skip, short* __restrict__ Y16) {
    __shared__ short CsB[64 * 72];   // C[q][n], live throughout
    __shared__ short Wsh[64 * 72];   // B at load; W per head after M
    __shared__ short XtS[32 * 72];   // Xt[p][k] per head (padded, MFMA operand)
    __shared__ __align__(16) short PtL[32 * 64];  // prev tile, linear copy of (swizzled) st16
    __shared__ __align__(16) short XKP[64 * 32];  // raw x tile [k][p]
    __shared__ float acsH[64];
    __shared__ float dtS[64];
    int tid = threadIdx.x;
    int bid = blockIdx.x;
    int hg = bid & 3;
    int bc = bid >> 2;
    int b = bc >> 6, c = bc & 63;
    int h0 = hg * HGRP;
    size_t tbase = (size_t)b * SEQ + (size_t)c * 64;
    int wave = tid >> 6, lane = tid & 63;
    int lr = lane & 15, lg = lane >> 4;

    for (int i = tid; i < 64 * 64; i += 256) {
        int q = i >> 6, n = i & 63;
        const short* rowp = xbc + (tbase + q) * CONVD + DINNER;
        Wsh[q * 72 + n] = rowp[n];            // B (consumed by M, then reused as W)
        CsB[q * 72 + n] = rowp[DSTATE + n];   // C
    }
    __syncthreads();

    // M = C . B^T : wave owns q-strip of 16 rows, kept in regs
    f32x4 macc[4];
    bf16x8 ca0 = *(const bf16x8*)&CsB[(wave * 16 + lr) * 72 + lg * 8];
    bf16x8 ca1 = *(const bf16x8*)&CsB[(wave * 16 + lr) * 72 + 32 + lg * 8];
    {
        #pragma unroll
        for (int ct = 0; ct < 4; ct++) {
            bf16x8 b0 = *(const bf16x8*)&Wsh[(ct * 16 + lr) * 72 + lg * 8];
            bf16x8 b1 = *(const bf16x8*)&Wsh[(ct * 16 + lr) * 72 + 32 + lg * 8];
            f32x4 z = {0.f, 0.f, 0.f, 0.f};
            z = __builtin_amdgcn_mfma_f32_16x16x32_bf16(ca0, b0, z, 0, 0, 0);
            z = __builtin_amdgcn_mfma_f32_16x16x32_bf16(ca1, b1, z, 0, 0, 0);
            macc[ct] = z;
        }
    }
    __syncthreads();   // all waves done reading B before Wsh is overwritten

    for (int hh = 0; hh < HGRP; hh++) {
        int h = h0 + hh;
        // phase 1: issue bulk loads + stage per-head scalars
        {
            int s = wave * 64 + lane;
            gload16(xbc + (tbase + (s >> 2)) * CONVD + h * HD + (s & 3) * 8, XKP + wave * 512);
            gload16(st16 + ((size_t)bc * NH + h) * 2048 + s * 8, PtL + wave * 512);
        }
        if (tid < 64) {
            acsH[tid] = acs_g[(((size_t)(b * NH + h)) * 64 + c) * 64 + tid];
            dtS[tid] = dts[(tbase + tid) * NH + h];
        }
        __syncthreads();
        // phase 2: W build (wave-local rows) + Xt transpose
        #pragma unroll
        for (int ct = 0; ct < 4; ct++) {
            int k = ct * 16 + lr;
            #pragma unroll
            for (int r = 0; r < 4; r++) {
                int q = wave * 16 + lg * 4 + r;
                float wv = 0.f;
                if (k <= q) wv = macc[ct][r] * __expf(acsH[q] - acsH[k]);
                float wo = __shfl_xor(wv, 1);
                if (!(lr & 1))
                    *(unsigned*)&Wsh[q * 72 + k] = cvtpk(wv, wo);
            }
        }
        for (int i = tid; i < 2048; i += 256) {
            int p = i & 31, k = i >> 5;
            XtS[p * 72 + k] = (short)f2bf(bf2f(XKP[k * 32 + p]) * dtS[k]);
        }
        __syncthreads();
        // phase 3: MFMAs + Y write
        float eq[4];
        #pragma unroll
        for (int r = 0; r < 4; r++) eq[r] = __expf(acsH[wave * 16 + lg * 4 + r]);
        float dsk = D_skip[h];
        bf16x8 wa0 = *(const bf16x8*)&Wsh[(wave * 16 + lr) * 72 + lg * 8];
        bf16x8 wa1 = *(const bf16x8*)&Wsh[(wave * 16 + lr) * 72 + 32 + lg * 8];
        #pragma unroll
        for (int pt = 0; pt < 2; pt++) {
            int p = pt * 16 + lr;
            bf16x8 xb0 = *(const bf16x8*)&XtS[p * 72 + lg * 8];
            bf16x8 xb1 = *(const bf16x8*)&XtS[p * 72 + 32 + lg * 8];
            f32x4 zd = {0.f, 0.f, 0.f, 0.f};
            zd = __builtin_amdgcn_mfma_f32_16x16x32_bf16(wa0, xb0, zd, 0, 0, 0);
            zd = __builtin_amdgcn_mfma_f32_16x16x32_bf16(wa1, xb1, zd, 0, 0, 0);
            bf16x8 pb0 = *(const bf16x8*)&PtL[p * 64 + ((lg ^ (p & 7)) << 3)];
            bf16x8 pb1 = *(const bf16x8*)&PtL[p * 64 + (((lg + 4) ^ (p & 7)) << 3)];
            f32x4 zo = {0.f, 0.f, 0.f, 0.f};
            zo = __builtin_amdgcn_mfma_f32_16x16x32_bf16(ca0, pb0, zo, 0, 0, 0);
            zo = __builtin_amdgcn_mfma_f32_16x16x32_bf16(ca1, pb1, zo, 0, 0, 0);
            #pragma unroll
            for (int r = 0; r < 4; r++) {
                int q = wave * 16 + lg * 4 + r;
                float xv = bf2f(XKP[q * 32 + p]);
                float v = zd[r] + eq[r] * zo[r] + dsk * xv;
                float vo = __shfl_xor(v, 1);
                if (!(lr & 1))
                    *(unsigned*)&Y16[((tbase + q) * NH + h) * HD + p] = cvtpk(v, vo);
            }
        }
        __syncthreads();   // protect buffers before next head overwrite
    }
}

// ---------------- gate: Yb = bf16( rmsnorm(Y16 * silu(z16), gw, 1e-5) ) ----------------
__global__ void k_gate(const short* __restrict__ Y16, const short* __restrict__ z16,
                       const float* __restrict__ gw, short* __restrict__ Yb) {
    int t = blockIdx.x;
    int lane = threadIdx.x;  // 64
    union { int4 v; short s[8]; } zu, yu;
    zu.v = *(const int4*)(z16 + (size_t)t * DINNER + lane * 8);
    yu.v = *(const int4*)(Y16 + (size_t)t * DINNER + lane * 8);
    float g[8];
    float ss = 0.f;
    #pragma unroll
    for (int i = 0; i < 8; i++) {
        float zf = bf2f(zu.s[i]);
        g[i] = bf2f(yu.s[i]) * fsilu(zf);
        ss += g[i] * g[i];
    }
    #pragma unroll
    for (int o = 32; o > 0; o >>= 1) ss += __shfl_down(ss, o);
    ss = __shfl(ss, 0);
    float rr = rsqrtf(ss * (1.0f / DINNER) + 1e-5f);
    const float* wr = gw + lane * 8;
    float4 w0 = *(const float4*)wr;
    float4 w1 = *(const float4*)(wr + 4);
    float wv[8] = {w0.x, w0.y, w0.z, w0.w, w1.x, w1.y, w1.z, w1.w};
    union { uint4 v; unsigned u[4]; } ou;
    #pragma unroll
    for (int i = 0; i < 4; i++)
        ou.u[i] = cvtpk(g[2*i] * rr * wv[2*i], g[2*i+1] * rr * wv[2*i+1]);
    *(uint4*)(Yb + (size_t)t * DINNER + lane * 8) = ou.v;
}

extern "C" void kernel_launch(void* const* d_in, const int* in_sizes, int n_in,
                              void* d_out, int out_size, void* d_ws, size_t ws_size,
                              hipStream_t stream) {
    const int*   ids        = (const int*)d_in[0];
    const float* embed_w    = (const float*)d_in[1];
    const float* in_proj_w  = (const float*)d_in[2];
    const float* conv_w     = (const float*)d_in[3];
    const float* conv_b     = (const float*)d_in[4];
    const float* A_log      = (const float*)d_in[5];
    const float* D_skip     = (const float*)d_in[6];
    const float* dt_bias    = (const float*)d_in[7];
    const float* gate_w     = (const float*)d_in[8];
    const float* out_proj_w = (const float*)d_in[9];
    const float* norm_w     = (const float*)d_in[10];
    float* out = (float*)d_out;

    if (ws_size < WS_FLOATS * sizeof(float)) {
        k_diag<<<1, 64, 0, stream>>>(out, (float)(ws_size >> 20));
        return;
    }

    float* ws   = (float*)d_ws;
    short* u16  = (short*)(ws + U16_OFF);
    short* z16  = (short*)(ws + Z16_OFF);
    short* xbc  = (short*)(ws + XBC_OFF);
    float* dts  = ws + DTS_OFF;
    float* acs  = ws + ACS_OFF;
    float* cdec = ws + CDEC_OFF;
    short* Wp   = (short*)(ws + WP_OFF);
    short* Wo   = (short*)(ws + WO_OFF);
    short* We   = (short*)(ws + WE_OFF);
    short* st16 = (short*)(ws + UNION_OFF);                 // bf16 states (swizzled), 33.5 MB
    short* Y16  = (short*)(ws + UNION_OFF + Y16_SUB);       // bf16 Y, 33.5 MB
    short* Yb   = (short*)(ws + UNION_OFF);                 // gate out, aliases dead st16
    short* xf16 = (short*)(ws + UNION_OFF + XF_SUB);        // aliases dead Y16

    k_cvt<<<(NPAD * DMODEL + 255) / 256, 256, 0, stream>>>(in_proj_w, Wp, DPROJ * DMODEL, NPAD * DMODEL);
    k_cvt<<<(DMODEL * DINNER + 255) / 256, 256, 0, stream>>>(out_proj_w, Wo, DMODEL * DINNER, DMODEL * DINNER);
    k_cvt<<<(VOCAB * DMODEL + 255) / 256, 256, 0, stream>>>(embed_w, We, VOCAB * DMODEL, VOCAB * DMODEL);
    k_embed<<<TOK, 64, 0, stream>>>(ids, embed_w, norm_w, u16);
    k_gemm_mfma<0><<<dim3(NPAD / 128, TOK / 128), 512, 0, stream>>>(
        u16, Wp, DMODEL, nullptr, z16, xbc, dts, dt_bias, nullptr, nullptr, conv_w, conv_b);
    k_states<<<BATCH * 64 * 4, 256, 0, stream>>>(xbc, dts, A_log, st16, acs, cdec);
    k_scan<<<BATCH * NH * 4, 256, 0, stream>>>((unsigned*)st16, cdec);
    k_y<<<BATCH * 64 * 4, 256, 0, stream>>>(xbc, dts, st16, acs, D_skip, Y16);
    k_gate<<<TOK, 64, 0, stream>>>(Y16, z16, gate_w, Yb);
    k_gemm_mfma<1><<<dim3(DMODEL / 128, TOK / 128), 512, 0, stream>>>(
        Yb, Wo, DINNER, nullptr, xf16, nullptr, nullptr, nullptr, ids, embed_w, nullptr, nullptr);
    k_gemm_mfma<2><<<dim3(VOCAB / 128, TOK / 128), 512, 0, stream>>>(
        xf16, We, DMODEL, out, nullptr, nullptr, nullptr, nullptr, nullptr, nullptr, nullptr, nullptr);
}